// Round 8
// baseline (138.688 us; speedup 1.0000x reference)
//
#include <hip/hip_runtime.h>

typedef unsigned short u16;
typedef unsigned int   u32;
typedef __attribute__((ext_vector_type(4))) unsigned int u32x4;
typedef __attribute__((ext_vector_type(2))) unsigned int u32x2;
typedef __attribute__((ext_vector_type(8))) short        s16x8;
typedef __attribute__((ext_vector_type(4))) float        f32x4;
typedef __attribute__((ext_vector_type(2))) float        f32x2;

#define S_LEN 4096

typedef const __attribute__((address_space(1))) void gas_void;
typedef __attribute__((address_space(3))) void las_void;

__device__ __forceinline__ u16 f2bf(float f) {
    u32 u = __builtin_bit_cast(u32, f);
    u32 r = (u + 0x7fffu + ((u >> 16) & 1u)) >> 16;
    return (u16)r;
}
__device__ __forceinline__ float bflo(u32 w) { return __builtin_bit_cast(float, w << 16); }
__device__ __forceinline__ float bfhi(u32 w) { return __builtin_bit_cast(float, w & 0xffff0000u); }

__device__ __forceinline__ float rmax16(float v) {
    v = fmaxf(v, __shfl_xor(v, 1));
    v = fmaxf(v, __shfl_xor(v, 2));
    v = fmaxf(v, __shfl_xor(v, 4));
    v = fmaxf(v, __shfl_xor(v, 8));
    return v;
}
__device__ __forceinline__ float rsum16(float v) {
    v += __shfl_xor(v, 1);
    v += __shfl_xor(v, 2);
    v += __shfl_xor(v, 4);
    v += __shfl_xor(v, 8);
    return v;
}

// ---------------- fp32 -> bf16 cast (vectorized) ----------------
__global__ __launch_bounds__(256)
void cvt_f32_bf16(const float* __restrict__ in, u16* __restrict__ out, int n4) {
    int i = blockIdx.x * 256 + threadIdx.x;
    if (i >= n4) return;
    const f32x4 v = *(const f32x4*)(in + (size_t)i * 4);
    u32x2 o;
    o.x = (u32)f2bf(v.x) | ((u32)f2bf(v.y) << 16);
    o.y = (u32)f2bf(v.z) | ((u32)f2bf(v.w) << 16);
    *(u32x2*)(out + (size_t)i * 4) = o;
}

// ---------------- all four weights -> bf16, wq/wk/wv concatenated ----------------
__global__ __launch_bounds__(256)
void cvt_weights(const float* __restrict__ wq, const float* __restrict__ wk,
                 const float* __restrict__ wv, const float* __restrict__ wo,
                 u16* __restrict__ wqkv, u16* __restrict__ wob) {
    const int i   = blockIdx.x * 256 + threadIdx.x;    // 4*262144 total
    const int sel = i >> 18;
    const int loc = i & 262143;
    const float* src = (sel == 0) ? wq : (sel == 1) ? wk : (sel == 2) ? wv : wo;
    u16* dst = (sel < 3) ? (wqkv + (size_t)sel * 1048576) : wob;
    const f32x4 v = *(const f32x4*)(src + (size_t)loc * 4);
    u32x2 o;
    o.x = (u32)f2bf(v.x) | ((u32)f2bf(v.y) << 16);
    o.y = (u32)f2bf(v.z) | ((u32)f2bf(v.w) << 16);
    *(u32x2*)(dst + (size_t)loc * 4) = o;
}

// ---------------- cos/sin table from rope_freqs (S x 32) ----------------
__global__ __launch_bounds__(256)
void rope_tab(const float* __restrict__ freqs, float* __restrict__ tab) {
    const int i = blockIdx.x * 256 + threadIdx.x;      // 131072
    const float f = freqs[i];
    float sn, cs;
    sincosf(f, &sn, &cs);
    tab[i * 2]     = cs;
    tab[i * 2 + 1] = sn;
}

// =====================================================================
// m201-style fine-phase bf16 GEMM: C[M,N] = A[M,1024] * B[N,1024]^T
// BM=256, BN=128, BK=64, 512 thr (8 waves 4Mx2N, 64x64 out each).
// Triple-buffered LDS (144 KB): stage tile j+2 while computing tile j;
// end-of-tile s_waitcnt vmcnt(6) certifies tile j+1 (counted, never 0
// until drain). Each K-tile = 4 phases:
//   { 2-6 ds_read_b128 | 2 global_load_lds -> s_barrier ->
//     lgkmcnt(0)+sched_barrier -> setprio(1) + 8 MFMA + setprio(0) -> s_barrier }
// B-frags are reused across phase pairs (16 ds_reads/tile/wave).
// =====================================================================
#define VMW(n) asm volatile("s_waitcnt vmcnt(" #n ")" ::: "memory")
#define LGKM0() do { asm volatile("s_waitcnt lgkmcnt(0)" ::: "memory"); \
                     __builtin_amdgcn_sched_barrier(0); } while (0)
#define DSR0(d, a)   asm volatile("ds_read_b128 %0, %1"              : "=v"(d) : "v"(a))
#define DSR(d, a, o) asm volatile("ds_read_b128 %0, %1 offset:" #o   : "=v"(d) : "v"(a))
#define MFMA16(a, b, c) __builtin_amdgcn_mfma_f32_16x16x32_bf16(a, b, c, 0, 0, 0)
#define GL(p, d) __builtin_amdgcn_global_load_lds((gas_void*)(p), (las_void*)(d), 16, 0, 0)

template<int MODE>
__global__ __launch_bounds__(512, 2)
void gemm_bt(const u16* __restrict__ A, const u16* __restrict__ Bw,
             void* __restrict__ Cv, const float* __restrict__ cstab) {
    __shared__ __align__(16) u16 As[3][16384];   // 3 x (256 rows x 64)
    __shared__ __align__(16) u16 Bs[3][8192];    // 3 x (128 rows x 64)
    const int t    = threadIdx.x;
    const int bm   = blockIdx.x << 8;
    const int bn   = blockIdx.y << 7;
    const int wave = t >> 6;
    const int wr   = wave >> 1;                  // 0..3 (64-row band of A)
    const int wc   = wave & 1;                   // 0..1 (64-col band of B)
    const int lane = t & 63;
    const int fr   = lane & 15;
    const int kg   = lane >> 4;
    const int f7   = fr & 7;
    const int wq16 = wave << 9;                  // wave-uniform LDS u16 base
    const int K    = 1024;

    const int srow = t >> 3;                     // 0..63
    const int cSw  = (t & 7) ^ (srow & 7);       // inverse-swizzled source chunk

    const u16* ga0 = A  + (size_t)(bm + srow) * K + (cSw << 3);
    const u16* ga1 = ga0 + (size_t)64 * K;
    const u16* ga2 = ga1 + (size_t)64 * K;
    const u16* ga3 = ga2 + (size_t)64 * K;
    const u16* gb0 = Bw + (size_t)(bn + srow) * K + (cSw << 3);
    const u16* gb1 = gb0 + (size_t)64 * K;

    f32x4 acc[4][4];
#pragma unroll
    for (int m = 0; m < 4; ++m)
#pragma unroll
        for (int n = 0; n < 4; ++n) acc[m][n] = f32x4{0.f, 0.f, 0.f, 0.f};

#define STAGE_A01(c) do { GL(ga0, &As[c][wq16]); GL(ga1, &As[c][4096 + wq16]); } while (0)
#define STAGE_A23(c) do { GL(ga2, &As[c][8192 + wq16]); GL(ga3, &As[c][12288 + wq16]); } while (0)
#define STAGE_B(c)   do { GL(gb0, &Bs[c][wq16]); GL(gb1, &Bs[c][4096 + wq16]); \
    ga0 += 64; ga1 += 64; ga2 += 64; ga3 += 64; gb0 += 64; gb1 += 64; } while (0)

// 8 MFMA on two A frags x four B frags (b0..b3 from scope)
#define MFMA8(A0, A1, M0, M1) do { \
    __builtin_amdgcn_s_setprio(1); \
    acc[M0][0] = MFMA16(A0, b0, acc[M0][0]); \
    acc[M0][1] = MFMA16(A0, b1, acc[M0][1]); \
    acc[M0][2] = MFMA16(A0, b2, acc[M0][2]); \
    acc[M0][3] = MFMA16(A0, b3, acc[M0][3]); \
    acc[M1][0] = MFMA16(A1, b0, acc[M1][0]); \
    acc[M1][1] = MFMA16(A1, b1, acc[M1][1]); \
    acc[M1][2] = MFMA16(A1, b2, acc[M1][2]); \
    acc[M1][3] = MFMA16(A1, b3, acc[M1][3]); \
    __builtin_amdgcn_s_setprio(0); \
} while (0)

    const u32 ldsA = (u32)(size_t)(las_void*)&As[0][0];
    const u32 ldsB = (u32)(size_t)(las_void*)&Bs[0][0];
    const u32 aRow = (u32)(((wr << 6) + fr) << 7);   // row byte offset in A buf
    const u32 bRow = (u32)(((wc << 6) + fr) << 7);   // row byte offset in B buf
    const u32 ck0  = (u32)((kg ^ f7) << 4);
    const u32 ck1  = (u32)(((4 + kg) ^ f7) << 4);

    // prologue: stage tiles 0 and 1; counted wait for tile 0 only
    STAGE_A01(0); STAGE_A23(0); STAGE_B(0);
    STAGE_A01(1); STAGE_A23(1); STAGE_B(1);
    VMW(6);
    __builtin_amdgcn_s_barrier();

    u32 cur = 0, stg = 2;
#pragma unroll 1
    for (int j = 0; j < 16; ++j) {
        const u32 aa0 = ldsA + cur * 32768u + aRow + ck0;
        const u32 aa1 = ldsA + cur * 32768u + aRow + ck1;
        const u32 ba0 = ldsB + cur * 16384u + bRow + ck0;
        const u32 ba1 = ldsB + cur * 16384u + bRow + ck1;
        s16x8 a0, a1, a2, a3, b0, b1, b2, b3;

        // ---- phase 1: kk0, m0/m1 + all B(kk0) ----
        DSR0(a0, aa0); DSR(a1, aa0, 2048);
        DSR0(b0, ba0); DSR(b1, ba0, 2048); DSR(b2, ba0, 4096); DSR(b3, ba0, 6144);
        if (j < 14) STAGE_A01(stg);
        __builtin_amdgcn_s_barrier();
        LGKM0();
        MFMA8(a0, a1, 0, 1);
        __builtin_amdgcn_s_barrier();

        // ---- phase 2: kk0, m2/m3 (reuse b0..b3) ----
        DSR(a2, aa0, 4096); DSR(a3, aa0, 6144);
        if (j < 14) STAGE_A23(stg);
        __builtin_amdgcn_s_barrier();
        LGKM0();
        MFMA8(a2, a3, 2, 3);
        __builtin_amdgcn_s_barrier();

        // ---- phase 3: kk1, m0/m1 + all B(kk1) ----
        DSR0(a0, aa1); DSR(a1, aa1, 2048);
        DSR0(b0, ba1); DSR(b1, ba1, 2048); DSR(b2, ba1, 4096); DSR(b3, ba1, 6144);
        if (j < 14) STAGE_B(stg);
        __builtin_amdgcn_s_barrier();
        LGKM0();
        MFMA8(a0, a1, 0, 1);
        __builtin_amdgcn_s_barrier();

        // ---- phase 4: kk1, m2/m3; counted vmcnt certifies tile j+1 ----
        DSR(a2, aa1, 4096); DSR(a3, aa1, 6144);
        __builtin_amdgcn_s_barrier();
        LGKM0();
        MFMA8(a2, a3, 2, 3);
        if (j < 14) VMW(6); else VMW(0);
        __builtin_amdgcn_s_barrier();

        cur = (cur == 2) ? 0 : cur + 1;
        stg = (stg == 2) ? 0 : stg + 1;
    }

#undef STAGE_A01
#undef STAGE_A23
#undef STAGE_B
#undef MFMA8

    // ---- epilogue ----
    if constexpr (MODE == 1) {
        const int sel   = bn >> 10;                        // 0=q,1=k,2=v
        u16* outb       = (u16*)Cv + (size_t)sel * 8388608;
        const int bcol  = (bn & 1023) + (wc << 6) + fr;
        const bool doRope = (bn < 2048);
        const int crow0 = bm + (wr << 6) + (kg << 2);
#pragma unroll
        for (int m = 0; m < 4; ++m)
#pragma unroll
            for (int r = 0; r < 4; ++r) {
                const int row = crow0 + (m << 4) + r;
                float v0 = acc[m][0][r], v1 = acc[m][1][r], v2 = acc[m][2][r], v3 = acc[m][3][r];
                if (doRope) {
                    const int s = row & (S_LEN - 1);
                    const f32x2 c0 = *(const f32x2*)(cstab + (((s << 5) + fr) << 1));
                    const f32x2 c1 = *(const f32x2*)(cstab + (((s << 5) + 16 + fr) << 1));
                    const float n0 = v0 * c0.x - v2 * c0.y;
                    const float n2 = v2 * c0.x + v0 * c0.y;
                    const float n1 = v1 * c1.x - v3 * c1.y;
                    const float n3 = v3 * c1.x + v1 * c1.y;
                    v0 = n0; v1 = n1; v2 = n2; v3 = n3;
                }
                u16* op = outb + (size_t)row * 1024 + bcol;
                op[0]  = f2bf(v0);
                op[16] = f2bf(v1);
                op[32] = f2bf(v2);
                op[48] = f2bf(v3);
            }
    } else {
        float* outf     = (float*)Cv;
        const int bcol  = bn + (wc << 6) + fr;
        const int crow0 = bm + (wr << 6) + (kg << 2);
#pragma unroll
        for (int m = 0; m < 4; ++m)
#pragma unroll
            for (int r = 0; r < 4; ++r) {
                const int row = crow0 + (m << 4) + r;
                float* op = outf + (size_t)row * 1024 + bcol;
                op[0]  = acc[m][0][r];
                op[16] = acc[m][1][r];
                op[32] = acc[m][2][r];
                op[48] = acc[m][3][r];
            }
    }
}

// ---------------- sliding-window attention, MFMA ----------------
// block = (b, h, 64-query chunk), 4 waves; wave w owns queries [qs+16w, qs+16w+16).
// K window [qs-64, qs+128) in Ks (swizzled); V transposed in Vt[dim][key] (swizzled).
__global__ __launch_bounds__(256)
void attn_kernel(const u16* __restrict__ Q, const u16* __restrict__ K,
                 const u16* __restrict__ V, u16* __restrict__ O) {
    __shared__ __align__(16) u16 Ks[192 * 64];   // 24 KB; reused as P[4][16][192]
    __shared__ __align__(16) u16 Vt[64 * 192];   // 24 KB
    const int bid = blockIdx.x;
    const int ch  = bid & 63;
    const int h   = (bid >> 6) & 15;
    const int b   = bid >> 10;
    const int qs  = ch << 6;
    const int t   = threadIdx.x;

#pragma unroll
    for (int i = 0; i < 6; ++i) {
        const int cid = t + (i << 8);            // 0..1535
        const int row = cid >> 3;                // 0..191
        const int cc  = cid & 7;
        const int kp  = qs - 64 + row;
        const int sc  = cc ^ (row & 7);
        u32x4 kd = {0u, 0u, 0u, 0u};
        if (kp >= 0 && kp < S_LEN)
            kd = *(const u32x4*)(K + ((size_t)(b * S_LEN + kp)) * 1024 + (h << 6) + (cc << 3));
        *(u32x4*)(&Ks[(row << 6) + (sc << 3)]) = kd;
    }
    if (t < 192) {
        const int kp = qs - 64 + t;
        const int tc = t >> 3;
        const int ti = t & 7;
        if (kp >= 0 && kp < S_LEN) {
            const size_t off = ((size_t)(b * S_LEN + kp)) * 1024 + (h << 6);
#pragma unroll
            for (int c = 0; c < 8; ++c) {
                const u32x4 vd = *(const u32x4*)(V + off + (c << 3));
#pragma unroll
                for (int jj = 0; jj < 4; ++jj) {
                    const int d0 = (c << 3) + (jj << 1);
                    const int d1 = d0 + 1;
                    Vt[d0 * 192 + ((tc ^ (d0 & 7)) << 3) + ti] = (u16)(vd[jj] & 0xffffu);
                    Vt[d1 * 192 + ((tc ^ (d1 & 7)) << 3) + ti] = (u16)(vd[jj] >> 16);
                }
            }
        } else {
#pragma unroll
            for (int c = 0; c < 8; ++c)
#pragma unroll
                for (int j = 0; j < 8; ++j) {
                    const int d = (c << 3) + j;
                    Vt[d * 192 + ((tc ^ (d & 7)) << 3) + ti] = 0;
                }
        }
    }
    __syncthreads();

    const int w    = t >> 6;
    const int lane = t & 63;
    const int fr   = lane & 15;
    const int kg   = lane >> 4;
    const int f7   = fr & 7;

    const size_t qgoff = ((size_t)(b * S_LEN + qs + (w << 4) + fr)) * 1024 + (h << 6) + (kg << 3);
    const s16x8 qa0 = *(const s16x8*)(Q + qgoff);
    const s16x8 qa1 = *(const s16x8*)(Q + qgoff + 32);

    f32x4 sfr[9];
#pragma unroll
    for (int n = 0; n < 9; ++n) {
        const int row = (w << 4) + (n << 4) + fr;          // row&7 == f7
        f32x4 a = f32x4{0.f, 0.f, 0.f, 0.f};
        const s16x8 kb0 = *(const s16x8*)(&Ks[(row << 6) + ((kg ^ f7) << 3)]);
        const s16x8 kb1 = *(const s16x8*)(&Ks[(row << 6) + (((4 + kg) ^ f7) << 3)]);
        a = __builtin_amdgcn_mfma_f32_16x16x32_bf16(qa0, kb0, a, 0, 0, 0);
        a = __builtin_amdgcn_mfma_f32_16x16x32_bf16(qa1, kb1, a, 0, 0, 0);
        sfr[n] = a;
    }

    const float NEG = -__builtin_inff();
    float mx[4] = {NEG, NEG, NEG, NEG};
#pragma unroll
    for (int n = 0; n < 9; ++n) {
        const int j = (n << 4) + fr;
#pragma unroll
        for (int r = 0; r < 4; ++r) {
            const int q  = (kg << 2) + r;
            const int kp = qs - 64 + (w << 4) + j;
            const bool valid = (j >= q) && (j - q < 128) && (kp >= 0) && (kp < S_LEN);
            const float s = valid ? sfr[n][r] * 0.125f : NEG;
            sfr[n][r] = s;
            mx[r] = fmaxf(mx[r], s);
        }
    }
#pragma unroll
    for (int r = 0; r < 4; ++r) mx[r] = rmax16(mx[r]);
    float ls[4] = {0.f, 0.f, 0.f, 0.f};
#pragma unroll
    for (int n = 0; n < 9; ++n)
#pragma unroll
        for (int r = 0; r < 4; ++r) {
            const float p = __expf(sfr[n][r] - mx[r]);
            sfr[n][r] = p;
            ls[r] += p;
        }
#pragma unroll
    for (int r = 0; r < 4; ++r) ls[r] = rsum16(ls[r]);

    __syncthreads();
    u16* Pw = Ks + w * 3072;                 // 16 rows x 192
#pragma unroll
    for (int n = 0; n < 9; ++n) {
        const int j = (n << 4) + fr;
#pragma unroll
        for (int r = 0; r < 4; ++r) {
            const int q = (kg << 2) + r;
            Pw[q * 192 + (((j >> 3) ^ (q & 7)) << 3) + (j & 7)] = f2bf(sfr[n][r]);
        }
    }
    {
        const int j = 144 + fr;
#pragma unroll
        for (int r = 0; r < 4; ++r) {
            const int q = (kg << 2) + r;
            Pw[q * 192 + (((j >> 3) ^ (q & 7)) << 3) + (j & 7)] = 0;
        }
    }
    __syncthreads();

    f32x4 o[4];
#pragma unroll
    for (int nf = 0; nf < 4; ++nf) o[nf] = f32x4{0.f, 0.f, 0.f, 0.f};
#pragma unroll
    for (int ks = 0; ks < 5; ++ks) {
        const s16x8 pa = *(const s16x8*)(&Pw[fr * 192 + ((((ks << 2) + kg) ^ f7) << 3)]);
#pragma unroll
        for (int nf = 0; nf < 4; ++nf) {
            const int rdim = (nf << 4) + fr;              // rdim&7 == f7
            int c = (w << 1) + (ks << 2) + kg;
            if (c > 23) c = 23;                           // clamp: P==0 there
            const s16x8 vb = *(const s16x8*)(&Vt[rdim * 192 + ((c ^ f7) << 3)]);
            o[nf] = __builtin_amdgcn_mfma_f32_16x16x32_bf16(pa, vb, o[nf], 0, 0, 0);
        }
    }

    const size_t obase = ((size_t)(b * S_LEN + qs + (w << 4) + (kg << 2))) * 1024 + (h << 6) + fr;
#pragma unroll
    for (int r = 0; r < 4; ++r) {
        const float inv = 1.f / ls[r];
#pragma unroll
        for (int nf = 0; nf < 4; ++nf)
            O[obase + (size_t)r * 1024 + (nf << 4)] = f2bf(o[nf][r] * inv);
    }
}

extern "C" void kernel_launch(void* const* d_in, const int* in_sizes, int n_in,
                              void* d_out, int out_size, void* d_ws, size_t ws_size,
                              hipStream_t stream) {
    const float* x  = (const float*)d_in[0];
    const float* fr = (const float*)d_in[1];
    const float* wq = (const float*)d_in[2];
    const float* wk = (const float*)d_in[3];
    const float* wv = (const float*)d_in[4];
    const float* wo = (const float*)d_in[5];

    u16* ws    = (u16*)d_ws;
    u16* xb    = ws;                       // 8388608
    u16* wqkvb = xb + 8388608;             // 3145728
    u16* wob   = wqkvb + 3145728;          // 1048576
    u16* qb    = wob + 1048576;            // 8388608  (kb, vb follow contiguously)
    u16* kb    = qb + 8388608;
    u16* vb    = kb + 8388608;
    float* cstab = (float*)(vb + 8388608); // 262144 f32 (1 MB)
    u16* ob    = xb;                       // reuse xb after QKV GEMM

    cvt_f32_bf16<<<8192, 256, 0, stream>>>(x, xb, 2097152);
    cvt_weights<<<4096, 256, 0, stream>>>(wq, wk, wv, wo, wqkvb, wob);
    rope_tab<<<512, 256, 0, stream>>>(fr, cstab);

    dim3 gqkv(32, 24);   // M/256 x 3072/128 = 768 blocks (3 full cohorts)
    gemm_bt<1><<<gqkv, 512, 0, stream>>>(xb, wqkvb, qb, cstab);

    attn_kernel<<<2048, 256, 0, stream>>>(qb, kb, vb, ob);

    dim3 gout(32, 8);    // M/256 x 1024/128 = 256 blocks (1 full cohort)
    gemm_bt<2><<<gout, 512, 0, stream>>>(ob, wob, d_out, nullptr);
}

// Round 9
// 118.116 us; speedup vs baseline: 1.1742x; 1.1742x over previous
//
#include <hip/hip_runtime.h>

typedef unsigned short u16;
typedef unsigned int   u32;
typedef __attribute__((ext_vector_type(4))) unsigned int u32x4;
typedef __attribute__((ext_vector_type(2))) unsigned int u32x2;
typedef __attribute__((ext_vector_type(8))) short        s16x8;
typedef __attribute__((ext_vector_type(4))) float        f32x4;
typedef __attribute__((ext_vector_type(2))) float        f32x2;

#define S_LEN 4096

typedef const __attribute__((address_space(1))) void gas_void;
typedef __attribute__((address_space(3))) void las_void;

__device__ __forceinline__ u16 f2bf(float f) {
    u32 u = __builtin_bit_cast(u32, f);
    u32 r = (u + 0x7fffu + ((u >> 16) & 1u)) >> 16;
    return (u16)r;
}
__device__ __forceinline__ float bflo(u32 w) { return __builtin_bit_cast(float, w << 16); }
__device__ __forceinline__ float bfhi(u32 w) { return __builtin_bit_cast(float, w & 0xffff0000u); }

__device__ __forceinline__ float rmax16(float v) {
    v = fmaxf(v, __shfl_xor(v, 1));
    v = fmaxf(v, __shfl_xor(v, 2));
    v = fmaxf(v, __shfl_xor(v, 4));
    v = fmaxf(v, __shfl_xor(v, 8));
    return v;
}
__device__ __forceinline__ float rsum16(float v) {
    v += __shfl_xor(v, 1);
    v += __shfl_xor(v, 2);
    v += __shfl_xor(v, 4);
    v += __shfl_xor(v, 8);
    return v;
}

// ---------------- fused prep: x->bf16 | weights->bf16 | rope cos/sin table ----------------
__global__ __launch_bounds__(256)
void prep_kernel(const float* __restrict__ x,
                 const float* __restrict__ wq, const float* __restrict__ wk,
                 const float* __restrict__ wv, const float* __restrict__ wo,
                 const float* __restrict__ freqs,
                 u16* __restrict__ xb, u16* __restrict__ wqkv, u16* __restrict__ wob,
                 float* __restrict__ tab) {
    const int bid = blockIdx.x;
    const int t   = threadIdx.x;
    if (bid < 8192) {                                  // x: 2097152 f32x4
        const int i = bid * 256 + t;
        const f32x4 v = *(const f32x4*)(x + (size_t)i * 4);
        u32x2 o;
        o.x = (u32)f2bf(v.x) | ((u32)f2bf(v.y) << 16);
        o.y = (u32)f2bf(v.z) | ((u32)f2bf(v.w) << 16);
        *(u32x2*)(xb + (size_t)i * 4) = o;
    } else if (bid < 12288) {                          // weights: 4 x 262144 f32x4
        const int i   = (bid - 8192) * 256 + t;
        const int sel = i >> 18;
        const int loc = i & 262143;
        const float* src = (sel == 0) ? wq : (sel == 1) ? wk : (sel == 2) ? wv : wo;
        u16* dst = (sel < 3) ? (wqkv + (size_t)sel * 1048576) : wob;
        const f32x4 v = *(const f32x4*)(src + (size_t)loc * 4);
        u32x2 o;
        o.x = (u32)f2bf(v.x) | ((u32)f2bf(v.y) << 16);
        o.y = (u32)f2bf(v.z) | ((u32)f2bf(v.w) << 16);
        *(u32x2*)(dst + (size_t)loc * 4) = o;
    } else {                                           // rope table: 131072
        const int i = (bid - 12288) * 256 + t;
        const float f = freqs[i];
        float sn, cs;
        sincosf(f, &sn, &cs);
        tab[i * 2]     = cs;
        tab[i * 2 + 1] = sn;
    }
}

// =====================================================================
// Deep-pipelined bf16 GEMM (round-6 verified structure): ONE barrier per
// K-tile, register double-buffered frags, gload_lds w16, counted waits.
// BM=128, BN=256, BK=64, 512 thr (8 waves, 64x64 out each).
// MODE 1: fused QKV epilogue — q,k row-major bf16 (+RoPE on f32 acc);
//         V written TRANSPOSED: vt[(b*1024+col)*4096 + s].
// MODE 2: f32 row-major output.
// =====================================================================
#define VMW0() asm volatile("s_waitcnt vmcnt(0)" ::: "memory")
#define LGKM0() do { asm volatile("s_waitcnt lgkmcnt(0)" ::: "memory"); \
                     __builtin_amdgcn_sched_barrier(0); } while (0)
#define DSR0(d, a)   asm volatile("ds_read_b128 %0, %1"              : "=v"(d) : "v"(a))
#define DSR(d, a, o) asm volatile("ds_read_b128 %0, %1 offset:" #o   : "=v"(d) : "v"(a))
#define MFMA16(a, b, c) __builtin_amdgcn_mfma_f32_16x16x32_bf16(a, b, c, 0, 0, 0)
#define GL(p, d) __builtin_amdgcn_global_load_lds((gas_void*)(p), (las_void*)(d), 16, 0, 0)

#define FRAGS(P) s16x8 P##a0,P##a1,P##a2,P##a3,P##a4,P##a5,P##a6,P##a7, \
                       P##b0,P##b1,P##b2,P##b3,P##b4,P##b5,P##b6,P##b7

#define LOADTILE(P, CUR) do { \
    const u32 abase_ = ldsA + ((u32)(CUR) << 14) + arow; \
    const u32 bbase_ = ldsB + ((u32)(CUR) << 15) + brow; \
    const u32 aa0_ = abase_ + ck0, aa1_ = abase_ + ck1; \
    const u32 ba0_ = bbase_ + ck0, ba1_ = bbase_ + ck1; \
    DSR0(P##a0, aa0_); DSR(P##a1, aa0_, 2048); DSR(P##a2, aa0_, 4096); DSR(P##a3, aa0_, 6144); \
    DSR0(P##a4, aa1_); DSR(P##a5, aa1_, 2048); DSR(P##a6, aa1_, 4096); DSR(P##a7, aa1_, 6144); \
    DSR0(P##b0, ba0_); DSR(P##b1, ba0_, 2048); DSR(P##b2, ba0_, 4096); DSR(P##b3, ba0_, 6144); \
    DSR0(P##b4, ba1_); DSR(P##b5, ba1_, 2048); DSR(P##b6, ba1_, 4096); DSR(P##b7, ba1_, 6144); \
} while (0)

#define MFMA32(P) do { \
    __builtin_amdgcn_s_setprio(1); \
    acc[0][0]=MFMA16(P##a0,P##b0,acc[0][0]); acc[1][0]=MFMA16(P##a1,P##b0,acc[1][0]); \
    acc[2][0]=MFMA16(P##a2,P##b0,acc[2][0]); acc[3][0]=MFMA16(P##a3,P##b0,acc[3][0]); \
    acc[0][1]=MFMA16(P##a0,P##b1,acc[0][1]); acc[1][1]=MFMA16(P##a1,P##b1,acc[1][1]); \
    acc[2][1]=MFMA16(P##a2,P##b1,acc[2][1]); acc[3][1]=MFMA16(P##a3,P##b1,acc[3][1]); \
    acc[0][2]=MFMA16(P##a0,P##b2,acc[0][2]); acc[1][2]=MFMA16(P##a1,P##b2,acc[1][2]); \
    acc[2][2]=MFMA16(P##a2,P##b2,acc[2][2]); acc[3][2]=MFMA16(P##a3,P##b2,acc[3][2]); \
    acc[0][3]=MFMA16(P##a0,P##b3,acc[0][3]); acc[1][3]=MFMA16(P##a1,P##b3,acc[1][3]); \
    acc[2][3]=MFMA16(P##a2,P##b3,acc[2][3]); acc[3][3]=MFMA16(P##a3,P##b3,acc[3][3]); \
    acc[0][0]=MFMA16(P##a4,P##b4,acc[0][0]); acc[1][0]=MFMA16(P##a5,P##b4,acc[1][0]); \
    acc[2][0]=MFMA16(P##a6,P##b4,acc[2][0]); acc[3][0]=MFMA16(P##a7,P##b4,acc[3][0]); \
    acc[0][1]=MFMA16(P##a4,P##b5,acc[0][1]); acc[1][1]=MFMA16(P##a5,P##b5,acc[1][1]); \
    acc[2][1]=MFMA16(P##a6,P##b5,acc[2][1]); acc[3][1]=MFMA16(P##a7,P##b5,acc[3][1]); \
    acc[0][2]=MFMA16(P##a4,P##b6,acc[0][2]); acc[1][2]=MFMA16(P##a5,P##b6,acc[1][2]); \
    acc[2][2]=MFMA16(P##a6,P##b6,acc[2][2]); acc[3][2]=MFMA16(P##a7,P##b6,acc[3][2]); \
    acc[0][3]=MFMA16(P##a4,P##b7,acc[0][3]); acc[1][3]=MFMA16(P##a5,P##b7,acc[1][3]); \
    acc[2][3]=MFMA16(P##a6,P##b7,acc[2][3]); acc[3][3]=MFMA16(P##a7,P##b7,acc[3][3]); \
    __builtin_amdgcn_s_setprio(0); \
} while (0)

template<int MODE>
__global__ __launch_bounds__(512, 2)
void gemm_bt(const u16* __restrict__ A, const u16* __restrict__ Bw,
             void* __restrict__ Cv, const float* __restrict__ cstab) {
    __shared__ __align__(16) u16 As[2][8192];    // [2][128 rows][64]
    __shared__ __align__(16) u16 Bs[2][16384];   // [2][256 rows][64]
    const int t    = threadIdx.x;
    const int bm   = blockIdx.x << 7;
    const int bn   = blockIdx.y << 8;
    const int wave = t >> 6;
    const int wr   = (wave >> 2) & 1;
    const int wc   = wave & 3;
    const int lane = t & 63;
    const int fr   = lane & 15;
    const int kg   = lane >> 4;
    const int f7   = fr & 7;
    const int wq16 = wave << 9;
    const int K    = 1024;

    const int srow = t >> 3;
    const int cSw  = (t & 7) ^ (srow & 7);

    const u16* ga0 = A  + (size_t)(bm + srow) * K + (cSw << 3);
    const u16* ga1 = ga0 + (size_t)64 * K;
    const u16* gb0 = Bw + (size_t)(bn + srow) * K + (cSw << 3);
    const u16* gb1 = gb0 + (size_t)64 * K;
    const u16* gb2 = gb1 + (size_t)64 * K;
    const u16* gb3 = gb2 + (size_t)64 * K;

    f32x4 acc[4][4];
#pragma unroll
    for (int m = 0; m < 4; ++m)
#pragma unroll
        for (int n = 0; n < 4; ++n) acc[m][n] = f32x4{0.f, 0.f, 0.f, 0.f};

    FRAGS(X);
    FRAGS(Y);

#define STAGE(cur) do { \
    GL(ga0, &As[cur][wq16]);          GL(ga1, &As[cur][4096 + wq16]); \
    GL(gb0, &Bs[cur][wq16]);          GL(gb1, &Bs[cur][4096 + wq16]); \
    GL(gb2, &Bs[cur][8192 + wq16]);   GL(gb3, &Bs[cur][12288 + wq16]); \
    ga0 += 64; ga1 += 64; gb0 += 64; gb1 += 64; gb2 += 64; gb3 += 64; \
} while (0)

    const u32 ldsA = (u32)(size_t)(las_void*)&As[0][0];
    const u32 ldsB = (u32)(size_t)(las_void*)&Bs[0][0];
    const u32 arow = (u32)(((wr << 6) + fr) << 7);
    const u32 brow = (u32)(((wc << 6) + fr) << 7);
    const u32 ck0  = (u32)((kg ^ f7) << 4);
    const u32 ck1  = (u32)(((4 + kg) ^ f7) << 4);

    STAGE(0);
    VMW0();
    __builtin_amdgcn_s_barrier();
    LOADTILE(X, 0);
    STAGE(1);

#pragma unroll 1
    for (int j = 0; j < 16; j += 2) {
        LGKM0();
        VMW0();
        __builtin_amdgcn_s_barrier();
        if (j < 14) STAGE(0);
        LOADTILE(Y, 1);
        MFMA32(X);
        LGKM0();
        if (j < 14) {
            VMW0();
            __builtin_amdgcn_s_barrier();
            if (j < 13) STAGE(1);
            LOADTILE(X, 0);
        }
        MFMA32(Y);
    }

#undef STAGE

    // ---- epilogue ----
    if constexpr (MODE == 1) {
        const int sel   = bn >> 10;                        // 0=q,1=k,2=v
        const int bcol  = (bn & 1023) + (wc << 6) + fr;
        const int crow0 = bm + (wr << 6) + (kg << 2);
        if (sel == 2) {
            // V transposed: vt[(b*1024 + col)*4096 + s]; r=0..3 are consecutive tokens
            u16* vt = (u16*)Cv + (size_t)16777216;
#pragma unroll
            for (int m = 0; m < 4; ++m) {
                const int row0 = crow0 + (m << 4);
                const int bb   = row0 >> 12;
                const int s0   = row0 & 4095;
#pragma unroll
                for (int n = 0; n < 4; ++n) {
                    u32x2 pk;
                    pk.x = (u32)f2bf(acc[m][n][0]) | ((u32)f2bf(acc[m][n][1]) << 16);
                    pk.y = (u32)f2bf(acc[m][n][2]) | ((u32)f2bf(acc[m][n][3]) << 16);
                    *(u32x2*)(vt + ((size_t)((bb << 10) + bcol + (n << 4))) * 4096 + s0) = pk;
                }
            }
        } else {
            u16* outb = (u16*)Cv + (size_t)sel * 8388608;
#pragma unroll
            for (int m = 0; m < 4; ++m)
#pragma unroll
                for (int r = 0; r < 4; ++r) {
                    const int row = crow0 + (m << 4) + r;
                    float v0 = acc[m][0][r], v1 = acc[m][1][r], v2 = acc[m][2][r], v3 = acc[m][3][r];
                    const int s = row & (S_LEN - 1);
                    const f32x2 c0 = *(const f32x2*)(cstab + (((s << 5) + fr) << 1));
                    const f32x2 c1 = *(const f32x2*)(cstab + (((s << 5) + 16 + fr) << 1));
                    const float n0 = v0 * c0.x - v2 * c0.y;
                    const float n2 = v2 * c0.x + v0 * c0.y;
                    const float n1 = v1 * c1.x - v3 * c1.y;
                    const float n3 = v3 * c1.x + v1 * c1.y;
                    u16* op = outb + (size_t)row * 1024 + bcol;
                    op[0]  = f2bf(n0);
                    op[16] = f2bf(n1);
                    op[32] = f2bf(n2);
                    op[48] = f2bf(n3);
                }
        }
    } else {
        float* outf     = (float*)Cv;
        const int bcol  = bn + (wc << 6) + fr;
        const int crow0 = bm + (wr << 6) + (kg << 2);
#pragma unroll
        for (int m = 0; m < 4; ++m)
#pragma unroll
            for (int r = 0; r < 4; ++r) {
                const int row = crow0 + (m << 4) + r;
                float* op = outf + (size_t)row * 1024 + bcol;
                op[0]  = acc[m][0][r];
                op[16] = acc[m][1][r];
                op[32] = acc[m][2][r];
                op[48] = acc[m][3][r];
            }
    }
}

// ---------------- sliding-window attention, MFMA, gload_lds staging ----------------
// block = (b, h, 64-query chunk), 4 waves; wave w owns queries [qs+16w, qs+16w+16).
// Ks[192 rows][8 chunks] XOR-swizzled via pre-swizzled source; Vs[64 d][24 chunks]
// rotate-swizzled (chunk + (d&7)*3 mod 24). V comes pre-transposed from the GEMM.
// OOB-window staging reads land in adjacent finite ws data; masked to P=0 before use.
__global__ __launch_bounds__(256)
void attn_kernel(const u16* __restrict__ Q, const u16* __restrict__ K,
                 const u16* __restrict__ Vt, u16* __restrict__ O) {
    __shared__ __align__(16) u16 Ks[192 * 64];   // 24 KB; reused as P[4][16][192]
    __shared__ __align__(16) u16 Vs[64 * 192];   // 24 KB
    const int bid = blockIdx.x;
    const int ch  = bid & 63;
    const int h   = (bid >> 6) & 15;
    const int b   = bid >> 10;
    const int qs  = ch << 6;
    const int t   = threadIdx.x;
    const int ub  = t & 192;                     // wave-uniform base (wave*64)

    // ---- stage K: LDS[row][c] holds global chunk c^(row&7) ----
#pragma unroll
    for (int i = 0; i < 6; ++i) {
        const int cid = (i << 8) + t;            // 0..1535
        const int row = cid >> 3;
        const int g   = (cid & 7) ^ (row & 7);
        const int kp  = qs - 64 + row;           // may be OOB-row: stays in-buffer, masked later
        const u16* src = K + ((size_t)((b << 12) + kp)) * 1024 + (h << 6) + (g << 3);
        GL(src, &Ks[((i << 8) + ub) << 3]);
    }
    // ---- stage V^T: LDS[d][c] holds global chunk (c - (d&7)*3) mod 24 ----
#pragma unroll
    for (int i = 0; i < 6; ++i) {
        const int cid = (i << 8) + t;            // 0..1535
        const int d   = cid / 24;
        const int c   = cid - d * 24;
        int g = c - (d & 7) * 3;
        if (g < 0) g += 24;
        const int key = qs - 64 + (g << 3);
        const u16* src = Vt + ((size_t)((b << 10) + (h << 6) + d)) * 4096 + key;
        GL(src, &Vs[((i << 8) + ub) << 3]);
    }

    const int w    = t >> 6;
    const int lane = t & 63;
    const int fr   = lane & 15;
    const int kg   = lane >> 4;
    const int f7   = fr & 7;

    const size_t qgoff = ((size_t)((b << 12) + qs + (w << 4) + fr)) * 1024 + (h << 6) + (kg << 3);
    const s16x8 qa0 = *(const s16x8*)(Q + qgoff);
    const s16x8 qa1 = *(const s16x8*)(Q + qgoff + 32);

    VMW0();
    __syncthreads();

    // ---- QK^T: 9 key fragments (window of 144 keys starting at w*16) ----
    f32x4 sfr[9];
#pragma unroll
    for (int n = 0; n < 9; ++n) {
        const int row = (w << 4) + (n << 4) + fr;          // row&7 == f7
        f32x4 a = f32x4{0.f, 0.f, 0.f, 0.f};
        const s16x8 kb0 = *(const s16x8*)(&Ks[(row << 6) + ((kg ^ f7) << 3)]);
        const s16x8 kb1 = *(const s16x8*)(&Ks[(row << 6) + (((4 + kg) ^ f7) << 3)]);
        a = MFMA16(qa0, kb0, a);
        a = MFMA16(qa1, kb1, a);
        sfr[n] = a;
    }

    // ---- mask + scale + wave-parallel softmax ----
    const float NEG = -__builtin_inff();
    float mx[4] = {NEG, NEG, NEG, NEG};
#pragma unroll
    for (int n = 0; n < 9; ++n) {
        const int j = (n << 4) + fr;
#pragma unroll
        for (int r = 0; r < 4; ++r) {
            const int q  = (kg << 2) + r;
            const int kp = qs - 64 + (w << 4) + j;
            const bool valid = (j >= q) && (j - q < 128) && (kp >= 0) && (kp < S_LEN);
            const float s = valid ? sfr[n][r] * 0.125f : NEG;
            sfr[n][r] = s;
            mx[r] = fmaxf(mx[r], s);
        }
    }
#pragma unroll
    for (int r = 0; r < 4; ++r) mx[r] = rmax16(mx[r]);
    float ls[4] = {0.f, 0.f, 0.f, 0.f};
#pragma unroll
    for (int n = 0; n < 9; ++n)
#pragma unroll
        for (int r = 0; r < 4; ++r) {
            const float p = __expf(sfr[n][r] - mx[r]);
            sfr[n][r] = p;
            ls[r] += p;
        }
#pragma unroll
    for (int r = 0; r < 4; ++r) ls[r] = rsum16(ls[r]);

    // ---- write P (bf16) into Ks buffer, swizzled; pad keys [144,160) with 0 ----
    __syncthreads();
    u16* Pw = Ks + w * 3072;                 // 16 rows x 192
#pragma unroll
    for (int n = 0; n < 9; ++n) {
        const int j = (n << 4) + fr;
#pragma unroll
        for (int r = 0; r < 4; ++r) {
            const int q = (kg << 2) + r;
            Pw[q * 192 + (((j >> 3) ^ (q & 7)) << 3) + (j & 7)] = f2bf(sfr[n][r]);
        }
    }
    {
        const int j = 144 + fr;
#pragma unroll
        for (int r = 0; r < 4; ++r) {
            const int q = (kg << 2) + r;
            Pw[q * 192 + (((j >> 3) ^ (q & 7)) << 3) + (j & 7)] = 0;
        }
    }
    __syncthreads();

    // ---- PV: P[16 x 160] * V[160 x 64] from Vs rows ----
    f32x4 o[4];
#pragma unroll
    for (int nf = 0; nf < 4; ++nf) o[nf] = f32x4{0.f, 0.f, 0.f, 0.f};
    const int cs0 = f7 * 3;
#pragma unroll
    for (int ks = 0; ks < 5; ++ks) {
        const s16x8 pa = *(const s16x8*)(&Pw[fr * 192 + ((((ks << 2) + kg) ^ f7) << 3)]);
        int c = (w << 1) + (ks << 2) + kg;
        if (c > 23) c = 23;                           // clamp: P==0 there
        int cs = c + cs0;
        if (cs >= 24) cs -= 24;
#pragma unroll
        for (int nf = 0; nf < 4; ++nf) {
            const int d = (nf << 4) + fr;             // d&7 == f7
            const s16x8 vbf = *(const s16x8*)(&Vs[d * 192 + (cs << 3)]);
            o[nf] = MFMA16(pa, vbf, o[nf]);
        }
    }

    // ---- normalize + store ----
    const size_t obase = ((size_t)((b << 12) + qs + (w << 4) + (kg << 2))) * 1024 + (h << 6) + fr;
#pragma unroll
    for (int r = 0; r < 4; ++r) {
        const float inv = 1.f / ls[r];
#pragma unroll
        for (int nf = 0; nf < 4; ++nf)
            O[obase + (size_t)r * 1024 + (nf << 4)] = f2bf(o[nf][r] * inv);
    }
}

extern "C" void kernel_launch(void* const* d_in, const int* in_sizes, int n_in,
                              void* d_out, int out_size, void* d_ws, size_t ws_size,
                              hipStream_t stream) {
    const float* x  = (const float*)d_in[0];
    const float* fr = (const float*)d_in[1];
    const float* wq = (const float*)d_in[2];
    const float* wk = (const float*)d_in[3];
    const float* wv = (const float*)d_in[4];
    const float* wo = (const float*)d_in[5];

    u16* ws    = (u16*)d_ws;
    u16* xb    = ws;                       // 8388608
    u16* wqkvb = xb + 8388608;             // 3145728
    u16* wob   = wqkvb + 3145728;          // 1048576
    u16* qb    = wob + 1048576;            // 8388608  (kb, vtb follow contiguously)
    u16* kb    = qb + 8388608;
    u16* vtb   = kb + 8388608;             // V transposed [b*1024+col][4096]
    float* cstab = (float*)(vtb + 8388608);
    u16* ob    = xb;                       // reuse xb after QKV GEMM

    prep_kernel<<<12800, 256, 0, stream>>>(x, wq, wk, wv, wo, fr, xb, wqkvb, wob, cstab);

    dim3 gqkv(64, 12);   // M/128 x 3072/256 = 768 blocks (3 full cohorts)
    gemm_bt<1><<<gqkv, 512, 0, stream>>>(xb, wqkvb, qb, cstab);

    attn_kernel<<<2048, 256, 0, stream>>>(qb, kb, vtb, ob);

    dim3 gout(64, 4);    // M/128 x 1024/256 = 256 blocks (1 full cohort)
    gemm_bt<2><<<gout, 512, 0, stream>>>(ob, wob, d_out, nullptr);
}

// Round 10
// 115.677 us; speedup vs baseline: 1.1989x; 1.0211x over previous
//
#include <hip/hip_runtime.h>

typedef unsigned short u16;
typedef unsigned int   u32;
typedef __attribute__((ext_vector_type(4))) unsigned int u32x4;
typedef __attribute__((ext_vector_type(2))) unsigned int u32x2;
typedef __attribute__((ext_vector_type(8))) short        s16x8;
typedef __attribute__((ext_vector_type(4))) float        f32x4;
typedef __attribute__((ext_vector_type(2))) float        f32x2;

#define S_LEN 4096

typedef const __attribute__((address_space(1))) void gas_void;
typedef __attribute__((address_space(3))) void las_void;

__device__ __forceinline__ u16 f2bf(float f) {
    u32 u = __builtin_bit_cast(u32, f);
    u32 r = (u + 0x7fffu + ((u >> 16) & 1u)) >> 16;
    return (u16)r;
}

__device__ __forceinline__ float rmax16(float v) {
    v = fmaxf(v, __shfl_xor(v, 1));
    v = fmaxf(v, __shfl_xor(v, 2));
    v = fmaxf(v, __shfl_xor(v, 4));
    v = fmaxf(v, __shfl_xor(v, 8));
    return v;
}
__device__ __forceinline__ float rsum16(float v) {
    v += __shfl_xor(v, 1);
    v += __shfl_xor(v, 2);
    v += __shfl_xor(v, 4);
    v += __shfl_xor(v, 8);
    return v;
}

// ---------------- fused prep: x->bf16 | weights->bf16 | rope cos/sin table ----------------
__global__ __launch_bounds__(256)
void prep_kernel(const float* __restrict__ x,
                 const float* __restrict__ wq, const float* __restrict__ wk,
                 const float* __restrict__ wv, const float* __restrict__ wo,
                 const float* __restrict__ freqs,
                 u16* __restrict__ xb, u16* __restrict__ wqkv, u16* __restrict__ wob,
                 float* __restrict__ tab) {
    const int bid = blockIdx.x;
    const int t   = threadIdx.x;
    if (bid < 8192) {                                  // x: 2097152 f32x4
        const int i = bid * 256 + t;
        const f32x4 v = *(const f32x4*)(x + (size_t)i * 4);
        u32x2 o;
        o.x = (u32)f2bf(v.x) | ((u32)f2bf(v.y) << 16);
        o.y = (u32)f2bf(v.z) | ((u32)f2bf(v.w) << 16);
        *(u32x2*)(xb + (size_t)i * 4) = o;
    } else if (bid < 12288) {                          // weights: 4 x 262144 f32x4
        const int i   = (bid - 8192) * 256 + t;
        const int sel = i >> 18;
        const int loc = i & 262143;
        const float* src = (sel == 0) ? wq : (sel == 1) ? wk : (sel == 2) ? wv : wo;
        u16* dst = (sel < 3) ? (wqkv + (size_t)sel * 1048576) : wob;
        const f32x4 v = *(const f32x4*)(src + (size_t)loc * 4);
        u32x2 o;
        o.x = (u32)f2bf(v.x) | ((u32)f2bf(v.y) << 16);
        o.y = (u32)f2bf(v.z) | ((u32)f2bf(v.w) << 16);
        *(u32x2*)(dst + (size_t)loc * 4) = o;
    } else {                                           // rope table: 131072
        const int i = (bid - 12288) * 256 + t;
        const float f = freqs[i];
        float sn, cs;
        sincosf(f, &sn, &cs);
        tab[i * 2]     = cs;
        tab[i * 2 + 1] = sn;
    }
}

// =====================================================================
// Deep-pipelined bf16 GEMM (round-6 verified structure): ONE barrier per
// K-tile, register double-buffered frags, gload_lds w16, counted waits.
// BM=128, BN=256, BK=64, 512 thr (8 waves, 64x64 out each).
// MODE 1: fused QKV epilogue. Q,K written HEAD-MAJOR [b][h][s][64] bf16
//         (+RoPE on f32 acc). V written transposed [b][h][d][s].
// MODE 2: f32 row-major output.
// =====================================================================
#define VMW0() asm volatile("s_waitcnt vmcnt(0)" ::: "memory")
#define LGKM0() do { asm volatile("s_waitcnt lgkmcnt(0)" ::: "memory"); \
                     __builtin_amdgcn_sched_barrier(0); } while (0)
#define DSR0(d, a)   asm volatile("ds_read_b128 %0, %1"              : "=v"(d) : "v"(a))
#define DSR(d, a, o) asm volatile("ds_read_b128 %0, %1 offset:" #o   : "=v"(d) : "v"(a))
#define MFMA16(a, b, c) __builtin_amdgcn_mfma_f32_16x16x32_bf16(a, b, c, 0, 0, 0)
#define GL(p, d) __builtin_amdgcn_global_load_lds((gas_void*)(p), (las_void*)(d), 16, 0, 0)

#define FRAGS(P) s16x8 P##a0,P##a1,P##a2,P##a3,P##a4,P##a5,P##a6,P##a7, \
                       P##b0,P##b1,P##b2,P##b3,P##b4,P##b5,P##b6,P##b7

#define LOADTILE(P, CUR) do { \
    const u32 abase_ = ldsA + ((u32)(CUR) << 14) + arow; \
    const u32 bbase_ = ldsB + ((u32)(CUR) << 15) + brow; \
    const u32 aa0_ = abase_ + ck0, aa1_ = abase_ + ck1; \
    const u32 ba0_ = bbase_ + ck0, ba1_ = bbase_ + ck1; \
    DSR0(P##a0, aa0_); DSR(P##a1, aa0_, 2048); DSR(P##a2, aa0_, 4096); DSR(P##a3, aa0_, 6144); \
    DSR0(P##a4, aa1_); DSR(P##a5, aa1_, 2048); DSR(P##a6, aa1_, 4096); DSR(P##a7, aa1_, 6144); \
    DSR0(P##b0, ba0_); DSR(P##b1, ba0_, 2048); DSR(P##b2, ba0_, 4096); DSR(P##b3, ba0_, 6144); \
    DSR0(P##b4, ba1_); DSR(P##b5, ba1_, 2048); DSR(P##b6, ba1_, 4096); DSR(P##b7, ba1_, 6144); \
} while (0)

#define MFMA32(P) do { \
    __builtin_amdgcn_s_setprio(1); \
    acc[0][0]=MFMA16(P##a0,P##b0,acc[0][0]); acc[1][0]=MFMA16(P##a1,P##b0,acc[1][0]); \
    acc[2][0]=MFMA16(P##a2,P##b0,acc[2][0]); acc[3][0]=MFMA16(P##a3,P##b0,acc[3][0]); \
    acc[0][1]=MFMA16(P##a0,P##b1,acc[0][1]); acc[1][1]=MFMA16(P##a1,P##b1,acc[1][1]); \
    acc[2][1]=MFMA16(P##a2,P##b1,acc[2][1]); acc[3][1]=MFMA16(P##a3,P##b1,acc[3][1]); \
    acc[0][2]=MFMA16(P##a0,P##b2,acc[0][2]); acc[1][2]=MFMA16(P##a1,P##b2,acc[1][2]); \
    acc[2][2]=MFMA16(P##a2,P##b2,acc[2][2]); acc[3][2]=MFMA16(P##a3,P##b2,acc[3][2]); \
    acc[0][3]=MFMA16(P##a0,P##b3,acc[0][3]); acc[1][3]=MFMA16(P##a1,P##b3,acc[1][3]); \
    acc[2][3]=MFMA16(P##a2,P##b3,acc[2][3]); acc[3][3]=MFMA16(P##a3,P##b3,acc[3][3]); \
    acc[0][0]=MFMA16(P##a4,P##b4,acc[0][0]); acc[1][0]=MFMA16(P##a5,P##b4,acc[1][0]); \
    acc[2][0]=MFMA16(P##a6,P##b4,acc[2][0]); acc[3][0]=MFMA16(P##a7,P##b4,acc[3][0]); \
    acc[0][1]=MFMA16(P##a4,P##b5,acc[0][1]); acc[1][1]=MFMA16(P##a5,P##b5,acc[1][1]); \
    acc[2][1]=MFMA16(P##a6,P##b5,acc[2][1]); acc[3][1]=MFMA16(P##a7,P##b5,acc[3][1]); \
    acc[0][2]=MFMA16(P##a4,P##b6,acc[0][2]); acc[1][2]=MFMA16(P##a5,P##b6,acc[1][2]); \
    acc[2][2]=MFMA16(P##a6,P##b6,acc[2][2]); acc[3][2]=MFMA16(P##a7,P##b6,acc[3][2]); \
    acc[0][3]=MFMA16(P##a4,P##b7,acc[0][3]); acc[1][3]=MFMA16(P##a5,P##b7,acc[1][3]); \
    acc[2][3]=MFMA16(P##a6,P##b7,acc[2][3]); acc[3][3]=MFMA16(P##a7,P##b7,acc[3][3]); \
    __builtin_amdgcn_s_setprio(0); \
} while (0)

template<int MODE>
__global__ __launch_bounds__(512, 2)
void gemm_bt(const u16* __restrict__ A, const u16* __restrict__ Bw,
             void* __restrict__ Cv, const float* __restrict__ cstab) {
    __shared__ __align__(16) u16 As[2][8192];    // [2][128 rows][64]
    __shared__ __align__(16) u16 Bs[2][16384];   // [2][256 rows][64]
    const int t    = threadIdx.x;
    const int bm   = blockIdx.x << 7;
    const int bn   = blockIdx.y << 8;
    const int wave = t >> 6;
    const int wr   = (wave >> 2) & 1;
    const int wc   = wave & 3;
    const int lane = t & 63;
    const int fr   = lane & 15;
    const int kg   = lane >> 4;
    const int f7   = fr & 7;
    const int wq16 = wave << 9;
    const int K    = 1024;

    const int srow = t >> 3;
    const int cSw  = (t & 7) ^ (srow & 7);

    const u16* ga0 = A  + (size_t)(bm + srow) * K + (cSw << 3);
    const u16* ga1 = ga0 + (size_t)64 * K;
    const u16* gb0 = Bw + (size_t)(bn + srow) * K + (cSw << 3);
    const u16* gb1 = gb0 + (size_t)64 * K;
    const u16* gb2 = gb1 + (size_t)64 * K;
    const u16* gb3 = gb2 + (size_t)64 * K;

    f32x4 acc[4][4];
#pragma unroll
    for (int m = 0; m < 4; ++m)
#pragma unroll
        for (int n = 0; n < 4; ++n) acc[m][n] = f32x4{0.f, 0.f, 0.f, 0.f};

    FRAGS(X);
    FRAGS(Y);

#define STAGE(cur) do { \
    GL(ga0, &As[cur][wq16]);          GL(ga1, &As[cur][4096 + wq16]); \
    GL(gb0, &Bs[cur][wq16]);          GL(gb1, &Bs[cur][4096 + wq16]); \
    GL(gb2, &Bs[cur][8192 + wq16]);   GL(gb3, &Bs[cur][12288 + wq16]); \
    ga0 += 64; ga1 += 64; gb0 += 64; gb1 += 64; gb2 += 64; gb3 += 64; \
} while (0)

    const u32 ldsA = (u32)(size_t)(las_void*)&As[0][0];
    const u32 ldsB = (u32)(size_t)(las_void*)&Bs[0][0];
    const u32 arow = (u32)(((wr << 6) + fr) << 7);
    const u32 brow = (u32)(((wc << 6) + fr) << 7);
    const u32 ck0  = (u32)((kg ^ f7) << 4);
    const u32 ck1  = (u32)(((4 + kg) ^ f7) << 4);

    STAGE(0);
    VMW0();
    __builtin_amdgcn_s_barrier();
    LOADTILE(X, 0);
    STAGE(1);

#pragma unroll 1
    for (int j = 0; j < 16; j += 2) {
        LGKM0();
        VMW0();
        __builtin_amdgcn_s_barrier();
        if (j < 14) STAGE(0);
        LOADTILE(Y, 1);
        MFMA32(X);
        LGKM0();
        if (j < 14) {
            VMW0();
            __builtin_amdgcn_s_barrier();
            if (j < 13) STAGE(1);
            LOADTILE(X, 0);
        }
        MFMA32(Y);
    }

#undef STAGE

    // ---- epilogue ----
    if constexpr (MODE == 1) {
        const int sel   = bn >> 10;                        // 0=q,1=k,2=v
        const int bcol  = (bn & 1023) + (wc << 6) + fr;
        const int crow0 = bm + (wr << 6) + (kg << 2);
        if (sel == 2) {
            // V transposed: vt[((b*16+h)*64 + d)*4096 + s]
            u16* vt = (u16*)Cv + (size_t)16777216;
#pragma unroll
            for (int m = 0; m < 4; ++m) {
                const int row0 = crow0 + (m << 4);
                const int bb   = row0 >> 12;
                const int s0   = row0 & 4095;
#pragma unroll
                for (int n = 0; n < 4; ++n) {
                    u32x2 pk;
                    pk.x = (u32)f2bf(acc[m][n][0]) | ((u32)f2bf(acc[m][n][1]) << 16);
                    pk.y = (u32)f2bf(acc[m][n][2]) | ((u32)f2bf(acc[m][n][3]) << 16);
                    *(u32x2*)(vt + ((size_t)((bb << 10) + bcol + (n << 4))) * 4096 + s0) = pk;
                }
            }
        } else {
            // Q/K head-major: out[((b*16+h)*4096 + s)*64 + d], d = (bcol&63) + n*16
            u16* outb = (u16*)Cv + (size_t)sel * 8388608;
            const int hh = bcol >> 6;
            const int dd = bcol & 63;
#pragma unroll
            for (int m = 0; m < 4; ++m)
#pragma unroll
                for (int r = 0; r < 4; ++r) {
                    const int row = crow0 + (m << 4) + r;
                    float v0 = acc[m][0][r], v1 = acc[m][1][r], v2 = acc[m][2][r], v3 = acc[m][3][r];
                    const int s = row & (S_LEN - 1);
                    const f32x2 c0 = *(const f32x2*)(cstab + (((s << 5) + fr) << 1));
                    const f32x2 c1 = *(const f32x2*)(cstab + (((s << 5) + 16 + fr) << 1));
                    const float n0 = v0 * c0.x - v2 * c0.y;
                    const float n2 = v2 * c0.x + v0 * c0.y;
                    const float n1 = v1 * c1.x - v3 * c1.y;
                    const float n3 = v3 * c1.x + v1 * c1.y;
                    const int bb = row >> 12;
                    u16* op = outb + (((size_t)((bb << 4) + hh)) * 4096 + s) * 64 + dd;
                    op[0]  = f2bf(n0);
                    op[16] = f2bf(n1);
                    op[32] = f2bf(n2);
                    op[48] = f2bf(n3);
                }
        }
    } else {
        float* outf     = (float*)Cv;
        const int bcol  = bn + (wc << 6) + fr;
        const int crow0 = bm + (wr << 6) + (kg << 2);
#pragma unroll
        for (int m = 0; m < 4; ++m)
#pragma unroll
            for (int r = 0; r < 4; ++r) {
                const int row = crow0 + (m << 4) + r;
                float* op = outf + (size_t)row * 1024 + bcol;
                op[0]  = acc[m][0][r];
                op[16] = acc[m][1][r];
                op[32] = acc[m][2][r];
                op[48] = acc[m][3][r];
            }
    }
}

// ---------------- sliding-window attention, MFMA, head-major inputs ----------------
// Q,K: [b][h][s][64]; Vt: [b][h][d][s]. Block = (b, h, 64-query chunk), XCD-chunked
// swizzle so consecutive windows share an XCD L2. K window = contiguous 24 KB.
// OOB-window staging reads land in adjacent finite ws data; masked to P=0 before use.
__global__ __launch_bounds__(256)
void attn_kernel(const u16* __restrict__ Q, const u16* __restrict__ K,
                 const u16* __restrict__ Vt, u16* __restrict__ O) {
    __shared__ __align__(16) u16 Ks[192 * 64];   // 24 KB; reused as P[4][16][192]
    __shared__ __align__(16) u16 Vs[64 * 192];   // 24 KB
    const int bid0 = blockIdx.x;
    const int bid  = ((bid0 & 7) << 8) | (bid0 >> 3);   // XCD-chunked (2048 = 8*256, bijective)
    const int ch  = bid & 63;
    const int h   = (bid >> 6) & 15;
    const int b   = bid >> 10;
    const int qs  = ch << 6;
    const int t   = threadIdx.x;
    const int ub  = t & 192;                     // wave-uniform base (wave*64)

    const u16* kwin = K + ((size_t)((b << 4) + h) << 18);   // per-(b,h) K slice [4096][64]

    // ---- stage K: LDS[row][c] holds global chunk c^(row&7); window contiguous ----
#pragma unroll
    for (int i = 0; i < 6; ++i) {
        const int cid = (i << 8) + t;            // 0..1535
        const int row = cid >> 3;
        const int g   = (cid & 7) ^ (row & 7);
        const int kp  = qs - 64 + row;           // may be OOB: stays in-ws, masked later
        const u16* src = kwin + (long)kp * 64 + (g << 3);
        GL(src, &Ks[((i << 8) + ub) << 3]);
    }
    // ---- stage V^T: LDS[d][c] holds global chunk (c - (d&7)*3) mod 24 ----
#pragma unroll
    for (int i = 0; i < 6; ++i) {
        const int cid = (i << 8) + t;            // 0..1535
        const int d   = cid / 24;
        const int c   = cid - d * 24;
        int g = c - (d & 7) * 3;
        if (g < 0) g += 24;
        const int key = qs - 64 + (g << 3);
        const u16* src = Vt + ((size_t)((b << 10) + (h << 6) + d)) * 4096 + key;
        GL(src, &Vs[((i << 8) + ub) << 3]);
    }

    const int w    = t >> 6;
    const int lane = t & 63;
    const int fr   = lane & 15;
    const int kg   = lane >> 4;
    const int f7   = fr & 7;

    // Q head-major: contiguous per (b,h) slice
    const size_t qgoff = (((size_t)((b << 4) + h)) * 4096 + qs + (w << 4) + fr) * 64 + (kg << 3);
    const s16x8 qa0 = *(const s16x8*)(Q + qgoff);
    const s16x8 qa1 = *(const s16x8*)(Q + qgoff + 32);

    VMW0();
    __syncthreads();

    // ---- QK^T: 9 key fragments (window of 144 keys starting at w*16) ----
    f32x4 sfr[9];
#pragma unroll
    for (int n = 0; n < 9; ++n) {
        const int row = (w << 4) + (n << 4) + fr;          // row&7 == f7
        f32x4 a = f32x4{0.f, 0.f, 0.f, 0.f};
        const s16x8 kb0 = *(const s16x8*)(&Ks[(row << 6) + ((kg ^ f7) << 3)]);
        const s16x8 kb1 = *(const s16x8*)(&Ks[(row << 6) + (((4 + kg) ^ f7) << 3)]);
        a = MFMA16(qa0, kb0, a);
        a = MFMA16(qa1, kb1, a);
        sfr[n] = a;
    }

    // ---- mask + scale + wave-parallel softmax ----
    const float NEG = -__builtin_inff();
    float mx[4] = {NEG, NEG, NEG, NEG};
#pragma unroll
    for (int n = 0; n < 9; ++n) {
        const int j = (n << 4) + fr;
#pragma unroll
        for (int r = 0; r < 4; ++r) {
            const int q  = (kg << 2) + r;
            const int kp = qs - 64 + (w << 4) + j;
            const bool valid = (j >= q) && (j - q < 128) && (kp >= 0) && (kp < S_LEN);
            const float s = valid ? sfr[n][r] * 0.125f : NEG;
            sfr[n][r] = s;
            mx[r] = fmaxf(mx[r], s);
        }
    }
#pragma unroll
    for (int r = 0; r < 4; ++r) mx[r] = rmax16(mx[r]);
    float ls[4] = {0.f, 0.f, 0.f, 0.f};
#pragma unroll
    for (int n = 0; n < 9; ++n)
#pragma unroll
        for (int r = 0; r < 4; ++r) {
            const float p = __expf(sfr[n][r] - mx[r]);
            sfr[n][r] = p;
            ls[r] += p;
        }
#pragma unroll
    for (int r = 0; r < 4; ++r) ls[r] = rsum16(ls[r]);

    // ---- write P (bf16) into Ks buffer, swizzled; pad keys [144,160) with 0 ----
    __syncthreads();
    u16* Pw = Ks + w * 3072;                 // 16 rows x 192
#pragma unroll
    for (int n = 0; n < 9; ++n) {
        const int j = (n << 4) + fr;
#pragma unroll
        for (int r = 0; r < 4; ++r) {
            const int q = (kg << 2) + r;
            Pw[q * 192 + (((j >> 3) ^ (q & 7)) << 3) + (j & 7)] = f2bf(sfr[n][r]);
        }
    }
    {
        const int j = 144 + fr;
#pragma unroll
        for (int r = 0; r < 4; ++r) {
            const int q = (kg << 2) + r;
            Pw[q * 192 + (((j >> 3) ^ (q & 7)) << 3) + (j & 7)] = 0;
        }
    }
    __syncthreads();

    // ---- PV: P[16 x 160] * V[160 x 64] from Vs rows ----
    f32x4 o[4];
#pragma unroll
    for (int nf = 0; nf < 4; ++nf) o[nf] = f32x4{0.f, 0.f, 0.f, 0.f};
    const int cs0 = f7 * 3;
#pragma unroll
    for (int ks = 0; ks < 5; ++ks) {
        const s16x8 pa = *(const s16x8*)(&Pw[fr * 192 + ((((ks << 2) + kg) ^ f7) << 3)]);
        int c = (w << 1) + (ks << 2) + kg;
        if (c > 23) c = 23;                           // clamp: P==0 there
        int cs = c + cs0;
        if (cs >= 24) cs -= 24;
#pragma unroll
        for (int nf = 0; nf < 4; ++nf) {
            const int d = (nf << 4) + fr;             // d&7 == f7
            const s16x8 vbf = *(const s16x8*)(&Vs[d * 192 + (cs << 3)]);
            o[nf] = MFMA16(pa, vbf, o[nf]);
        }
    }

    // ---- normalize + store (O stays [b][s][1024] for the projection GEMM) ----
    const size_t obase = ((size_t)((b << 12) + qs + (w << 4) + (kg << 2))) * 1024 + (h << 6) + fr;
#pragma unroll
    for (int r = 0; r < 4; ++r) {
        const float inv = 1.f / ls[r];
#pragma unroll
        for (int nf = 0; nf < 4; ++nf)
            O[obase + (size_t)r * 1024 + (nf << 4)] = f2bf(o[nf][r] * inv);
    }
}

extern "C" void kernel_launch(void* const* d_in, const int* in_sizes, int n_in,
                              void* d_out, int out_size, void* d_ws, size_t ws_size,
                              hipStream_t stream) {
    const float* x  = (const float*)d_in[0];
    const float* fr = (const float*)d_in[1];
    const float* wq = (const float*)d_in[2];
    const float* wk = (const float*)d_in[3];
    const float* wv = (const float*)d_in[4];
    const float* wo = (const float*)d_in[5];

    u16* ws    = (u16*)d_ws;
    u16* xb    = ws;                       // 8388608
    u16* wqkvb = xb + 8388608;             // 3145728
    u16* wob   = wqkvb + 3145728;          // 1048576
    u16* qb    = wob + 1048576;            // 8388608 (head-major); kb, vtb follow
    u16* kb    = qb + 8388608;             // head-major [b][h][s][64]
    u16* vtb   = kb + 8388608;             // V transposed [b][h][d][s]
    float* cstab = (float*)(vtb + 8388608);
    u16* ob    = xb;                       // reuse xb after QKV GEMM

    prep_kernel<<<12800, 256, 0, stream>>>(x, wq, wk, wv, wo, fr, xb, wqkvb, wob, cstab);

    dim3 gqkv(64, 12);   // M/128 x 3072/256 = 768 blocks (3 full cohorts)
    gemm_bt<1><<<gqkv, 512, 0, stream>>>(xb, wqkvb, qb, cstab);

    attn_kernel<<<2048, 256, 0, stream>>>(qb, kb, vtb, ob);

    dim3 gout(64, 4);    // M/128 x 1024/256 = 256 blocks (1 full cohort)
    gemm_bt<2><<<gout, 512, 0, stream>>>(ob, wob, d_out, nullptr);
}

// Round 12
// 115.663 us; speedup vs baseline: 1.1991x; 1.0001x over previous
//
#include <hip/hip_runtime.h>

typedef unsigned short u16;
typedef unsigned int   u32;
typedef __attribute__((ext_vector_type(4))) unsigned int u32x4;
typedef __attribute__((ext_vector_type(2))) unsigned int u32x2;
typedef __attribute__((ext_vector_type(8))) short        s16x8;
typedef __attribute__((ext_vector_type(4))) float        f32x4;
typedef __attribute__((ext_vector_type(2))) float        f32x2;

#define S_LEN 4096

typedef const __attribute__((address_space(1))) void gas_void;
typedef __attribute__((address_space(3))) void las_void;

__device__ __forceinline__ u16 f2bf(float f) {
    u32 u = __builtin_bit_cast(u32, f);
    u32 r = (u + 0x7fffu + ((u >> 16) & 1u)) >> 16;
    return (u16)r;
}

__device__ __forceinline__ float rmax16(float v) {
    v = fmaxf(v, __shfl_xor(v, 1));
    v = fmaxf(v, __shfl_xor(v, 2));
    v = fmaxf(v, __shfl_xor(v, 4));
    v = fmaxf(v, __shfl_xor(v, 8));
    return v;
}
__device__ __forceinline__ float rsum16(float v) {
    v += __shfl_xor(v, 1);
    v += __shfl_xor(v, 2);
    v += __shfl_xor(v, 4);
    v += __shfl_xor(v, 8);
    return v;
}

// ---------------- fused prep: x->bf16 | weights->bf16 | rope cos/sin table ----------------
__global__ __launch_bounds__(256)
void prep_kernel(const float* __restrict__ x,
                 const float* __restrict__ wq, const float* __restrict__ wk,
                 const float* __restrict__ wv, const float* __restrict__ wo,
                 const float* __restrict__ freqs,
                 u16* __restrict__ xb, u16* __restrict__ wqkv, u16* __restrict__ wob,
                 float* __restrict__ tab) {
    const int bid = blockIdx.x;
    const int t   = threadIdx.x;
    if (bid < 8192) {
        const int i = bid * 256 + t;
        const f32x4 v = *(const f32x4*)(x + (size_t)i * 4);
        u32x2 o;
        o.x = (u32)f2bf(v.x) | ((u32)f2bf(v.y) << 16);
        o.y = (u32)f2bf(v.z) | ((u32)f2bf(v.w) << 16);
        *(u32x2*)(xb + (size_t)i * 4) = o;
    } else if (bid < 12288) {
        const int i   = (bid - 8192) * 256 + t;
        const int sel = i >> 18;
        const int loc = i & 262143;
        const float* src = (sel == 0) ? wq : (sel == 1) ? wk : (sel == 2) ? wv : wo;
        u16* dst = (sel < 3) ? (wqkv + (size_t)sel * 1048576) : wob;
        const f32x4 v = *(const f32x4*)(src + (size_t)loc * 4);
        u32x2 o;
        o.x = (u32)f2bf(v.x) | ((u32)f2bf(v.y) << 16);
        o.y = (u32)f2bf(v.z) | ((u32)f2bf(v.w) << 16);
        *(u32x2*)(dst + (size_t)loc * 4) = o;
    } else {
        const int i = (bid - 12288) * 256 + t;
        const float f = freqs[i];
        float sn, cs;
        sincosf(f, &sn, &cs);
        tab[i * 2]     = cs;
        tab[i * 2 + 1] = sn;
    }
}

#define VMW(n) asm volatile("s_waitcnt vmcnt(" #n ")" ::: "memory")
#define VMW0() asm volatile("s_waitcnt vmcnt(0)" ::: "memory")
#define LGKM0() do { asm volatile("s_waitcnt lgkmcnt(0)" ::: "memory"); \
                     __builtin_amdgcn_sched_barrier(0); } while (0)
#define DSR0(d, a)   asm volatile("ds_read_b128 %0, %1"              : "=v"(d) : "v"(a))
#define DSR(d, a, o) asm volatile("ds_read_b128 %0, %1 offset:" #o   : "=v"(d) : "v"(a))
#define MFMA16(a, b, c) __builtin_amdgcn_mfma_f32_16x16x32_bf16(a, b, c, 0, 0, 0)
#define GL(p, d) __builtin_amdgcn_global_load_lds((gas_void*)(p), (las_void*)(d), 16, 0, 0)

// =====================================================================
// QKV GEMM: C[8192,3072] = A[8192,1024] * B[3072,1024]^T
// BM=128, BN=256, BK=32, 256 thr (4 waves: wr=wave>>1, wc=wave&1),
// wave tile 64x128 (4 m-frags x 8 n-frags), 48 KB LDS -> 2 blocks/CU:
// cross-block overlap replaces intra-block phase staggering.
// Per K-tile: 2 phases x 16 MFMA; reads 8 / 4; stages 4 / 2 gload_lds;
// counted waits VMW(4) at p0-end, VMW(2) at tile-end (0 only last tile).
// Epilogue: Q,K head-major [b][h][s][64] + RoPE on f32 acc; V^T [b][h][d][s].
// =====================================================================
__global__ __launch_bounds__(256, 2)
void gemm_qkv(const u16* __restrict__ A, const u16* __restrict__ Bw,
              void* __restrict__ Cv, const float* __restrict__ cstab) {
    __shared__ __align__(16) u16 As[2][4096];   // [2][128 rows][32]
    __shared__ __align__(16) u16 Bs[2][8192];   // [2][256 rows][32]
    const int t    = threadIdx.x;
    const int bm   = blockIdx.x << 7;
    const int bn   = blockIdx.y << 8;
    const int wave = t >> 6;
    const int wr   = (wave >> 1) & 1;
    const int wc   = wave & 1;
    const int lane = t & 63;
    const int fr   = lane & 15;
    const int kg   = lane >> 4;
    const int wq16 = wave << 9;                 // wave segment in each GL region
    const int K    = 1024;

    const int srow = t >> 2;                    // 0..63 rows per gload
    const int cg   = (t & 3) ^ ((srow >> 1) & 3);   // inverse-swizzled source chunk

    const u16* ga0 = A  + (size_t)(bm + srow) * K + (cg << 3);
    const u16* ga1 = ga0 + (size_t)64 * K;
    const u16* gb0 = Bw + (size_t)(bn + srow) * K + (cg << 3);
    const u16* gb1 = gb0 + (size_t)64 * K;
    const u16* gb2 = gb0 + (size_t)128 * K;
    const u16* gb3 = gb0 + (size_t)192 * K;

    f32x4 acc[4][8];
#pragma unroll
    for (int m = 0; m < 4; ++m)
#pragma unroll
        for (int n = 0; n < 8; ++n) acc[m][n] = f32x4{0.f, 0.f, 0.f, 0.f};
    s16x8 af0, af1, af2, af3, bf0, bf1, bf2, bf3;

#define SGA(S)   do { GL(ga0, &As[S][wq16]); GL(ga1, &As[S][2048 + wq16]); } while (0)
#define SGB13(S) do { GL(gb0, &Bs[S][wq16]); GL(gb2, &Bs[S][4096 + wq16]); } while (0)
#define SGB24(S) do { GL(gb1, &Bs[S][2048 + wq16]); GL(gb3, &Bs[S][6144 + wq16]); \
    ga0 += 32; ga1 += 32; gb0 += 32; gb1 += 32; gb2 += 32; gb3 += 32; } while (0)

#define MF16(NB) do { \
    acc[0][NB+0]=MFMA16(af0,bf0,acc[0][NB+0]); acc[1][NB+0]=MFMA16(af1,bf0,acc[1][NB+0]); \
    acc[2][NB+0]=MFMA16(af2,bf0,acc[2][NB+0]); acc[3][NB+0]=MFMA16(af3,bf0,acc[3][NB+0]); \
    acc[0][NB+1]=MFMA16(af0,bf1,acc[0][NB+1]); acc[1][NB+1]=MFMA16(af1,bf1,acc[1][NB+1]); \
    acc[2][NB+1]=MFMA16(af2,bf1,acc[2][NB+1]); acc[3][NB+1]=MFMA16(af3,bf1,acc[3][NB+1]); \
    acc[0][NB+2]=MFMA16(af0,bf2,acc[0][NB+2]); acc[1][NB+2]=MFMA16(af1,bf2,acc[1][NB+2]); \
    acc[2][NB+2]=MFMA16(af2,bf2,acc[2][NB+2]); acc[3][NB+2]=MFMA16(af3,bf2,acc[3][NB+2]); \
    acc[0][NB+3]=MFMA16(af0,bf3,acc[0][NB+3]); acc[1][NB+3]=MFMA16(af1,bf3,acc[1][NB+3]); \
    acc[2][NB+3]=MFMA16(af2,bf3,acc[2][NB+3]); acc[3][NB+3]=MFMA16(af3,bf3,acc[3][NB+3]); \
} while (0)

    const u32 ldsA = (u32)(size_t)(las_void*)&As[0][0];
    const u32 ldsB = (u32)(size_t)(las_void*)&Bs[0][0];
    const u32 ckq  = (u32)((kg ^ ((fr >> 1) & 3)) << 4);
    const u32 aRow = (u32)(((wr << 6) + fr) << 6) + ckq;    // row*64B + chunk
    const u32 bRow = (u32)(((wc << 7) + fr) << 6) + ckq;

// one K-tile: 2 phases. SON = staging enabled (tile+1 exists).
#define QT(CUR, STG, SON) do { \
    const u32 aB = ldsA + (CUR) * 8192u + aRow; \
    const u32 bB = ldsB + (CUR) * 16384u + bRow; \
    DSR0(af0, aB); DSR(af1, aB, 1024); DSR(af2, aB, 2048); DSR(af3, aB, 3072); \
    DSR0(bf0, bB); DSR(bf1, bB, 1024); DSR(bf2, bB, 2048); DSR(bf3, bB, 3072); \
    if (SON) { SGA(STG); SGB13(STG); } \
    __builtin_amdgcn_s_barrier(); \
    LGKM0(); \
    __builtin_amdgcn_s_setprio(1); MF16(0); __builtin_amdgcn_s_setprio(0); \
    if (SON) VMW(4); else VMW0(); \
    __builtin_amdgcn_s_barrier(); \
    DSR(bf0, bB, 4096); DSR(bf1, bB, 5120); DSR(bf2, bB, 6144); DSR(bf3, bB, 7168); \
    if (SON) SGB24(STG); \
    __builtin_amdgcn_s_barrier(); \
    LGKM0(); \
    __builtin_amdgcn_s_setprio(1); MF16(4); __builtin_amdgcn_s_setprio(0); \
    if (SON) VMW(2); \
    __builtin_amdgcn_s_barrier(); \
} while (0)

    // prologue: stage tile 0 (A12, B13, B24); certify A12+B13 only (counted)
    SGA(0); SGB13(0); SGB24(0);
    VMW(2);
    __builtin_amdgcn_s_barrier();

#pragma unroll 1
    for (int jj = 0; jj < 15; ++jj) {   // tiles 0..29
        QT(0, 1, 1);
        QT(1, 0, 1);
    }
    QT(0, 1, 1);    // tile 30 (stages tile 31)
    QT(1, 0, 0);    // tile 31 (final: VMW(0) at p0, no staging)

#undef QT
#undef SGA
#undef SGB13
#undef SGB24
#undef MF16

    // ---- epilogue ----
    const int sel   = bn >> 10;                        // 0=q,1=k,2=v
    const int bcol  = (bn & 1023) + (wc << 7);
    const int crow0 = bm + (wr << 6) + (kg << 2);
    if (sel == 2) {
        // V transposed: vt[((b*16+h)*64 + d)*4096 + s], r-quad packed
        u16* vt = (u16*)Cv + (size_t)16777216;
#pragma unroll
        for (int m = 0; m < 4; ++m) {
            const int row0 = crow0 + (m << 4);
            const int bb   = row0 >> 12;
            const int s0   = row0 & 4095;
#pragma unroll
            for (int nf = 0; nf < 8; ++nf) {
                const int col = bcol + (nf << 4) + fr;
                const int hh  = col >> 6;
                const int d   = col & 63;
                u32x2 pk;
                pk.x = (u32)f2bf(acc[m][nf][0]) | ((u32)f2bf(acc[m][nf][1]) << 16);
                pk.y = (u32)f2bf(acc[m][nf][2]) | ((u32)f2bf(acc[m][nf][3]) << 16);
                *(u32x2*)(vt + ((size_t)((bb << 4) + hh) * 64 + d) * 4096 + s0) = pk;
            }
        }
    } else {
        // Q/K head-major [b][h][s][64] with RoPE.
        // Wave band covers heads hb (nf 0..3) and hb+1 (nf 4..7);
        // RoPE pairs within a head: (nf, nf+2) -> dims (d, d+32).
        u16* outb = (u16*)Cv + (size_t)sel * 8388608;
        const int hb = bcol >> 6;
#pragma unroll
        for (int m = 0; m < 4; ++m)
#pragma unroll
            for (int r = 0; r < 4; ++r) {
                const int row = crow0 + (m << 4) + r;
                const int s   = row & 4095;
                const int bb  = row >> 12;
                const f32x2 c0 = *(const f32x2*)(cstab + (((s << 5) + fr) << 1));
                const f32x2 c1 = *(const f32x2*)(cstab + (((s << 5) + 16 + fr) << 1));
#pragma unroll
                for (int g = 0; g < 2; ++g) {          // g=0: head hb (nf 0..3); g=1: head hb+1 (nf 4..7)
                    u16* qp = outb + ((size_t)((bb << 4) + hb + g) * 4096 + s) * 64;
                    {   // pair (4g, 4g+2): dims (fr, fr+32), trig c0
                        const float lo = acc[m][(g << 2) + 0][r];
                        const float hi = acc[m][(g << 2) + 2][r];
                        qp[fr]      = f2bf(lo * c0.x - hi * c0.y);
                        qp[32 + fr] = f2bf(hi * c0.x + lo * c0.y);
                    }
                    {   // pair (4g+1, 4g+3): dims (16+fr, 48+fr), trig c1
                        const float lo = acc[m][(g << 2) + 1][r];
                        const float hi = acc[m][(g << 2) + 3][r];
                        qp[16 + fr] = f2bf(lo * c1.x - hi * c1.y);
                        qp[48 + fr] = f2bf(hi * c1.x + lo * c1.y);
                    }
                }
            }
    }
}

// =====================================================================
// Output-projection GEMM (round-6 verified structure, f32 out).
// BM=128, BN=256, BK=64, 512 thr, one barrier per K-tile.
// =====================================================================
#define FRAGS(P) s16x8 P##a0,P##a1,P##a2,P##a3,P##a4,P##a5,P##a6,P##a7, \
                       P##b0,P##b1,P##b2,P##b3,P##b4,P##b5,P##b6,P##b7

#define LOADTILE(P, CUR) do { \
    const u32 abase_ = ldsA + ((u32)(CUR) << 14) + arow; \
    const u32 bbase_ = ldsB + ((u32)(CUR) << 15) + brow; \
    const u32 aa0_ = abase_ + ck0, aa1_ = abase_ + ck1; \
    const u32 ba0_ = bbase_ + ck0, ba1_ = bbase_ + ck1; \
    DSR0(P##a0, aa0_); DSR(P##a1, aa0_, 2048); DSR(P##a2, aa0_, 4096); DSR(P##a3, aa0_, 6144); \
    DSR0(P##a4, aa1_); DSR(P##a5, aa1_, 2048); DSR(P##a6, aa1_, 4096); DSR(P##a7, aa1_, 6144); \
    DSR0(P##b0, ba0_); DSR(P##b1, ba0_, 2048); DSR(P##b2, ba0_, 4096); DSR(P##b3, ba0_, 6144); \
    DSR0(P##b4, ba1_); DSR(P##b5, ba1_, 2048); DSR(P##b6, ba1_, 4096); DSR(P##b7, ba1_, 6144); \
} while (0)

#define MFMA32(P) do { \
    __builtin_amdgcn_s_setprio(1); \
    acc[0][0]=MFMA16(P##a0,P##b0,acc[0][0]); acc[1][0]=MFMA16(P##a1,P##b0,acc[1][0]); \
    acc[2][0]=MFMA16(P##a2,P##b0,acc[2][0]); acc[3][0]=MFMA16(P##a3,P##b0,acc[3][0]); \
    acc[0][1]=MFMA16(P##a0,P##b1,acc[0][1]); acc[1][1]=MFMA16(P##a1,P##b1,acc[1][1]); \
    acc[2][1]=MFMA16(P##a2,P##b1,acc[2][1]); acc[3][1]=MFMA16(P##a3,P##b1,acc[3][1]); \
    acc[0][2]=MFMA16(P##a0,P##b2,acc[0][2]); acc[1][2]=MFMA16(P##a1,P##b2,acc[1][2]); \
    acc[2][2]=MFMA16(P##a2,P##b2,acc[2][2]); acc[3][2]=MFMA16(P##a3,P##b2,acc[3][2]); \
    acc[0][3]=MFMA16(P##a0,P##b3,acc[0][3]); acc[1][3]=MFMA16(P##a1,P##b3,acc[1][3]); \
    acc[2][3]=MFMA16(P##a2,P##b3,acc[2][3]); acc[3][3]=MFMA16(P##a3,P##b3,acc[3][3]); \
    acc[0][0]=MFMA16(P##a4,P##b4,acc[0][0]); acc[1][0]=MFMA16(P##a5,P##b4,acc[1][0]); \
    acc[2][0]=MFMA16(P##a6,P##b4,acc[2][0]); acc[3][0]=MFMA16(P##a7,P##b4,acc[3][0]); \
    acc[0][1]=MFMA16(P##a4,P##b5,acc[0][1]); acc[1][1]=MFMA16(P##a5,P##b5,acc[1][1]); \
    acc[2][1]=MFMA16(P##a6,P##b5,acc[2][1]); acc[3][1]=MFMA16(P##a7,P##b5,acc[3][1]); \
    acc[0][2]=MFMA16(P##a4,P##b6,acc[0][2]); acc[1][2]=MFMA16(P##a5,P##b6,acc[1][2]); \
    acc[2][2]=MFMA16(P##a6,P##b6,acc[2][2]); acc[3][2]=MFMA16(P##a7,P##b6,acc[3][2]); \
    acc[0][3]=MFMA16(P##a4,P##b7,acc[0][3]); acc[1][3]=MFMA16(P##a5,P##b7,acc[1][3]); \
    acc[2][3]=MFMA16(P##a6,P##b7,acc[2][3]); acc[3][3]=MFMA16(P##a7,P##b7,acc[3][3]); \
    __builtin_amdgcn_s_setprio(0); \
} while (0)

__global__ __launch_bounds__(512, 2)
void gemm_out(const u16* __restrict__ A, const u16* __restrict__ Bw,
              float* __restrict__ Cv) {
    __shared__ __align__(16) u16 As[2][8192];
    __shared__ __align__(16) u16 Bs[2][16384];
    const int t    = threadIdx.x;
    const int bm   = blockIdx.x << 7;
    const int bn   = blockIdx.y << 8;
    const int wave = t >> 6;
    const int wr   = (wave >> 2) & 1;
    const int wc   = wave & 3;
    const int lane = t & 63;
    const int fr   = lane & 15;
    const int kg   = lane >> 4;
    const int f7   = fr & 7;
    const int wq16 = wave << 9;
    const int K    = 1024;

    const int srow = t >> 3;
    const int cSw  = (t & 7) ^ (srow & 7);

    const u16* ga0 = A  + (size_t)(bm + srow) * K + (cSw << 3);
    const u16* ga1 = ga0 + (size_t)64 * K;
    const u16* gb0 = Bw + (size_t)(bn + srow) * K + (cSw << 3);
    const u16* gb1 = gb0 + (size_t)64 * K;
    const u16* gb2 = gb1 + (size_t)64 * K;
    const u16* gb3 = gb2 + (size_t)64 * K;

    f32x4 acc[4][4];
#pragma unroll
    for (int m = 0; m < 4; ++m)
#pragma unroll
        for (int n = 0; n < 4; ++n) acc[m][n] = f32x4{0.f, 0.f, 0.f, 0.f};

    FRAGS(X);
    FRAGS(Y);

#define STAGE(cur) do { \
    GL(ga0, &As[cur][wq16]);          GL(ga1, &As[cur][4096 + wq16]); \
    GL(gb0, &Bs[cur][wq16]);          GL(gb1, &Bs[cur][4096 + wq16]); \
    GL(gb2, &Bs[cur][8192 + wq16]);   GL(gb3, &Bs[cur][12288 + wq16]); \
    ga0 += 64; ga1 += 64; gb0 += 64; gb1 += 64; gb2 += 64; gb3 += 64; \
} while (0)

    const u32 ldsA = (u32)(size_t)(las_void*)&As[0][0];
    const u32 ldsB = (u32)(size_t)(las_void*)&Bs[0][0];
    const u32 arow = (u32)(((wr << 6) + fr) << 7);
    const u32 brow = (u32)(((wc << 6) + fr) << 7);
    const u32 ck0  = (u32)((kg ^ f7) << 4);
    const u32 ck1  = (u32)(((4 + kg) ^ f7) << 4);

    STAGE(0);
    VMW0();
    __builtin_amdgcn_s_barrier();
    LOADTILE(X, 0);
    STAGE(1);

#pragma unroll 1
    for (int j = 0; j < 16; j += 2) {
        LGKM0();
        VMW0();
        __builtin_amdgcn_s_barrier();
        if (j < 14) STAGE(0);
        LOADTILE(Y, 1);
        MFMA32(X);
        LGKM0();
        if (j < 14) {
            VMW0();
            __builtin_amdgcn_s_barrier();
            if (j < 13) STAGE(1);
            LOADTILE(X, 0);
        }
        MFMA32(Y);
    }
#undef STAGE

    const int bcol  = bn + (wc << 6) + fr;
    const int crow0 = bm + (wr << 6) + (kg << 2);
#pragma unroll
    for (int m = 0; m < 4; ++m)
#pragma unroll
        for (int r = 0; r < 4; ++r) {
            const int row = crow0 + (m << 4) + r;
            float* op = Cv + (size_t)row * 1024 + bcol;
            op[0]  = acc[m][0][r];
            op[16] = acc[m][1][r];
            op[32] = acc[m][2][r];
            op[48] = acc[m][3][r];
        }
}

// ---------------- sliding-window attention, MFMA, head-major inputs ----------------
__global__ __launch_bounds__(256)
void attn_kernel(const u16* __restrict__ Q, const u16* __restrict__ K,
                 const u16* __restrict__ Vt, u16* __restrict__ O) {
    __shared__ __align__(16) u16 Ks[192 * 64];
    __shared__ __align__(16) u16 Vs[64 * 192];
    const int bid0 = blockIdx.x;
    const int bid  = ((bid0 & 7) << 8) | (bid0 >> 3);
    const int ch  = bid & 63;
    const int h   = (bid >> 6) & 15;
    const int b   = bid >> 10;
    const int qs  = ch << 6;
    const int t   = threadIdx.x;
    const int ub  = t & 192;

    const u16* kwin = K + ((size_t)((b << 4) + h) << 18);

#pragma unroll
    for (int i = 0; i < 6; ++i) {
        const int cid = (i << 8) + t;
        const int row = cid >> 3;
        const int g   = (cid & 7) ^ (row & 7);
        const int kp  = qs - 64 + row;
        const u16* src = kwin + (long)kp * 64 + (g << 3);
        GL(src, &Ks[((i << 8) + ub) << 3]);
    }
#pragma unroll
    for (int i = 0; i < 6; ++i) {
        const int cid = (i << 8) + t;
        const int d   = cid / 24;
        const int c   = cid - d * 24;
        int g = c - (d & 7) * 3;
        if (g < 0) g += 24;
        const int key = qs - 64 + (g << 3);
        const u16* src = Vt + ((size_t)((b << 10) + (h << 6) + d)) * 4096 + key;
        GL(src, &Vs[((i << 8) + ub) << 3]);
    }

    const int w    = t >> 6;
    const int lane = t & 63;
    const int fr   = lane & 15;
    const int kg   = lane >> 4;
    const int f7   = fr & 7;

    const size_t qgoff = (((size_t)((b << 4) + h)) * 4096 + qs + (w << 4) + fr) * 64 + (kg << 3);
    const s16x8 qa0 = *(const s16x8*)(Q + qgoff);
    const s16x8 qa1 = *(const s16x8*)(Q + qgoff + 32);

    VMW0();
    __syncthreads();

    f32x4 sfr[9];
#pragma unroll
    for (int n = 0; n < 9; ++n) {
        const int row = (w << 4) + (n << 4) + fr;
        f32x4 a = f32x4{0.f, 0.f, 0.f, 0.f};
        const s16x8 kb0 = *(const s16x8*)(&Ks[(row << 6) + ((kg ^ f7) << 3)]);
        const s16x8 kb1 = *(const s16x8*)(&Ks[(row << 6) + (((4 + kg) ^ f7) << 3)]);
        a = MFMA16(qa0, kb0, a);
        a = MFMA16(qa1, kb1, a);
        sfr[n] = a;
    }

    const float NEG = -__builtin_inff();
    float mx[4] = {NEG, NEG, NEG, NEG};
#pragma unroll
    for (int n = 0; n < 9; ++n) {
        const int j = (n << 4) + fr;
#pragma unroll
        for (int r = 0; r < 4; ++r) {
            const int q  = (kg << 2) + r;
            const int kp = qs - 64 + (w << 4) + j;
            const bool valid = (j >= q) && (j - q < 128) && (kp >= 0) && (kp < S_LEN);
            const float s = valid ? sfr[n][r] * 0.125f : NEG;
            sfr[n][r] = s;
            mx[r] = fmaxf(mx[r], s);
        }
    }
#pragma unroll
    for (int r = 0; r < 4; ++r) mx[r] = rmax16(mx[r]);
    float ls[4] = {0.f, 0.f, 0.f, 0.f};
#pragma unroll
    for (int n = 0; n < 9; ++n)
#pragma unroll
        for (int r = 0; r < 4; ++r) {
            const float p = __expf(sfr[n][r] - mx[r]);
            sfr[n][r] = p;
            ls[r] += p;
        }
#pragma unroll
    for (int r = 0; r < 4; ++r) ls[r] = rsum16(ls[r]);

    __syncthreads();
    u16* Pw = Ks + w * 3072;
#pragma unroll
    for (int n = 0; n < 9; ++n) {
        const int j = (n << 4) + fr;
#pragma unroll
        for (int r = 0; r < 4; ++r) {
            const int q = (kg << 2) + r;
            Pw[q * 192 + (((j >> 3) ^ (q & 7)) << 3) + (j & 7)] = f2bf(sfr[n][r]);
        }
    }
    {
        const int j = 144 + fr;
#pragma unroll
        for (int r = 0; r < 4; ++r) {
            const int q = (kg << 2) + r;
            Pw[q * 192 + (((j >> 3) ^ (q & 7)) << 3) + (j & 7)] = 0;
        }
    }
    __syncthreads();

    f32x4 o[4];
#pragma unroll
    for (int nf = 0; nf < 4; ++nf) o[nf] = f32x4{0.f, 0.f, 0.f, 0.f};
    const int cs0 = f7 * 3;
#pragma unroll
    for (int ks = 0; ks < 5; ++ks) {
        const s16x8 pa = *(const s16x8*)(&Pw[fr * 192 + ((((ks << 2) + kg) ^ f7) << 3)]);
        int c = (w << 1) + (ks << 2) + kg;
        if (c > 23) c = 23;
        int cs = c + cs0;
        if (cs >= 24) cs -= 24;
#pragma unroll
        for (int nf = 0; nf < 4; ++nf) {
            const int d = (nf << 4) + fr;
            const s16x8 vbf = *(const s16x8*)(&Vs[d * 192 + (cs << 3)]);
            o[nf] = MFMA16(pa, vbf, o[nf]);
        }
    }

    const size_t obase = ((size_t)((b << 12) + qs + (w << 4) + (kg << 2))) * 1024 + (h << 6) + fr;
#pragma unroll
    for (int r = 0; r < 4; ++r) {
        const float inv = 1.f / ls[r];
#pragma unroll
        for (int nf = 0; nf < 4; ++nf)
            O[obase + (size_t)r * 1024 + (nf << 4)] = f2bf(o[nf][r] * inv);
    }
}

extern "C" void kernel_launch(void* const* d_in, const int* in_sizes, int n_in,
                              void* d_out, int out_size, void* d_ws, size_t ws_size,
                              hipStream_t stream) {
    const float* x  = (const float*)d_in[0];
    const float* fr = (const float*)d_in[1];
    const float* wq = (const float*)d_in[2];
    const float* wk = (const float*)d_in[3];
    const float* wv = (const float*)d_in[4];
    const float* wo = (const float*)d_in[5];

    u16* ws    = (u16*)d_ws;
    u16* xb    = ws;                       // 8388608
    u16* wqkvb = xb + 8388608;             // 3145728
    u16* wob   = wqkvb + 3145728;          // 1048576
    u16* qb    = wob + 1048576;            // Q head-major; K, V^T follow
    u16* kb    = qb + 8388608;
    u16* vtb   = kb + 8388608;
    float* cstab = (float*)(vtb + 8388608);
    u16* ob    = xb;                       // reuse xb after QKV GEMM

    prep_kernel<<<12800, 256, 0, stream>>>(x, wq, wk, wv, wo, fr, xb, wqkvb, wob, cstab);

    dim3 gqkv(64, 12);   // 128x256 tiles -> 768 blocks, 2 resident/CU, 3 total/CU
    gemm_qkv<<<gqkv, 256, 0, stream>>>(xb, wqkvb, qb, cstab);

    attn_kernel<<<2048, 256, 0, stream>>>(qb, kb, vtb, ob);

    dim3 gout(64, 4);    // round-6 structure, 256 blocks
    gemm_out<<<gout, 512, 0, stream>>>(ob, wob, (float*)d_out);
}

// Round 13
// 115.394 us; speedup vs baseline: 1.2019x; 1.0023x over previous
//
#include <hip/hip_runtime.h>

typedef unsigned short u16;
typedef unsigned int   u32;
typedef __attribute__((ext_vector_type(4))) unsigned int u32x4;
typedef __attribute__((ext_vector_type(2))) unsigned int u32x2;
typedef __attribute__((ext_vector_type(8))) short        s16x8;
typedef __attribute__((ext_vector_type(4))) float        f32x4;
typedef __attribute__((ext_vector_type(2))) float        f32x2;

#define S_LEN 4096

typedef const __attribute__((address_space(1))) void gas_void;
typedef __attribute__((address_space(3))) void las_void;

__device__ __forceinline__ u16 f2bf(float f) {
    u32 u = __builtin_bit_cast(u32, f);
    u32 r = (u + 0x7fffu + ((u >> 16) & 1u)) >> 16;
    return (u16)r;
}

__device__ __forceinline__ float rmax16(float v) {
    v = fmaxf(v, __shfl_xor(v, 1));
    v = fmaxf(v, __shfl_xor(v, 2));
    v = fmaxf(v, __shfl_xor(v, 4));
    v = fmaxf(v, __shfl_xor(v, 8));
    return v;
}
__device__ __forceinline__ float rsum16(float v) {
    v += __shfl_xor(v, 1);
    v += __shfl_xor(v, 2);
    v += __shfl_xor(v, 4);
    v += __shfl_xor(v, 8);
    return v;
}

// ---------------- fused prep: x->bf16 | weights->bf16 | rope cos/sin table ----------------
__global__ __launch_bounds__(256)
void prep_kernel(const float* __restrict__ x,
                 const float* __restrict__ wq, const float* __restrict__ wk,
                 const float* __restrict__ wv, const float* __restrict__ wo,
                 const float* __restrict__ freqs,
                 u16* __restrict__ xb, u16* __restrict__ wqkv, u16* __restrict__ wob,
                 float* __restrict__ tab) {
    const int bid = blockIdx.x;
    const int t   = threadIdx.x;
    if (bid < 8192) {
        const int i = bid * 256 + t;
        const f32x4 v = *(const f32x4*)(x + (size_t)i * 4);
        u32x2 o;
        o.x = (u32)f2bf(v.x) | ((u32)f2bf(v.y) << 16);
        o.y = (u32)f2bf(v.z) | ((u32)f2bf(v.w) << 16);
        *(u32x2*)(xb + (size_t)i * 4) = o;
    } else if (bid < 12288) {
        const int i   = (bid - 8192) * 256 + t;
        const int sel = i >> 18;
        const int loc = i & 262143;
        const float* src = (sel == 0) ? wq : (sel == 1) ? wk : (sel == 2) ? wv : wo;
        u16* dst = (sel < 3) ? (wqkv + (size_t)sel * 1048576) : wob;
        const f32x4 v = *(const f32x4*)(src + (size_t)loc * 4);
        u32x2 o;
        o.x = (u32)f2bf(v.x) | ((u32)f2bf(v.y) << 16);
        o.y = (u32)f2bf(v.z) | ((u32)f2bf(v.w) << 16);
        *(u32x2*)(dst + (size_t)loc * 4) = o;
    } else {
        const int i = (bid - 12288) * 256 + t;
        const float f = freqs[i];
        float sn, cs;
        sincosf(f, &sn, &cs);
        tab[i * 2]     = cs;
        tab[i * 2 + 1] = sn;
    }
}

#define VMW(n) asm volatile("s_waitcnt vmcnt(" #n ")" ::: "memory")
#define VMW0() asm volatile("s_waitcnt vmcnt(0)" ::: "memory")
#define LGKM0() do { asm volatile("s_waitcnt lgkmcnt(0)" ::: "memory"); \
                     __builtin_amdgcn_sched_barrier(0); } while (0)
#define DSR0(d, a)   asm volatile("ds_read_b128 %0, %1"              : "=v"(d) : "v"(a))
#define DSR(d, a, o) asm volatile("ds_read_b128 %0, %1 offset:" #o   : "=v"(d) : "v"(a))
#define MFMA16(a, b, c) __builtin_amdgcn_mfma_f32_16x16x32_bf16(a, b, c, 0, 0, 0)
#define GL(p, d) __builtin_amdgcn_global_load_lds((gas_void*)(p), (las_void*)(d), 16, 0, 0)

// =====================================================================
// QKV GEMM: C[8192,3072] = A[8192,1024] * B[3072,1024]^T
// BM=128, BN=256, BK=32, 256 thr (4 waves), wave tile 64x128,
// 48 KB LDS -> 2 blocks/CU. ANTI-PHASE STAGGER: co-resident blocks are
// offset ~half a K-tile via one s_sleep so one block's MFMA burst
// overlaps the other's LDS drain (breaks the shared-LDS-FIFO phase lock).
// Epilogue: Q,K head-major [b][h][s][64] + RoPE on f32 acc; V^T [b][h][d][s].
// =====================================================================
__global__ __launch_bounds__(256, 2)
void gemm_qkv(const u16* __restrict__ A, const u16* __restrict__ Bw,
              void* __restrict__ Cv, const float* __restrict__ cstab) {
    __shared__ __align__(16) u16 As[2][4096];   // [2][128 rows][32]
    __shared__ __align__(16) u16 Bs[2][8192];   // [2][256 rows][32]
    const int t    = threadIdx.x;
    const int bm   = blockIdx.x << 7;
    const int bn   = blockIdx.y << 8;
    const int wave = t >> 6;
    const int wr   = (wave >> 1) & 1;
    const int wc   = wave & 1;
    const int lane = t & 63;
    const int fr   = lane & 15;
    const int kg   = lane >> 4;
    const int wq16 = wave << 9;                 // wave segment in each GL region
    const int K    = 1024;

    const int srow = t >> 2;                    // 0..63 rows per gload
    const int cg   = (t & 3) ^ ((srow >> 1) & 3);   // inverse-swizzled source chunk

    const u16* ga0 = A  + (size_t)(bm + srow) * K + (cg << 3);
    const u16* ga1 = ga0 + (size_t)64 * K;
    const u16* gb0 = Bw + (size_t)(bn + srow) * K + (cg << 3);
    const u16* gb1 = gb0 + (size_t)64 * K;
    const u16* gb2 = gb0 + (size_t)128 * K;
    const u16* gb3 = gb0 + (size_t)192 * K;

    f32x4 acc[4][8];
#pragma unroll
    for (int m = 0; m < 4; ++m)
#pragma unroll
        for (int n = 0; n < 8; ++n) acc[m][n] = f32x4{0.f, 0.f, 0.f, 0.f};
    s16x8 af0, af1, af2, af3, bf0, bf1, bf2, bf3;

#define SGA(S)   do { GL(ga0, &As[S][wq16]); GL(ga1, &As[S][2048 + wq16]); } while (0)
#define SGB13(S) do { GL(gb0, &Bs[S][wq16]); GL(gb2, &Bs[S][4096 + wq16]); } while (0)
#define SGB24(S) do { GL(gb1, &Bs[S][2048 + wq16]); GL(gb3, &Bs[S][6144 + wq16]); \
    ga0 += 32; ga1 += 32; gb0 += 32; gb1 += 32; gb2 += 32; gb3 += 32; } while (0)

#define MF16(NB) do { \
    acc[0][NB+0]=MFMA16(af0,bf0,acc[0][NB+0]); acc[1][NB+0]=MFMA16(af1,bf0,acc[1][NB+0]); \
    acc[2][NB+0]=MFMA16(af2,bf0,acc[2][NB+0]); acc[3][NB+0]=MFMA16(af3,bf0,acc[3][NB+0]); \
    acc[0][NB+1]=MFMA16(af0,bf1,acc[0][NB+1]); acc[1][NB+1]=MFMA16(af1,bf1,acc[1][NB+1]); \
    acc[2][NB+1]=MFMA16(af2,bf1,acc[2][NB+1]); acc[3][NB+1]=MFMA16(af3,bf1,acc[3][NB+1]); \
    acc[0][NB+2]=MFMA16(af0,bf2,acc[0][NB+2]); acc[1][NB+2]=MFMA16(af1,bf2,acc[1][NB+2]); \
    acc[2][NB+2]=MFMA16(af2,bf2,acc[2][NB+2]); acc[3][NB+2]=MFMA16(af3,bf2,acc[3][NB+2]); \
    acc[0][NB+3]=MFMA16(af0,bf3,acc[0][NB+3]); acc[1][NB+3]=MFMA16(af1,bf3,acc[1][NB+3]); \
    acc[2][NB+3]=MFMA16(af2,bf3,acc[2][NB+3]); acc[3][NB+3]=MFMA16(af3,bf3,acc[3][NB+3]); \
} while (0)

    const u32 ldsA = (u32)(size_t)(las_void*)&As[0][0];
    const u32 ldsB = (u32)(size_t)(las_void*)&Bs[0][0];
    const u32 ckq  = (u32)((kg ^ ((fr >> 1) & 3)) << 4);
    const u32 aRow = (u32)(((wr << 6) + fr) << 6) + ckq;    // row*64B + chunk
    const u32 bRow = (u32)(((wc << 7) + fr) << 6) + ckq;

// one K-tile: 2 phases. SON = staging enabled (tile+1 exists).
#define QT(CUR, STG, SON) do { \
    const u32 aB = ldsA + (CUR) * 8192u + aRow; \
    const u32 bB = ldsB + (CUR) * 16384u + bRow; \
    DSR0(af0, aB); DSR(af1, aB, 1024); DSR(af2, aB, 2048); DSR(af3, aB, 3072); \
    DSR0(bf0, bB); DSR(bf1, bB, 1024); DSR(bf2, bB, 2048); DSR(bf3, bB, 3072); \
    if (SON) { SGA(STG); SGB13(STG); } \
    __builtin_amdgcn_s_barrier(); \
    LGKM0(); \
    __builtin_amdgcn_s_setprio(1); MF16(0); __builtin_amdgcn_s_setprio(0); \
    if (SON) VMW(4); else VMW0(); \
    __builtin_amdgcn_s_barrier(); \
    DSR(bf0, bB, 4096); DSR(bf1, bB, 5120); DSR(bf2, bB, 6144); DSR(bf3, bB, 7168); \
    if (SON) SGB24(STG); \
    __builtin_amdgcn_s_barrier(); \
    LGKM0(); \
    __builtin_amdgcn_s_setprio(1); MF16(4); __builtin_amdgcn_s_setprio(0); \
    if (SON) VMW(2); \
    __builtin_amdgcn_s_barrier(); \
} while (0)

    // prologue: stage tile 0 (A12, B13, B24); certify A12+B13 only (counted)
    SGA(0); SGB13(0); SGB24(0);
    VMW(2);
    __builtin_amdgcn_s_barrier();

    // ---- anti-phase stagger: offset co-resident partner block by ~half a
    // K-tile so its MFMA bursts overlap our LDS drains. Parity of
    // lin^(lin>>8) differs within a pair for both (i,i+256) and (2i,2i+1)
    // pairing orders. One-time ~768-cycle sleep; work unchanged.
    {
        const int lin = blockIdx.y * gridDim.x + blockIdx.x;
        if ((lin ^ (lin >> 8)) & 1) __builtin_amdgcn_s_sleep(12);
    }

#pragma unroll 1
    for (int jj = 0; jj < 15; ++jj) {   // tiles 0..29
        QT(0, 1, 1);
        QT(1, 0, 1);
    }
    QT(0, 1, 1);    // tile 30 (stages tile 31)
    QT(1, 0, 0);    // tile 31 (final: VMW(0) at p0, no staging)

#undef QT
#undef SGA
#undef SGB13
#undef SGB24
#undef MF16

    // ---- epilogue ----
    const int sel   = bn >> 10;                        // 0=q,1=k,2=v
    const int bcol  = (bn & 1023) + (wc << 7);
    const int crow0 = bm + (wr << 6) + (kg << 2);
    if (sel == 2) {
        // V transposed: vt[((b*16+h)*64 + d)*4096 + s], r-quad packed
        u16* vt = (u16*)Cv + (size_t)16777216;
#pragma unroll
        for (int m = 0; m < 4; ++m) {
            const int row0 = crow0 + (m << 4);
            const int bb   = row0 >> 12;
            const int s0   = row0 & 4095;
#pragma unroll
            for (int nf = 0; nf < 8; ++nf) {
                const int col = bcol + (nf << 4) + fr;
                const int hh  = col >> 6;
                const int d   = col & 63;
                u32x2 pk;
                pk.x = (u32)f2bf(acc[m][nf][0]) | ((u32)f2bf(acc[m][nf][1]) << 16);
                pk.y = (u32)f2bf(acc[m][nf][2]) | ((u32)f2bf(acc[m][nf][3]) << 16);
                *(u32x2*)(vt + ((size_t)((bb << 4) + hh) * 64 + d) * 4096 + s0) = pk;
            }
        }
    } else {
        // Q/K head-major [b][h][s][64] with RoPE.
        // Wave band covers heads hb (nf 0..3) and hb+1 (nf 4..7);
        // RoPE pairs within a head: (nf, nf+2) -> dims (d, d+32).
        u16* outb = (u16*)Cv + (size_t)sel * 8388608;
        const int hb = bcol >> 6;
#pragma unroll
        for (int m = 0; m < 4; ++m)
#pragma unroll
            for (int r = 0; r < 4; ++r) {
                const int row = crow0 + (m << 4) + r;
                const int s   = row & 4095;
                const int bb  = row >> 12;
                const f32x2 c0 = *(const f32x2*)(cstab + (((s << 5) + fr) << 1));
                const f32x2 c1 = *(const f32x2*)(cstab + (((s << 5) + 16 + fr) << 1));
#pragma unroll
                for (int g = 0; g < 2; ++g) {          // g=0: head hb (nf 0..3); g=1: head hb+1 (nf 4..7)
                    u16* qp = outb + ((size_t)((bb << 4) + hb + g) * 4096 + s) * 64;
                    {   // pair (4g, 4g+2): dims (fr, fr+32), trig c0
                        const float lo = acc[m][(g << 2) + 0][r];
                        const float hi = acc[m][(g << 2) + 2][r];
                        qp[fr]      = f2bf(lo * c0.x - hi * c0.y);
                        qp[32 + fr] = f2bf(hi * c0.x + lo * c0.y);
                    }
                    {   // pair (4g+1, 4g+3): dims (16+fr, 48+fr), trig c1
                        const float lo = acc[m][(g << 2) + 1][r];
                        const float hi = acc[m][(g << 2) + 3][r];
                        qp[16 + fr] = f2bf(lo * c1.x - hi * c1.y);
                        qp[48 + fr] = f2bf(hi * c1.x + lo * c1.y);
                    }
                }
            }
    }
}

// =====================================================================
// Output-projection GEMM (round-6 verified structure, f32 out).
// BM=128, BN=256, BK=64, 512 thr, one barrier per K-tile.
// =====================================================================
#define FRAGS(P) s16x8 P##a0,P##a1,P##a2,P##a3,P##a4,P##a5,P##a6,P##a7, \
                       P##b0,P##b1,P##b2,P##b3,P##b4,P##b5,P##b6,P##b7

#define LOADTILE(P, CUR) do { \
    const u32 abase_ = ldsA + ((u32)(CUR) << 14) + arow; \
    const u32 bbase_ = ldsB + ((u32)(CUR) << 15) + brow; \
    const u32 aa0_ = abase_ + ck0, aa1_ = abase_ + ck1; \
    const u32 ba0_ = bbase_ + ck0, ba1_ = bbase_ + ck1; \
    DSR0(P##a0, aa0_); DSR(P##a1, aa0_, 2048); DSR(P##a2, aa0_, 4096); DSR(P##a3, aa0_, 6144); \
    DSR0(P##a4, aa1_); DSR(P##a5, aa1_, 2048); DSR(P##a6, aa1_, 4096); DSR(P##a7, aa1_, 6144); \
    DSR0(P##b0, ba0_); DSR(P##b1, ba0_, 2048); DSR(P##b2, ba0_, 4096); DSR(P##b3, ba0_, 6144); \
    DSR0(P##b4, ba1_); DSR(P##b5, ba1_, 2048); DSR(P##b6, ba1_, 4096); DSR(P##b7, ba1_, 6144); \
} while (0)

#define MFMA32(P) do { \
    __builtin_amdgcn_s_setprio(1); \
    acc[0][0]=MFMA16(P##a0,P##b0,acc[0][0]); acc[1][0]=MFMA16(P##a1,P##b0,acc[1][0]); \
    acc[2][0]=MFMA16(P##a2,P##b0,acc[2][0]); acc[3][0]=MFMA16(P##a3,P##b0,acc[3][0]); \
    acc[0][1]=MFMA16(P##a0,P##b1,acc[0][1]); acc[1][1]=MFMA16(P##a1,P##b1,acc[1][1]); \
    acc[2][1]=MFMA16(P##a2,P##b1,acc[2][1]); acc[3][1]=MFMA16(P##a3,P##b1,acc[3][1]); \
    acc[0][2]=MFMA16(P##a0,P##b2,acc[0][2]); acc[1][2]=MFMA16(P##a1,P##b2,acc[1][2]); \
    acc[2][2]=MFMA16(P##a2,P##b2,acc[2][2]); acc[3][2]=MFMA16(P##a3,P##b2,acc[3][2]); \
    acc[0][3]=MFMA16(P##a0,P##b3,acc[0][3]); acc[1][3]=MFMA16(P##a1,P##b3,acc[1][3]); \
    acc[2][3]=MFMA16(P##a2,P##b3,acc[2][3]); acc[3][3]=MFMA16(P##a3,P##b3,acc[3][3]); \
    acc[0][0]=MFMA16(P##a4,P##b4,acc[0][0]); acc[1][0]=MFMA16(P##a5,P##b4,acc[1][0]); \
    acc[2][0]=MFMA16(P##a6,P##b4,acc[2][0]); acc[3][0]=MFMA16(P##a7,P##b4,acc[3][0]); \
    acc[0][1]=MFMA16(P##a4,P##b5,acc[0][1]); acc[1][1]=MFMA16(P##a5,P##b5,acc[1][1]); \
    acc[2][1]=MFMA16(P##a6,P##b5,acc[2][1]); acc[3][1]=MFMA16(P##a7,P##b5,acc[3][1]); \
    acc[0][2]=MFMA16(P##a4,P##b6,acc[0][2]); acc[1][2]=MFMA16(P##a5,P##b6,acc[1][2]); \
    acc[2][2]=MFMA16(P##a6,P##b6,acc[2][2]); acc[3][2]=MFMA16(P##a7,P##b6,acc[3][2]); \
    acc[0][3]=MFMA16(P##a4,P##b7,acc[0][3]); acc[1][3]=MFMA16(P##a5,P##b7,acc[1][3]); \
    acc[2][3]=MFMA16(P##a6,P##b7,acc[2][3]); acc[3][3]=MFMA16(P##a7,P##b7,acc[3][3]); \
    __builtin_amdgcn_s_setprio(0); \
} while (0)

__global__ __launch_bounds__(512, 2)
void gemm_out(const u16* __restrict__ A, const u16* __restrict__ Bw,
              float* __restrict__ Cv) {
    __shared__ __align__(16) u16 As[2][8192];
    __shared__ __align__(16) u16 Bs[2][16384];
    const int t    = threadIdx.x;
    const int bm   = blockIdx.x << 7;
    const int bn   = blockIdx.y << 8;
    const int wave = t >> 6;
    const int wr   = (wave >> 2) & 1;
    const int wc   = wave & 3;
    const int lane = t & 63;
    const int fr   = lane & 15;
    const int kg   = lane >> 4;
    const int f7   = fr & 7;
    const int wq16 = wave << 9;
    const int K    = 1024;

    const int srow = t >> 3;
    const int cSw  = (t & 7) ^ (srow & 7);

    const u16* ga0 = A  + (size_t)(bm + srow) * K + (cSw << 3);
    const u16* ga1 = ga0 + (size_t)64 * K;
    const u16* gb0 = Bw + (size_t)(bn + srow) * K + (cSw << 3);
    const u16* gb1 = gb0 + (size_t)64 * K;
    const u16* gb2 = gb1 + (size_t)64 * K;
    const u16* gb3 = gb2 + (size_t)64 * K;

    f32x4 acc[4][4];
#pragma unroll
    for (int m = 0; m < 4; ++m)
#pragma unroll
        for (int n = 0; n < 4; ++n) acc[m][n] = f32x4{0.f, 0.f, 0.f, 0.f};

    FRAGS(X);
    FRAGS(Y);

#define STAGE(cur) do { \
    GL(ga0, &As[cur][wq16]);          GL(ga1, &As[cur][4096 + wq16]); \
    GL(gb0, &Bs[cur][wq16]);          GL(gb1, &Bs[cur][4096 + wq16]); \
    GL(gb2, &Bs[cur][8192 + wq16]);   GL(gb3, &Bs[cur][12288 + wq16]); \
    ga0 += 64; ga1 += 64; gb0 += 64; gb1 += 64; gb2 += 64; gb3 += 64; \
} while (0)

    const u32 ldsA = (u32)(size_t)(las_void*)&As[0][0];
    const u32 ldsB = (u32)(size_t)(las_void*)&Bs[0][0];
    const u32 arow = (u32)(((wr << 6) + fr) << 7);
    const u32 brow = (u32)(((wc << 6) + fr) << 7);
    const u32 ck0  = (u32)((kg ^ f7) << 4);
    const u32 ck1  = (u32)(((4 + kg) ^ f7) << 4);

    STAGE(0);
    VMW0();
    __builtin_amdgcn_s_barrier();
    LOADTILE(X, 0);
    STAGE(1);

#pragma unroll 1
    for (int j = 0; j < 16; j += 2) {
        LGKM0();
        VMW0();
        __builtin_amdgcn_s_barrier();
        if (j < 14) STAGE(0);
        LOADTILE(Y, 1);
        MFMA32(X);
        LGKM0();
        if (j < 14) {
            VMW0();
            __builtin_amdgcn_s_barrier();
            if (j < 13) STAGE(1);
            LOADTILE(X, 0);
        }
        MFMA32(Y);
    }
#undef STAGE

    const int bcol  = bn + (wc << 6) + fr;
    const int crow0 = bm + (wr << 6) + (kg << 2);
#pragma unroll
    for (int m = 0; m < 4; ++m)
#pragma unroll
        for (int r = 0; r < 4; ++r) {
            const int row = crow0 + (m << 4) + r;
            float* op = Cv + (size_t)row * 1024 + bcol;
            op[0]  = acc[m][0][r];
            op[16] = acc[m][1][r];
            op[32] = acc[m][2][r];
            op[48] = acc[m][3][r];
        }
}

// ---------------- sliding-window attention, MFMA, head-major inputs ----------------
__global__ __launch_bounds__(256)
void attn_kernel(const u16* __restrict__ Q, const u16* __restrict__ K,
                 const u16* __restrict__ Vt, u16* __restrict__ O) {
    __shared__ __align__(16) u16 Ks[192 * 64];
    __shared__ __align__(16) u16 Vs[64 * 192];
    const int bid0 = blockIdx.x;
    const int bid  = ((bid0 & 7) << 8) | (bid0 >> 3);
    const int ch  = bid & 63;
    const int h   = (bid >> 6) & 15;
    const int b   = bid >> 10;
    const int qs  = ch << 6;
    const int t   = threadIdx.x;
    const int ub  = t & 192;

    const u16* kwin = K + ((size_t)((b << 4) + h) << 18);

#pragma unroll
    for (int i = 0; i < 6; ++i) {
        const int cid = (i << 8) + t;
        const int row = cid >> 3;
        const int g   = (cid & 7) ^ (row & 7);
        const int kp  = qs - 64 + row;
        const u16* src = kwin + (long)kp * 64 + (g << 3);
        GL(src, &Ks[((i << 8) + ub) << 3]);
    }
#pragma unroll
    for (int i = 0; i < 6; ++i) {
        const int cid = (i << 8) + t;
        const int d   = cid / 24;
        const int c   = cid - d * 24;
        int g = c - (d & 7) * 3;
        if (g < 0) g += 24;
        const int key = qs - 64 + (g << 3);
        const u16* src = Vt + ((size_t)((b << 10) + (h << 6) + d)) * 4096 + key;
        GL(src, &Vs[((i << 8) + ub) << 3]);
    }

    const int w    = t >> 6;
    const int lane = t & 63;
    const int fr   = lane & 15;
    const int kg   = lane >> 4;
    const int f7   = fr & 7;

    const size_t qgoff = (((size_t)((b << 4) + h)) * 4096 + qs + (w << 4) + fr) * 64 + (kg << 3);
    const s16x8 qa0 = *(const s16x8*)(Q + qgoff);
    const s16x8 qa1 = *(const s16x8*)(Q + qgoff + 32);

    VMW0();
    __syncthreads();

    f32x4 sfr[9];
#pragma unroll
    for (int n = 0; n < 9; ++n) {
        const int row = (w << 4) + (n << 4) + fr;
        f32x4 a = f32x4{0.f, 0.f, 0.f, 0.f};
        const s16x8 kb0 = *(const s16x8*)(&Ks[(row << 6) + ((kg ^ f7) << 3)]);
        const s16x8 kb1 = *(const s16x8*)(&Ks[(row << 6) + (((4 + kg) ^ f7) << 3)]);
        a = MFMA16(qa0, kb0, a);
        a = MFMA16(qa1, kb1, a);
        sfr[n] = a;
    }

    const float NEG = -__builtin_inff();
    float mx[4] = {NEG, NEG, NEG, NEG};
#pragma unroll
    for (int n = 0; n < 9; ++n) {
        const int j = (n << 4) + fr;
#pragma unroll
        for (int r = 0; r < 4; ++r) {
            const int q  = (kg << 2) + r;
            const int kp = qs - 64 + (w << 4) + j;
            const bool valid = (j >= q) && (j - q < 128) && (kp >= 0) && (kp < S_LEN);
            const float s = valid ? sfr[n][r] * 0.125f : NEG;
            sfr[n][r] = s;
            mx[r] = fmaxf(mx[r], s);
        }
    }
#pragma unroll
    for (int r = 0; r < 4; ++r) mx[r] = rmax16(mx[r]);
    float ls[4] = {0.f, 0.f, 0.f, 0.f};
#pragma unroll
    for (int n = 0; n < 9; ++n)
#pragma unroll
        for (int r = 0; r < 4; ++r) {
            const float p = __expf(sfr[n][r] - mx[r]);
            sfr[n][r] = p;
            ls[r] += p;
        }
#pragma unroll
    for (int r = 0; r < 4; ++r) ls[r] = rsum16(ls[r]);

    __syncthreads();
    u16* Pw = Ks + w * 3072;
#pragma unroll
    for (int n = 0; n < 9; ++n) {
        const int j = (n << 4) + fr;
#pragma unroll
        for (int r = 0; r < 4; ++r) {
            const int q = (kg << 2) + r;
            Pw[q * 192 + (((j >> 3) ^ (q & 7)) << 3) + (j & 7)] = f2bf(sfr[n][r]);
        }
    }
    {
        const int j = 144 + fr;
#pragma unroll
        for (int r = 0; r < 4; ++r) {
            const int q = (kg << 2) + r;
            Pw[q * 192 + (((j >> 3) ^ (q & 7)) << 3) + (j & 7)] = 0;
        }
    }
    __syncthreads();

    f32x4 o[4];
#pragma unroll
    for (int nf = 0; nf < 4; ++nf) o[nf] = f32x4{0.f, 0.f, 0.f, 0.f};
    const int cs0 = f7 * 3;
#pragma unroll
    for (int ks = 0; ks < 5; ++ks) {
        const s16x8 pa = *(const s16x8*)(&Pw[fr * 192 + ((((ks << 2) + kg) ^ f7) << 3)]);
        int c = (w << 1) + (ks << 2) + kg;
        if (c > 23) c = 23;
        int cs = c + cs0;
        if (cs >= 24) cs -= 24;
#pragma unroll
        for (int nf = 0; nf < 4; ++nf) {
            const int d = (nf << 4) + fr;
            const s16x8 vbf = *(const s16x8*)(&Vs[d * 192 + (cs << 3)]);
            o[nf] = MFMA16(pa, vbf, o[nf]);
        }
    }

    const size_t obase = ((size_t)((b << 12) + qs + (w << 4) + (kg << 2))) * 1024 + (h << 6) + fr;
#pragma unroll
    for (int r = 0; r < 4; ++r) {
        const float inv = 1.f / ls[r];
#pragma unroll
        for (int nf = 0; nf < 4; ++nf)
            O[obase + (size_t)r * 1024 + (nf << 4)] = f2bf(o[nf][r] * inv);
    }
}

extern "C" void kernel_launch(void* const* d_in, const int* in_sizes, int n_in,
                              void* d_out, int out_size, void* d_ws, size_t ws_size,
                              hipStream_t stream) {
    const float* x  = (const float*)d_in[0];
    const float* fr = (const float*)d_in[1];
    const float* wq = (const float*)d_in[2];
    const float* wk = (const float*)d_in[3];
    const float* wv = (const float*)d_in[4];
    const float* wo = (const float*)d_in[5];

    u16* ws    = (u16*)d_ws;
    u16* xb    = ws;                       // 8388608
    u16* wqkvb = xb + 8388608;             // 3145728
    u16* wob   = wqkvb + 3145728;          // 1048576
    u16* qb    = wob + 1048576;            // Q head-major; K, V^T follow
    u16* kb    = qb + 8388608;
    u16* vtb   = kb + 8388608;
    float* cstab = (float*)(vtb + 8388608);
    u16* ob    = xb;                       // reuse xb after QKV GEMM

    prep_kernel<<<12800, 256, 0, stream>>>(x, wq, wk, wv, wo, fr, xb, wqkvb, wob, cstab);

    dim3 gqkv(64, 12);   // 128x256 tiles -> 768 blocks, 2 resident/CU, 3 total/CU
    gemm_qkv<<<gqkv, 256, 0, stream>>>(xb, wqkvb, qb, cstab);

    attn_kernel<<<2048, 256, 0, stream>>>(qb, kb, vtb, ob);

    dim3 gout(64, 4);    // round-6 structure, 256 blocks
    gemm_out<<<gout, 512, 0, stream>>>(ob, wob, (float*)d_out);
}

// Round 14
// 109.105 us; speedup vs baseline: 1.2711x; 1.0576x over previous
//
#include <hip/hip_runtime.h>

typedef unsigned short u16;
typedef unsigned int   u32;
typedef unsigned long long u64;
typedef __attribute__((ext_vector_type(4))) unsigned int u32x4;
typedef __attribute__((ext_vector_type(2))) unsigned int u32x2;
typedef __attribute__((ext_vector_type(8))) short        s16x8;
typedef __attribute__((ext_vector_type(4))) float        f32x4;
typedef __attribute__((ext_vector_type(2))) float        f32x2;

#define S_LEN 4096

typedef const __attribute__((address_space(1))) void gas_void;
typedef __attribute__((address_space(3))) void las_void;

__device__ __forceinline__ u16 f2bf(float f) {
    u32 u = __builtin_bit_cast(u32, f);
    u32 r = (u + 0x7fffu + ((u >> 16) & 1u)) >> 16;
    return (u16)r;
}

__device__ __forceinline__ float rmax16(float v) {
    v = fmaxf(v, __shfl_xor(v, 1));
    v = fmaxf(v, __shfl_xor(v, 2));
    v = fmaxf(v, __shfl_xor(v, 4));
    v = fmaxf(v, __shfl_xor(v, 8));
    return v;
}
__device__ __forceinline__ float rsum16(float v) {
    v += __shfl_xor(v, 1);
    v += __shfl_xor(v, 2);
    v += __shfl_xor(v, 4);
    v += __shfl_xor(v, 8);
    return v;
}

#define VMW0() asm volatile("s_waitcnt vmcnt(0)" ::: "memory")
#define VMWS(n) do { asm volatile("s_waitcnt vmcnt(" #n ")" ::: "memory"); \
                     __builtin_amdgcn_sched_barrier(0); } while (0)
#define SB0() __builtin_amdgcn_sched_barrier(0)
#define MFMA16(a, b, c) __builtin_amdgcn_mfma_f32_16x16x32_bf16(a, b, c, 0, 0, 0)
#define GL(p, d) __builtin_amdgcn_global_load_lds((gas_void*)(p), (las_void*)(d), 16, 0, 0)
#define GLB(d, a, o) asm volatile("global_load_dwordx4 %0, %1, off offset:" #o : "=v"(d) : "v"(a))

// =====================================================================
// prep: pack x -> A-frag layout, weights -> B-frag layout, rope table.
// Packed layout: pk[kt][frag][lane][8] (u16), element =
//   M[frag*16 + (lane&15)][kt*32 + (lane>>4)*8 + j]
// so one wave fragment load = contiguous 1 KB.
// blocks 0..511: x (16 rows each); 512..767: weights (wq,wk,wv,wo x 64);
// blocks 768..1279: rope cos/sin table.
// =====================================================================
__global__ __launch_bounds__(256)
void prep_kernel(const float* __restrict__ x,
                 const float* __restrict__ wq, const float* __restrict__ wk,
                 const float* __restrict__ wv, const float* __restrict__ wo,
                 const float* __restrict__ freqs,
                 u16* __restrict__ apk, u16* __restrict__ bpk, u16* __restrict__ wopk,
                 float* __restrict__ tab) {
    const int bid = blockIdx.x;
    const int t   = threadIdx.x;
    if (bid >= 768) {                                  // rope table: 131072 entries
        const int i = (bid - 768) * 256 + t;
        const float f = freqs[i];
        float sn, cs;
        sincosf(f, &sn, &cs);
        tab[i * 2]     = cs;
        tab[i * 2 + 1] = sn;
        return;
    }
    __shared__ u16 L[16][1032];                        // +8 pad: conflict-light reads
    const float* src;
    u16* dst;
    int nft, frag0, rowblk;
    if (bid < 512) { src = x; dst = apk; nft = 512; rowblk = bid; frag0 = bid; }
    else {
        const int wsel = (bid - 512) >> 6;
        rowblk = (bid - 512) & 63;
        src = (wsel == 0) ? wq : (wsel == 1) ? wk : (wsel == 2) ? wv : wo;
        if (wsel < 3) { dst = bpk;  nft = 192; frag0 = wsel * 64 + rowblk; }
        else          { dst = wopk; nft = 64;  frag0 = rowblk; }
    }
    // coalesced read of 16 rows, bf16 convert into LDS
#pragma unroll
    for (int r = 0; r < 16; ++r) {
        const f32x4 v = *(const f32x4*)(src + ((size_t)(rowblk * 16 + r)) * 1024 + t * 4);
        u16* Lp = &L[r][t * 4];
        Lp[0] = f2bf(v.x); Lp[1] = f2bf(v.y); Lp[2] = f2bf(v.z); Lp[3] = f2bf(v.w);
    }
    __syncthreads();
    // packed write: slot (c32, lane) <- L[lane&15][c32*32 + (lane>>4)*8 ..+8]
#pragma unroll
    for (int i = 0; i < 8; ++i) {
        const int idx = (i << 8) + t;
        const int c32 = idx >> 6;
        const int l   = idx & 63;
        const u32x4 d = *(const u32x4*)(&L[l & 15][(c32 << 5) + ((l >> 4) << 3)]);
        *(u32x4*)(dst + (((size_t)c32 * nft + frag0) * 64 + l) * 8) = d;
    }
}

// =====================================================================
// LDS-FREE fragment-streaming GEMM.
// Block 256 thr / 4 waves (2Mx2N), wave tile 64x128 (4 m-frags x 8 n-frags),
// block tile 128x256, K=1024 = 32 tiles of BK=32. Per wave per tile:
// 12 coalesced 1KB frag loads (global->reg, X/Y double-buffered),
// counted vmcnt(12), 32 MFMA. No LDS, no barriers, waves independent.
// MODE 1: fused QKV epilogue (Q,K head-major + RoPE; V^T) [r12-verified]
// MODE 2: f32 row-major out.
// SAK (A kt-stride bytes) = 512 frags * 1KB; SBK: QKV 192KB.., proj 64KB.
// =====================================================================
#define FRAGS(P) s16x8 P##a0,P##a1,P##a2,P##a3, \
                       P##b0,P##b1,P##b2,P##b3,P##b4,P##b5,P##b6,P##b7

#define LD_TILE(P) do { \
    GLB(P##a0, aA, 0); GLB(P##a1, aA, 1024); GLB(P##a2, aA, 2048); GLB(P##a3, aA, 3072); \
    GLB(P##b0, aB0, 0); GLB(P##b1, aB0, 1024); GLB(P##b2, aB0, 2048); GLB(P##b3, aB0, 3072); \
    GLB(P##b4, aB1, 0); GLB(P##b5, aB1, 1024); GLB(P##b6, aB1, 2048); GLB(P##b7, aB1, 3072); \
    aA += 524288u; aB0 += (u64)SBK; aB1 += (u64)SBK; \
} while (0)

#define MFMA32P(P) do { \
    acc[0][0]=MFMA16(P##a0,P##b0,acc[0][0]); acc[1][0]=MFMA16(P##a1,P##b0,acc[1][0]); \
    acc[2][0]=MFMA16(P##a2,P##b0,acc[2][0]); acc[3][0]=MFMA16(P##a3,P##b0,acc[3][0]); \
    acc[0][1]=MFMA16(P##a0,P##b1,acc[0][1]); acc[1][1]=MFMA16(P##a1,P##b1,acc[1][1]); \
    acc[2][1]=MFMA16(P##a2,P##b1,acc[2][1]); acc[3][1]=MFMA16(P##a3,P##b1,acc[3][1]); \
    acc[0][2]=MFMA16(P##a0,P##b2,acc[0][2]); acc[1][2]=MFMA16(P##a1,P##b2,acc[1][2]); \
    acc[2][2]=MFMA16(P##a2,P##b2,acc[2][2]); acc[3][2]=MFMA16(P##a3,P##b2,acc[3][2]); \
    acc[0][3]=MFMA16(P##a0,P##b3,acc[0][3]); acc[1][3]=MFMA16(P##a1,P##b3,acc[1][3]); \
    acc[2][3]=MFMA16(P##a2,P##b3,acc[2][3]); acc[3][3]=MFMA16(P##a3,P##b3,acc[3][3]); \
    acc[0][4]=MFMA16(P##a0,P##b4,acc[0][4]); acc[1][4]=MFMA16(P##a1,P##b4,acc[1][4]); \
    acc[2][4]=MFMA16(P##a2,P##b4,acc[2][4]); acc[3][4]=MFMA16(P##a3,P##b4,acc[3][4]); \
    acc[0][5]=MFMA16(P##a0,P##b5,acc[0][5]); acc[1][5]=MFMA16(P##a1,P##b5,acc[1][5]); \
    acc[2][5]=MFMA16(P##a2,P##b5,acc[2][5]); acc[3][5]=MFMA16(P##a3,P##b5,acc[3][5]); \
    acc[0][6]=MFMA16(P##a0,P##b6,acc[0][6]); acc[1][6]=MFMA16(P##a1,P##b6,acc[1][6]); \
    acc[2][6]=MFMA16(P##a2,P##b6,acc[2][6]); acc[3][6]=MFMA16(P##a3,P##b6,acc[3][6]); \
    acc[0][7]=MFMA16(P##a0,P##b7,acc[0][7]); acc[1][7]=MFMA16(P##a1,P##b7,acc[1][7]); \
    acc[2][7]=MFMA16(P##a2,P##b7,acc[2][7]); acc[3][7]=MFMA16(P##a3,P##b7,acc[3][7]); \
} while (0)

template<int SBK, int MODE>
__global__ __launch_bounds__(256, 2)
void gemm_pk(const u16* __restrict__ Apk, const u16* __restrict__ Bpk,
             void* __restrict__ Cv, const float* __restrict__ cstab) {
    const int t    = threadIdx.x;
    const int bm   = blockIdx.x << 7;
    const int bn   = blockIdx.y << 8;
    const int wave = t >> 6;
    const int wr   = (wave >> 1) & 1;
    const int wc   = wave & 1;
    const int lane = t & 63;
    const int fr   = lane & 15;
    const int kg   = lane >> 4;

    u64 aA  = (u64)(uintptr_t)Apk + (u64)(((bm >> 4) + (wr << 2)) * 1024 + lane * 16);
    u64 aB0 = (u64)(uintptr_t)Bpk + (u64)(((bn >> 4) + (wc << 3)) * 1024 + lane * 16);
    u64 aB1 = aB0 + 4096u;

    f32x4 acc[4][8];
#pragma unroll
    for (int m = 0; m < 4; ++m)
#pragma unroll
        for (int n = 0; n < 8; ++n) acc[m][n] = f32x4{0.f, 0.f, 0.f, 0.f};

    FRAGS(X);
    FRAGS(Y);

    LD_TILE(X);           // tile 0
    LD_TILE(Y);           // tile 1  (24 loads outstanding)

#pragma unroll 1
    for (int i = 0; i < 15; ++i) {            // tiles 0..29; issues 2..31
        VMWS(12);                             // even tile ready
        MFMA32P(X);
        SB0();
        LD_TILE(X);                           // tile 2i+2
        VMWS(12);                             // odd tile ready
        MFMA32P(Y);
        SB0();
        LD_TILE(Y);                           // tile 2i+3
    }
    VMWS(12);
    MFMA32P(X);                               // tile 30
    VMW0();
    SB0();
    MFMA32P(Y);                               // tile 31

    // ---- epilogue ----
    if constexpr (MODE == 1) {
        const int sel   = bn >> 10;                        // 0=q,1=k,2=v
        const int bcol  = (bn & 1023) + (wc << 7);
        const int crow0 = bm + (wr << 6) + (kg << 2);
        if (sel == 2) {
            // V transposed: vt[((b*16+h)*64 + d)*4096 + s], r-quad packed
            u16* vt = (u16*)Cv + (size_t)16777216;
#pragma unroll
            for (int m = 0; m < 4; ++m) {
                const int row0 = crow0 + (m << 4);
                const int bb   = row0 >> 12;
                const int s0   = row0 & 4095;
#pragma unroll
                for (int nf = 0; nf < 8; ++nf) {
                    const int col = bcol + (nf << 4) + fr;
                    const int hh  = col >> 6;
                    const int d   = col & 63;
                    u32x2 pk;
                    pk.x = (u32)f2bf(acc[m][nf][0]) | ((u32)f2bf(acc[m][nf][1]) << 16);
                    pk.y = (u32)f2bf(acc[m][nf][2]) | ((u32)f2bf(acc[m][nf][3]) << 16);
                    *(u32x2*)(vt + ((size_t)((bb << 4) + hh) * 64 + d) * 4096 + s0) = pk;
                }
            }
        } else {
            // Q/K head-major [b][h][s][64] with RoPE; heads hb (nf0-3), hb+1 (nf4-7)
            u16* outb = (u16*)Cv + (size_t)sel * 8388608;
            const int hb = bcol >> 6;
#pragma unroll
            for (int m = 0; m < 4; ++m)
#pragma unroll
                for (int r = 0; r < 4; ++r) {
                    const int row = crow0 + (m << 4) + r;
                    const int s   = row & 4095;
                    const int bb  = row >> 12;
                    const f32x2 c0 = *(const f32x2*)(cstab + (((s << 5) + fr) << 1));
                    const f32x2 c1 = *(const f32x2*)(cstab + (((s << 5) + 16 + fr) << 1));
#pragma unroll
                    for (int g = 0; g < 2; ++g) {
                        u16* qp = outb + ((size_t)((bb << 4) + hb + g) * 4096 + s) * 64;
                        {
                            const float lo = acc[m][(g << 2) + 0][r];
                            const float hi = acc[m][(g << 2) + 2][r];
                            qp[fr]      = f2bf(lo * c0.x - hi * c0.y);
                            qp[32 + fr] = f2bf(hi * c0.x + lo * c0.y);
                        }
                        {
                            const float lo = acc[m][(g << 2) + 1][r];
                            const float hi = acc[m][(g << 2) + 3][r];
                            qp[16 + fr] = f2bf(lo * c1.x - hi * c1.y);
                            qp[48 + fr] = f2bf(hi * c1.x + lo * c1.y);
                        }
                    }
                }
        }
    } else {
        float* outf     = (float*)Cv;
        const int bcol  = bn + (wc << 7) + fr;
        const int crow0 = bm + (wr << 6) + (kg << 2);
#pragma unroll
        for (int m = 0; m < 4; ++m)
#pragma unroll
            for (int r = 0; r < 4; ++r) {
                const int row = crow0 + (m << 4) + r;
                float* op = outf + (size_t)row * 1024 + bcol;
#pragma unroll
                for (int nf = 0; nf < 8; ++nf)
                    op[nf << 4] = acc[m][nf][r];
            }
    }
}

// ---------------- sliding-window attention, MFMA, head-major inputs ----------------
// Output written in A-frag-packed layout for the projection GEMM.
__global__ __launch_bounds__(256)
void attn_kernel(const u16* __restrict__ Q, const u16* __restrict__ K,
                 const u16* __restrict__ Vt, u16* __restrict__ O) {
    __shared__ __align__(16) u16 Ks[192 * 64];
    __shared__ __align__(16) u16 Vs[64 * 192];
    const int bid0 = blockIdx.x;
    const int bid  = ((bid0 & 7) << 8) | (bid0 >> 3);
    const int ch  = bid & 63;
    const int h   = (bid >> 6) & 15;
    const int b   = bid >> 10;
    const int qs  = ch << 6;
    const int t   = threadIdx.x;
    const int ub  = t & 192;

    const u16* kwin = K + ((size_t)((b << 4) + h) << 18);

#pragma unroll
    for (int i = 0; i < 6; ++i) {
        const int cid = (i << 8) + t;
        const int row = cid >> 3;
        const int g   = (cid & 7) ^ (row & 7);
        const int kp  = qs - 64 + row;
        const u16* src = kwin + (long)kp * 64 + (g << 3);
        GL(src, &Ks[((i << 8) + ub) << 3]);
    }
#pragma unroll
    for (int i = 0; i < 6; ++i) {
        const int cid = (i << 8) + t;
        const int d   = cid / 24;
        const int c   = cid - d * 24;
        int g = c - (d & 7) * 3;
        if (g < 0) g += 24;
        const int key = qs - 64 + (g << 3);
        const u16* src = Vt + ((size_t)((b << 10) + (h << 6) + d)) * 4096 + key;
        GL(src, &Vs[((i << 8) + ub) << 3]);
    }

    const int w    = t >> 6;
    const int lane = t & 63;
    const int fr   = lane & 15;
    const int kg   = lane >> 4;
    const int f7   = fr & 7;

    const size_t qgoff = (((size_t)((b << 4) + h)) * 4096 + qs + (w << 4) + fr) * 64 + (kg << 3);
    const s16x8 qa0 = *(const s16x8*)(Q + qgoff);
    const s16x8 qa1 = *(const s16x8*)(Q + qgoff + 32);

    VMW0();
    __syncthreads();

    f32x4 sfr[9];
#pragma unroll
    for (int n = 0; n < 9; ++n) {
        const int row = (w << 4) + (n << 4) + fr;
        f32x4 a = f32x4{0.f, 0.f, 0.f, 0.f};
        const s16x8 kb0 = *(const s16x8*)(&Ks[(row << 6) + ((kg ^ f7) << 3)]);
        const s16x8 kb1 = *(const s16x8*)(&Ks[(row << 6) + (((4 + kg) ^ f7) << 3)]);
        a = MFMA16(qa0, kb0, a);
        a = MFMA16(qa1, kb1, a);
        sfr[n] = a;
    }

    const float NEG = -__builtin_inff();
    float mx[4] = {NEG, NEG, NEG, NEG};
#pragma unroll
    for (int n = 0; n < 9; ++n) {
        const int j = (n << 4) + fr;
#pragma unroll
        for (int r = 0; r < 4; ++r) {
            const int q  = (kg << 2) + r;
            const int kp = qs - 64 + (w << 4) + j;
            const bool valid = (j >= q) && (j - q < 128) && (kp >= 0) && (kp < S_LEN);
            const float s = valid ? sfr[n][r] * 0.125f : NEG;
            sfr[n][r] = s;
            mx[r] = fmaxf(mx[r], s);
        }
    }
#pragma unroll
    for (int r = 0; r < 4; ++r) mx[r] = rmax16(mx[r]);
    float ls[4] = {0.f, 0.f, 0.f, 0.f};
#pragma unroll
    for (int n = 0; n < 9; ++n)
#pragma unroll
        for (int r = 0; r < 4; ++r) {
            const float p = __expf(sfr[n][r] - mx[r]);
            sfr[n][r] = p;
            ls[r] += p;
        }
#pragma unroll
    for (int r = 0; r < 4; ++r) ls[r] = rsum16(ls[r]);

    __syncthreads();
    u16* Pw = Ks + w * 3072;
#pragma unroll
    for (int n = 0; n < 9; ++n) {
        const int j = (n << 4) + fr;
#pragma unroll
        for (int r = 0; r < 4; ++r) {
            const int q = (kg << 2) + r;
            Pw[q * 192 + (((j >> 3) ^ (q & 7)) << 3) + (j & 7)] = f2bf(sfr[n][r]);
        }
    }
    {
        const int j = 144 + fr;
#pragma unroll
        for (int r = 0; r < 4; ++r) {
            const int q = (kg << 2) + r;
            Pw[q * 192 + (((j >> 3) ^ (q & 7)) << 3) + (j & 7)] = 0;
        }
    }
    __syncthreads();

    f32x4 o[4];
#pragma unroll
    for (int nf = 0; nf < 4; ++nf) o[nf] = f32x4{0.f, 0.f, 0.f, 0.f};
    const int cs0 = f7 * 3;
#pragma unroll
    for (int ks = 0; ks < 5; ++ks) {
        const s16x8 pa = *(const s16x8*)(&Pw[fr * 192 + ((((ks << 2) + kg) ^ f7) << 3)]);
        int c = (w << 1) + (ks << 2) + kg;
        if (c > 23) c = 23;
        int cs = c + cs0;
        if (cs >= 24) cs -= 24;
#pragma unroll
        for (int nf = 0; nf < 4; ++nf) {
            const int d = (nf << 4) + fr;
            const s16x8 vbf = *(const s16x8*)(&Vs[d * 192 + (cs << 3)]);
            o[nf] = MFMA16(pa, vbf, o[nf]);
        }
    }

    // ---- normalize + store in A-frag-packed layout (nfrag_tot = 512) ----
    // element (row = b*4096+qs+w*16+kg*4+r, col = h*64+nf*16+fr):
    // kt = col>>5, frag = row>>4, lane' = ((col%32)>>3)*16 + row%16, j = col&7
    const int mfrag = (b << 8) + (ch << 2) + w;
#pragma unroll
    for (int r = 0; r < 4; ++r) {
        const float inv = 1.f / ls[r];
#pragma unroll
        for (int nf = 0; nf < 4; ++nf) {
            const int kt  = (h << 1) + (nf >> 1);
            const int kgp = ((nf & 1) << 1) + (fr >> 3);
            const int lp  = (kgp << 4) + (kg << 2) + r;
            O[((((size_t)kt << 9) + mfrag) * 64 + lp) * 8 + (fr & 7)] = f2bf(o[nf][r] * inv);
        }
    }
}

extern "C" void kernel_launch(void* const* d_in, const int* in_sizes, int n_in,
                              void* d_out, int out_size, void* d_ws, size_t ws_size,
                              hipStream_t stream) {
    const float* x  = (const float*)d_in[0];
    const float* fr = (const float*)d_in[1];
    const float* wq = (const float*)d_in[2];
    const float* wk = (const float*)d_in[3];
    const float* wv = (const float*)d_in[4];
    const float* wo = (const float*)d_in[5];

    u16* ws    = (u16*)d_ws;
    u16* apk   = ws;                       // 8388608  (x packed; later attn-out packed)
    u16* bpk   = apk + 8388608;            // 3145728  (wq|wk|wv packed)
    u16* wopk  = bpk + 3145728;            // 1048576
    u16* qb    = wopk + 1048576;           // 8388608 head-major; kb, vtb follow
    u16* kb    = qb + 8388608;
    u16* vtb   = kb + 8388608;
    float* cstab = (float*)(vtb + 8388608);
    u16* opk   = apk;                      // reuse after QKV GEMM

    prep_kernel<<<1280, 256, 0, stream>>>(x, wq, wk, wv, wo, fr, apk, bpk, wopk, cstab);

    dim3 gqkv(64, 12);
    gemm_pk<196608, 1><<<gqkv, 256, 0, stream>>>(apk, bpk, qb, cstab);

    attn_kernel<<<2048, 256, 0, stream>>>(qb, kb, vtb, opk);

    dim3 gout(64, 4);
    gemm_pk<65536, 2><<<gout, 256, 0, stream>>>(opk, wopk, (float*)d_out, nullptr);
}

// Round 15
// 106.576 us; speedup vs baseline: 1.3013x; 1.0237x over previous
//
#include <hip/hip_runtime.h>

typedef unsigned short u16;
typedef unsigned int   u32;
typedef unsigned long long u64;
typedef __attribute__((ext_vector_type(4))) unsigned int u32x4;
typedef __attribute__((ext_vector_type(2))) unsigned int u32x2;
typedef __attribute__((ext_vector_type(8))) short        s16x8;
typedef __attribute__((ext_vector_type(4))) float        f32x4;
typedef __attribute__((ext_vector_type(2))) float        f32x2;

#define S_LEN 4096

typedef const __attribute__((address_space(1))) void gas_void;
typedef __attribute__((address_space(3))) void las_void;

__device__ __forceinline__ u16 f2bf(float f) {
    u32 u = __builtin_bit_cast(u32, f);
    u32 r = (u + 0x7fffu + ((u >> 16) & 1u)) >> 16;
    return (u16)r;
}

__device__ __forceinline__ float rmax16(float v) {
    v = fmaxf(v, __shfl_xor(v, 1));
    v = fmaxf(v, __shfl_xor(v, 2));
    v = fmaxf(v, __shfl_xor(v, 4));
    v = fmaxf(v, __shfl_xor(v, 8));
    return v;
}
__device__ __forceinline__ float rsum16(float v) {
    v += __shfl_xor(v, 1);
    v += __shfl_xor(v, 2);
    v += __shfl_xor(v, 4);
    v += __shfl_xor(v, 8);
    return v;
}

#define VMW0() asm volatile("s_waitcnt vmcnt(0)" ::: "memory")
#define VMWS(n) do { asm volatile("s_waitcnt vmcnt(" #n ")" ::: "memory"); \
                     __builtin_amdgcn_sched_barrier(0); } while (0)
#define LGKM0() do { asm volatile("s_waitcnt lgkmcnt(0)" ::: "memory"); \
                     __builtin_amdgcn_sched_barrier(0); } while (0)
#define SB0() __builtin_amdgcn_sched_barrier(0)
#define DSR0(d, a)   asm volatile("ds_read_b128 %0, %1"              : "=v"(d) : "v"(a))
#define DSR(d, a, o) asm volatile("ds_read_b128 %0, %1 offset:" #o   : "=v"(d) : "v"(a))
#define MFMA16(a, b, c) __builtin_amdgcn_mfma_f32_16x16x32_bf16(a, b, c, 0, 0, 0)
#define GL(p, d) __builtin_amdgcn_global_load_lds((gas_void*)(p), (las_void*)(d), 16, 0, 0)
#define GLB(d, a, o) asm volatile("global_load_dwordx4 %0, %1, off offset:" #o : "=v"(d) : "v"(a))

// =====================================================================
// prep: pack x -> A-frag layout, weights -> B-frag layout, rope table.
// Packed layout: pk[kt][frag][lane][8] (u16), element =
//   M[frag*16 + (lane&15)][kt*32 + (lane>>4)*8 + j]
// =====================================================================
__global__ __launch_bounds__(256)
void prep_kernel(const float* __restrict__ x,
                 const float* __restrict__ wq, const float* __restrict__ wk,
                 const float* __restrict__ wv, const float* __restrict__ wo,
                 const float* __restrict__ freqs,
                 u16* __restrict__ apk, u16* __restrict__ bpk, u16* __restrict__ wopk,
                 float* __restrict__ tab) {
    const int bid = blockIdx.x;
    const int t   = threadIdx.x;
    if (bid >= 768) {                                  // rope table: 131072 entries
        const int i = (bid - 768) * 256 + t;
        const float f = freqs[i];
        float sn, cs;
        sincosf(f, &sn, &cs);
        tab[i * 2]     = cs;
        tab[i * 2 + 1] = sn;
        return;
    }
    __shared__ u16 L[16][1032];
    const float* src;
    u16* dst;
    int nft, frag0, rowblk;
    if (bid < 512) { src = x; dst = apk; nft = 512; rowblk = bid; frag0 = bid; }
    else {
        const int wsel = (bid - 512) >> 6;
        rowblk = (bid - 512) & 63;
        src = (wsel == 0) ? wq : (wsel == 1) ? wk : (wsel == 2) ? wv : wo;
        if (wsel < 3) { dst = bpk;  nft = 192; frag0 = wsel * 64 + rowblk; }
        else          { dst = wopk; nft = 64;  frag0 = rowblk; }
    }
#pragma unroll
    for (int r = 0; r < 16; ++r) {
        const f32x4 v = *(const f32x4*)(src + ((size_t)(rowblk * 16 + r)) * 1024 + t * 4);
        u16* Lp = &L[r][t * 4];
        Lp[0] = f2bf(v.x); Lp[1] = f2bf(v.y); Lp[2] = f2bf(v.z); Lp[3] = f2bf(v.w);
    }
    __syncthreads();
#pragma unroll
    for (int i = 0; i < 8; ++i) {
        const int idx = (i << 8) + t;
        const int c32 = idx >> 6;
        const int l   = idx & 63;
        const u32x4 d = *(const u32x4*)(&L[l & 15][(c32 << 5) + ((l >> 4) << 3)]);
        *(u32x4*)(dst + (((size_t)c32 * nft + frag0) * 64 + l) * 8) = d;
    }
}

// =====================================================================
// HYBRID GEMM: A frags direct from L1 (packed global), B frags de-duplicated
// through LDS (gload_lds staging of packed frags -> conflict-free lane*16
// ds_read_b128). Block 256 thr / 4 waves (2Mx2N), wave tile 64x128,
// block tile 128x256, BK=32, 32 K-tiles. LDS 2 x 16 KB double buffer.
// Per tile per wave: 4 A glb + 4 B gload_lds + 8 ds_read + 32 MFMA.
// 1 barrier/tile; VMW(4) certifies {stage j+1, A j}, leaves A j+1 flying.
// MODE 1: fused QKV epilogue (Q,K head-major + RoPE; V^T). MODE 2: f32 out.
// =====================================================================
#define FRAGS(P) s16x8 P##a0,P##a1,P##a2,P##a3, \
                       P##b0,P##b1,P##b2,P##b3,P##b4,P##b5,P##b6,P##b7

#define LDA(P) do { \
    GLB(P##a0, aA, 0); GLB(P##a1, aA, 1024); GLB(P##a2, aA, 2048); GLB(P##a3, aA, 3072); \
    aA += 524288u; \
} while (0)

#define SGB(BUF) do { \
    GL((const u16*)gBs,          &Bs[BUF][(((wave << 2) + 0) << 9)]); \
    GL((const u16*)(gBs + 1024), &Bs[BUF][(((wave << 2) + 1) << 9)]); \
    GL((const u16*)(gBs + 2048), &Bs[BUF][(((wave << 2) + 2) << 9)]); \
    GL((const u16*)(gBs + 3072), &Bs[BUF][(((wave << 2) + 3) << 9)]); \
    gBs += (u64)SBK; \
} while (0)

#define LDB(P, BUF) do { \
    const u32 rb_ = ldsB + ((BUF) ? 16384u : 0u) + (wc << 13) + (lane << 4); \
    DSR0(P##b0, rb_); DSR(P##b1, rb_, 1024); DSR(P##b2, rb_, 2048); DSR(P##b3, rb_, 3072); \
    DSR(P##b4, rb_, 4096); DSR(P##b5, rb_, 5120); DSR(P##b6, rb_, 6144); DSR(P##b7, rb_, 7168); \
} while (0)

#define MFMA32P(P) do { \
    __builtin_amdgcn_s_setprio(1); \
    acc[0][0]=MFMA16(P##a0,P##b0,acc[0][0]); acc[1][0]=MFMA16(P##a1,P##b0,acc[1][0]); \
    acc[2][0]=MFMA16(P##a2,P##b0,acc[2][0]); acc[3][0]=MFMA16(P##a3,P##b0,acc[3][0]); \
    acc[0][1]=MFMA16(P##a0,P##b1,acc[0][1]); acc[1][1]=MFMA16(P##a1,P##b1,acc[1][1]); \
    acc[2][1]=MFMA16(P##a2,P##b1,acc[2][1]); acc[3][1]=MFMA16(P##a3,P##b1,acc[3][1]); \
    acc[0][2]=MFMA16(P##a0,P##b2,acc[0][2]); acc[1][2]=MFMA16(P##a1,P##b2,acc[1][2]); \
    acc[2][2]=MFMA16(P##a2,P##b2,acc[2][2]); acc[3][2]=MFMA16(P##a3,P##b2,acc[3][2]); \
    acc[0][3]=MFMA16(P##a0,P##b3,acc[0][3]); acc[1][3]=MFMA16(P##a1,P##b3,acc[1][3]); \
    acc[2][3]=MFMA16(P##a2,P##b3,acc[2][3]); acc[3][3]=MFMA16(P##a3,P##b3,acc[3][3]); \
    acc[0][4]=MFMA16(P##a0,P##b4,acc[0][4]); acc[1][4]=MFMA16(P##a1,P##b4,acc[1][4]); \
    acc[2][4]=MFMA16(P##a2,P##b4,acc[2][4]); acc[3][4]=MFMA16(P##a3,P##b4,acc[3][4]); \
    acc[0][5]=MFMA16(P##a0,P##b5,acc[0][5]); acc[1][5]=MFMA16(P##a1,P##b5,acc[1][5]); \
    acc[2][5]=MFMA16(P##a2,P##b5,acc[2][5]); acc[3][5]=MFMA16(P##a3,P##b5,acc[3][5]); \
    acc[0][6]=MFMA16(P##a0,P##b6,acc[0][6]); acc[1][6]=MFMA16(P##a1,P##b6,acc[1][6]); \
    acc[2][6]=MFMA16(P##a2,P##b6,acc[2][6]); acc[3][6]=MFMA16(P##a3,P##b6,acc[3][6]); \
    acc[0][7]=MFMA16(P##a0,P##b7,acc[0][7]); acc[1][7]=MFMA16(P##a1,P##b7,acc[1][7]); \
    acc[2][7]=MFMA16(P##a2,P##b7,acc[2][7]); acc[3][7]=MFMA16(P##a3,P##b7,acc[3][7]); \
    __builtin_amdgcn_s_setprio(0); \
} while (0)

template<int SBK, int MODE>
__global__ __launch_bounds__(256, 2)
void gemm_hy(const u16* __restrict__ Apk, const u16* __restrict__ Bpk,
             void* __restrict__ Cv, const float* __restrict__ cstab) {
    __shared__ __align__(1024) u16 Bs[2][8192];    // 2 x 16 KB, frag-linear
    const int t    = threadIdx.x;
    const int bm   = blockIdx.x << 7;
    const int bn   = blockIdx.y << 8;
    const int wave = t >> 6;
    const int wr   = (wave >> 1) & 1;
    const int wc   = wave & 1;
    const int lane = t & 63;
    const int fr   = lane & 15;
    const int kg   = lane >> 4;

    u64 aA  = (u64)(uintptr_t)Apk + (u64)((((bm >> 4) + (wr << 2)) << 10) + (lane << 4));
    u64 gBs = (u64)(uintptr_t)Bpk + (u64)((((bn >> 4) + (wave << 2)) << 10) + (lane << 4));
    const u32 ldsB = (u32)(size_t)(las_void*)&Bs[0][0];

    f32x4 acc[4][8];
#pragma unroll
    for (int m = 0; m < 4; ++m)
#pragma unroll
        for (int n = 0; n < 8; ++n) acc[m][n] = f32x4{0.f, 0.f, 0.f, 0.f};

    FRAGS(X);
    FRAGS(Y);

    // prologue: stage B0->buf0, A0->Xa, stage B1->buf1, A1->Ya
    SGB(0);
    LDA(X);
    SGB(1);
    LDA(Y);
    VMWS(12);                            // stage(0) landed (12 newer left flying)
    __builtin_amdgcn_s_barrier();
    LDB(X, 0);                           // tile 0 B frags

#pragma unroll 1
    for (int jj = 0; jj < 15; ++jj) {    // tiles 0..29 (stages/loads up to 31)
        // ---- X = tile 2jj (buf0) ----
        LGKM0();                         // Xb resident
        VMWS(4);                         // certify stage(2jj+1) + A(2jj); leave A(2jj+1)
        __builtin_amdgcn_s_barrier();
        SGB(0);                          // stage tile 2jj+2 -> buf0
        LDB(Y, 1);                       // ds_read tile 2jj+1
        MFMA32P(X);
        LDA(X);                          // A(2jj+2) (after MFMA: WAR-safe)
        // ---- Y = tile 2jj+1 (buf1) ----
        LGKM0();                         // Yb resident
        VMWS(4);                         // certify stage(2jj+2) + A(2jj+1); leave A(2jj+2)
        __builtin_amdgcn_s_barrier();
        SGB(1);                          // stage tile 2jj+3 -> buf1
        LDB(X, 0);                       // ds_read tile 2jj+2
        MFMA32P(Y);
        LDA(Y);                          // A(2jj+3)
    }
    // ---- tile 30 (X, buf0) ----
    LGKM0();
    VMWS(4);                             // certify stage(31) + A(30); leave A(31)
    __builtin_amdgcn_s_barrier();
    LDB(Y, 1);                           // ds_read tile 31
    MFMA32P(X);
    // ---- tile 31 (Y, buf1) ----
    LGKM0();
    VMW0();
    SB0();
    MFMA32P(Y);

    // ---- epilogue ----
    if constexpr (MODE == 1) {
        const int sel   = bn >> 10;                        // 0=q,1=k,2=v
        const int bcol  = (bn & 1023) + (wc << 7);
        const int crow0 = bm + (wr << 6) + (kg << 2);
        if (sel == 2) {
            u16* vt = (u16*)Cv + (size_t)16777216;
#pragma unroll
            for (int m = 0; m < 4; ++m) {
                const int row0 = crow0 + (m << 4);
                const int bb   = row0 >> 12;
                const int s0   = row0 & 4095;
#pragma unroll
                for (int nf = 0; nf < 8; ++nf) {
                    const int col = bcol + (nf << 4) + fr;
                    const int hh  = col >> 6;
                    const int d   = col & 63;
                    u32x2 pk;
                    pk.x = (u32)f2bf(acc[m][nf][0]) | ((u32)f2bf(acc[m][nf][1]) << 16);
                    pk.y = (u32)f2bf(acc[m][nf][2]) | ((u32)f2bf(acc[m][nf][3]) << 16);
                    *(u32x2*)(vt + ((size_t)((bb << 4) + hh) * 64 + d) * 4096 + s0) = pk;
                }
            }
        } else {
            u16* outb = (u16*)Cv + (size_t)sel * 8388608;
            const int hb = bcol >> 6;
#pragma unroll
            for (int m = 0; m < 4; ++m)
#pragma unroll
                for (int r = 0; r < 4; ++r) {
                    const int row = crow0 + (m << 4) + r;
                    const int s   = row & 4095;
                    const int bb  = row >> 12;
                    const f32x2 c0 = *(const f32x2*)(cstab + (((s << 5) + fr) << 1));
                    const f32x2 c1 = *(const f32x2*)(cstab + (((s << 5) + 16 + fr) << 1));
#pragma unroll
                    for (int g = 0; g < 2; ++g) {
                        u16* qp = outb + ((size_t)((bb << 4) + hb + g) * 4096 + s) * 64;
                        {
                            const float lo = acc[m][(g << 2) + 0][r];
                            const float hi = acc[m][(g << 2) + 2][r];
                            qp[fr]      = f2bf(lo * c0.x - hi * c0.y);
                            qp[32 + fr] = f2bf(hi * c0.x + lo * c0.y);
                        }
                        {
                            const float lo = acc[m][(g << 2) + 1][r];
                            const float hi = acc[m][(g << 2) + 3][r];
                            qp[16 + fr] = f2bf(lo * c1.x - hi * c1.y);
                            qp[48 + fr] = f2bf(hi * c1.x + lo * c1.y);
                        }
                    }
                }
        }
    } else {
        float* outf     = (float*)Cv;
        const int bcol  = bn + (wc << 7) + fr;
        const int crow0 = bm + (wr << 6) + (kg << 2);
#pragma unroll
        for (int m = 0; m < 4; ++m)
#pragma unroll
            for (int r = 0; r < 4; ++r) {
                const int row = crow0 + (m << 4) + r;
                float* op = outf + (size_t)row * 1024 + bcol;
#pragma unroll
                for (int nf = 0; nf < 8; ++nf)
                    op[nf << 4] = acc[m][nf][r];
            }
    }
}

// ---------------- sliding-window attention, MFMA, head-major inputs ----------------
// Output written in A-frag-packed layout for the projection GEMM.
__global__ __launch_bounds__(256)
void attn_kernel(const u16* __restrict__ Q, const u16* __restrict__ K,
                 const u16* __restrict__ Vt, u16* __restrict__ O) {
    __shared__ __align__(16) u16 Ks[192 * 64];
    __shared__ __align__(16) u16 Vs[64 * 192];
    const int bid0 = blockIdx.x;
    const int bid  = ((bid0 & 7) << 8) | (bid0 >> 3);
    const int ch  = bid & 63;
    const int h   = (bid >> 6) & 15;
    const int b   = bid >> 10;
    const int qs  = ch << 6;
    const int t   = threadIdx.x;
    const int ub  = t & 192;

    const u16* kwin = K + ((size_t)((b << 4) + h) << 18);

#pragma unroll
    for (int i = 0; i < 6; ++i) {
        const int cid = (i << 8) + t;
        const int row = cid >> 3;
        const int g   = (cid & 7) ^ (row & 7);
        const int kp  = qs - 64 + row;
        const u16* src = kwin + (long)kp * 64 + (g << 3);
        GL(src, &Ks[((i << 8) + ub) << 3]);
    }
#pragma unroll
    for (int i = 0; i < 6; ++i) {
        const int cid = (i << 8) + t;
        const int d   = cid / 24;
        const int c   = cid - d * 24;
        int g = c - (d & 7) * 3;
        if (g < 0) g += 24;
        const int key = qs - 64 + (g << 3);
        const u16* src = Vt + ((size_t)((b << 10) + (h << 6) + d)) * 4096 + key;
        GL(src, &Vs[((i << 8) + ub) << 3]);
    }

    const int w    = t >> 6;
    const int lane = t & 63;
    const int fr   = lane & 15;
    const int kg   = lane >> 4;
    const int f7   = fr & 7;

    const size_t qgoff = (((size_t)((b << 4) + h)) * 4096 + qs + (w << 4) + fr) * 64 + (kg << 3);
    const s16x8 qa0 = *(const s16x8*)(Q + qgoff);
    const s16x8 qa1 = *(const s16x8*)(Q + qgoff + 32);

    VMW0();
    __syncthreads();

    f32x4 sfr[9];
#pragma unroll
    for (int n = 0; n < 9; ++n) {
        const int row = (w << 4) + (n << 4) + fr;
        f32x4 a = f32x4{0.f, 0.f, 0.f, 0.f};
        const s16x8 kb0 = *(const s16x8*)(&Ks[(row << 6) + ((kg ^ f7) << 3)]);
        const s16x8 kb1 = *(const s16x8*)(&Ks[(row << 6) + (((4 + kg) ^ f7) << 3)]);
        a = MFMA16(qa0, kb0, a);
        a = MFMA16(qa1, kb1, a);
        sfr[n] = a;
    }

    const float NEG = -__builtin_inff();
    float mx[4] = {NEG, NEG, NEG, NEG};
#pragma unroll
    for (int n = 0; n < 9; ++n) {
        const int j = (n << 4) + fr;
#pragma unroll
        for (int r = 0; r < 4; ++r) {
            const int q  = (kg << 2) + r;
            const int kp = qs - 64 + (w << 4) + j;
            const bool valid = (j >= q) && (j - q < 128) && (kp >= 0) && (kp < S_LEN);
            const float s = valid ? sfr[n][r] * 0.125f : NEG;
            sfr[n][r] = s;
            mx[r] = fmaxf(mx[r], s);
        }
    }
#pragma unroll
    for (int r = 0; r < 4; ++r) mx[r] = rmax16(mx[r]);
    float ls[4] = {0.f, 0.f, 0.f, 0.f};
#pragma unroll
    for (int n = 0; n < 9; ++n)
#pragma unroll
        for (int r = 0; r < 4; ++r) {
            const float p = __expf(sfr[n][r] - mx[r]);
            sfr[n][r] = p;
            ls[r] += p;
        }
#pragma unroll
    for (int r = 0; r < 4; ++r) ls[r] = rsum16(ls[r]);

    __syncthreads();
    u16* Pw = Ks + w * 3072;
#pragma unroll
    for (int n = 0; n < 9; ++n) {
        const int j = (n << 4) + fr;
#pragma unroll
        for (int r = 0; r < 4; ++r) {
            const int q = (kg << 2) + r;
            Pw[q * 192 + (((j >> 3) ^ (q & 7)) << 3) + (j & 7)] = f2bf(sfr[n][r]);
        }
    }
    {
        const int j = 144 + fr;
#pragma unroll
        for (int r = 0; r < 4; ++r) {
            const int q = (kg << 2) + r;
            Pw[q * 192 + (((j >> 3) ^ (q & 7)) << 3) + (j & 7)] = 0;
        }
    }
    __syncthreads();

    f32x4 o[4];
#pragma unroll
    for (int nf = 0; nf < 4; ++nf) o[nf] = f32x4{0.f, 0.f, 0.f, 0.f};
    const int cs0 = f7 * 3;
#pragma unroll
    for (int ks = 0; ks < 5; ++ks) {
        const s16x8 pa = *(const s16x8*)(&Pw[fr * 192 + ((((ks << 2) + kg) ^ f7) << 3)]);
        int c = (w << 1) + (ks << 2) + kg;
        if (c > 23) c = 23;
        int cs = c + cs0;
        if (cs >= 24) cs -= 24;
#pragma unroll
        for (int nf = 0; nf < 4; ++nf) {
            const int d = (nf << 4) + fr;
            const s16x8 vbf = *(const s16x8*)(&Vs[d * 192 + (cs << 3)]);
            o[nf] = MFMA16(pa, vbf, o[nf]);
        }
    }

    // ---- normalize + store in A-frag-packed layout (nfrag_tot = 512) ----
    const int mfrag = (b << 8) + (ch << 2) + w;
#pragma unroll
    for (int r = 0; r < 4; ++r) {
        const float inv = 1.f / ls[r];
#pragma unroll
        for (int nf = 0; nf < 4; ++nf) {
            const int kt  = (h << 1) + (nf >> 1);
            const int kgp = ((nf & 1) << 1) + (fr >> 3);
            const int lp  = (kgp << 4) + (kg << 2) + r;
            O[((((size_t)kt << 9) + mfrag) * 64 + lp) * 8 + (fr & 7)] = f2bf(o[nf][r] * inv);
        }
    }
}

extern "C" void kernel_launch(void* const* d_in, const int* in_sizes, int n_in,
                              void* d_out, int out_size, void* d_ws, size_t ws_size,
                              hipStream_t stream) {
    const float* x  = (const float*)d_in[0];
    const float* fr = (const float*)d_in[1];
    const float* wq = (const float*)d_in[2];
    const float* wk = (const float*)d_in[3];
    const float* wv = (const float*)d_in[4];
    const float* wo = (const float*)d_in[5];

    u16* ws    = (u16*)d_ws;
    u16* apk   = ws;                       // 8388608  (x packed; later attn-out packed)
    u16* bpk   = apk + 8388608;            // 3145728  (wq|wk|wv packed)
    u16* wopk  = bpk + 3145728;            // 1048576
    u16* qb    = wopk + 1048576;           // 8388608 head-major; kb, vtb follow
    u16* kb    = qb + 8388608;
    u16* vtb   = kb + 8388608;
    float* cstab = (float*)(vtb + 8388608);
    u16* opk   = apk;                      // reuse after QKV GEMM

    prep_kernel<<<1280, 256, 0, stream>>>(x, wq, wk, wv, wo, fr, apk, bpk, wopk, cstab);

    dim3 gqkv(64, 12);
    gemm_hy<196608, 1><<<gqkv, 256, 0, stream>>>(apk, bpk, qb, cstab);

    attn_kernel<<<2048, 256, 0, stream>>>(qb, kb, vtb, opk);

    dim3 gout(64, 4);
    gemm_hy<65536, 2><<<gout, 256, 0, stream>>>(opk, wopk, (float*)d_out, nullptr);
}

// Round 16
// 106.323 us; speedup vs baseline: 1.3044x; 1.0024x over previous
//
#include <hip/hip_runtime.h>

typedef unsigned short u16;
typedef unsigned int   u32;
typedef unsigned long long u64;
typedef __attribute__((ext_vector_type(4))) unsigned int u32x4;
typedef __attribute__((ext_vector_type(2))) unsigned int u32x2;
typedef __attribute__((ext_vector_type(8))) short        s16x8;
typedef __attribute__((ext_vector_type(4))) float        f32x4;
typedef __attribute__((ext_vector_type(2))) float        f32x2;

#define S_LEN 4096

typedef const __attribute__((address_space(1))) void gas_void;
typedef __attribute__((address_space(3))) void las_void;

__device__ __forceinline__ u16 f2bf(float f) {
    u32 u = __builtin_bit_cast(u32, f);
    u32 r = (u + 0x7fffu + ((u >> 16) & 1u)) >> 16;
    return (u16)r;
}

__device__ __forceinline__ float rmax16(float v) {
    v = fmaxf(v, __shfl_xor(v, 1));
    v = fmaxf(v, __shfl_xor(v, 2));
    v = fmaxf(v, __shfl_xor(v, 4));
    v = fmaxf(v, __shfl_xor(v, 8));
    return v;
}
__device__ __forceinline__ float rsum16(float v) {
    v += __shfl_xor(v, 1);
    v += __shfl_xor(v, 2);
    v += __shfl_xor(v, 4);
    v += __shfl_xor(v, 8);
    return v;
}

#define VMW0() asm volatile("s_waitcnt vmcnt(0)" ::: "memory")
#define VMWS(n) do { asm volatile("s_waitcnt vmcnt(" #n ")" ::: "memory"); \
                     __builtin_amdgcn_sched_barrier(0); } while (0)
#define LGKM0() do { asm volatile("s_waitcnt lgkmcnt(0)" ::: "memory"); \
                     __builtin_amdgcn_sched_barrier(0); } while (0)
#define SB0() __builtin_amdgcn_sched_barrier(0)
#define DSR0(d, a)   asm volatile("ds_read_b128 %0, %1"              : "=v"(d) : "v"(a))
#define DSR(d, a, o) asm volatile("ds_read_b128 %0, %1 offset:" #o   : "=v"(d) : "v"(a))
#define MFMA16(a, b, c) __builtin_amdgcn_mfma_f32_16x16x32_bf16(a, b, c, 0, 0, 0)
#define GL(p, d) __builtin_amdgcn_global_load_lds((gas_void*)(p), (las_void*)(d), 16, 0, 0)
#define GLB(d, a, o) asm volatile("global_load_dwordx4 %0, %1, off offset:" #o : "=v"(d) : "v"(a))

// =====================================================================
// prep: pack x -> A-frag layout, weights -> B-frag layout, rope table.
// Packed layout: pk[kt][frag][lane][8] (u16), element =
//   M[frag*16 + (lane&15)][kt*32 + (lane>>4)*8 + j]
// =====================================================================
__global__ __launch_bounds__(256)
void prep_kernel(const float* __restrict__ x,
                 const float* __restrict__ wq, const float* __restrict__ wk,
                 const float* __restrict__ wv, const float* __restrict__ wo,
                 const float* __restrict__ freqs,
                 u16* __restrict__ apk, u16* __restrict__ bpk, u16* __restrict__ wopk,
                 float* __restrict__ tab) {
    const int bid = blockIdx.x;
    const int t   = threadIdx.x;
    if (bid >= 768) {                                  // rope table: 131072 entries
        const int i = (bid - 768) * 256 + t;
        const float f = freqs[i];
        float sn, cs;
        sincosf(f, &sn, &cs);
        tab[i * 2]     = cs;
        tab[i * 2 + 1] = sn;
        return;
    }
    __shared__ u16 L[16][1032];
    const float* src;
    u16* dst;
    int nft, frag0, rowblk;
    if (bid < 512) { src = x; dst = apk; nft = 512; rowblk = bid; frag0 = bid; }
    else {
        const int wsel = (bid - 512) >> 6;
        rowblk = (bid - 512) & 63;
        src = (wsel == 0) ? wq : (wsel == 1) ? wk : (wsel == 2) ? wv : wo;
        if (wsel < 3) { dst = bpk;  nft = 192; frag0 = wsel * 64 + rowblk; }
        else          { dst = wopk; nft = 64;  frag0 = rowblk; }
    }
#pragma unroll
    for (int r = 0; r < 16; ++r) {
        const f32x4 v = *(const f32x4*)(src + ((size_t)(rowblk * 16 + r)) * 1024 + t * 4);
        u16* Lp = &L[r][t * 4];
        Lp[0] = f2bf(v.x); Lp[1] = f2bf(v.y); Lp[2] = f2bf(v.z); Lp[3] = f2bf(v.w);
    }
    __syncthreads();
#pragma unroll
    for (int i = 0; i < 8; ++i) {
        const int idx = (i << 8) + t;
        const int c32 = idx >> 6;
        const int l   = idx & 63;
        const u32x4 d = *(const u32x4*)(&L[l & 15][(c32 << 5) + ((l >> 4) << 3)]);
        *(u32x4*)(dst + (((size_t)c32 * nft + frag0) * 64 + l) * 8) = d;
    }
}

// =====================================================================
// HYBRID QKV GEMM (r15-verified): A direct from L1, B via LDS.
// 256 thr / 4 waves (2Mx2N), wave 64x128, BM=128 BN=256 BK=32.
// =====================================================================
#define FRAGS(P) s16x8 P##a0,P##a1,P##a2,P##a3, \
                       P##b0,P##b1,P##b2,P##b3,P##b4,P##b5,P##b6,P##b7

#define LDA(P) do { \
    GLB(P##a0, aA, 0); GLB(P##a1, aA, 1024); GLB(P##a2, aA, 2048); GLB(P##a3, aA, 3072); \
    aA += 524288u; \
} while (0)

#define SGB(BUF) do { \
    GL((const u16*)gBs,          &Bs[BUF][(((wave << 2) + 0) << 9)]); \
    GL((const u16*)(gBs + 1024), &Bs[BUF][(((wave << 2) + 1) << 9)]); \
    GL((const u16*)(gBs + 2048), &Bs[BUF][(((wave << 2) + 2) << 9)]); \
    GL((const u16*)(gBs + 3072), &Bs[BUF][(((wave << 2) + 3) << 9)]); \
    gBs += 196608u; \
} while (0)

#define LDB(P, BUF) do { \
    const u32 rb_ = ldsB + ((BUF) ? 16384u : 0u) + (wc << 13) + (lane << 4); \
    DSR0(P##b0, rb_); DSR(P##b1, rb_, 1024); DSR(P##b2, rb_, 2048); DSR(P##b3, rb_, 3072); \
    DSR(P##b4, rb_, 4096); DSR(P##b5, rb_, 5120); DSR(P##b6, rb_, 6144); DSR(P##b7, rb_, 7168); \
} while (0)

#define MFMA32P(P) do { \
    __builtin_amdgcn_s_setprio(1); \
    acc[0][0]=MFMA16(P##a0,P##b0,acc[0][0]); acc[1][0]=MFMA16(P##a1,P##b0,acc[1][0]); \
    acc[2][0]=MFMA16(P##a2,P##b0,acc[2][0]); acc[3][0]=MFMA16(P##a3,P##b0,acc[3][0]); \
    acc[0][1]=MFMA16(P##a0,P##b1,acc[0][1]); acc[1][1]=MFMA16(P##a1,P##b1,acc[1][1]); \
    acc[2][1]=MFMA16(P##a2,P##b1,acc[2][1]); acc[3][1]=MFMA16(P##a3,P##b1,acc[3][1]); \
    acc[0][2]=MFMA16(P##a0,P##b2,acc[0][2]); acc[1][2]=MFMA16(P##a1,P##b2,acc[1][2]); \
    acc[2][2]=MFMA16(P##a2,P##b2,acc[2][2]); acc[3][2]=MFMA16(P##a3,P##b2,acc[3][2]); \
    acc[0][3]=MFMA16(P##a0,P##b3,acc[0][3]); acc[1][3]=MFMA16(P##a1,P##b3,acc[1][3]); \
    acc[2][3]=MFMA16(P##a2,P##b3,acc[2][3]); acc[3][3]=MFMA16(P##a3,P##b3,acc[3][3]); \
    acc[0][4]=MFMA16(P##a0,P##b4,acc[0][4]); acc[1][4]=MFMA16(P##a1,P##b4,acc[1][4]); \
    acc[2][4]=MFMA16(P##a2,P##b4,acc[2][4]); acc[3][4]=MFMA16(P##a3,P##b4,acc[3][4]); \
    acc[0][5]=MFMA16(P##a0,P##b5,acc[0][5]); acc[1][5]=MFMA16(P##a1,P##b5,acc[1][5]); \
    acc[2][5]=MFMA16(P##a2,P##b5,acc[2][5]); acc[3][5]=MFMA16(P##a3,P##b5,acc[3][5]); \
    acc[0][6]=MFMA16(P##a0,P##b6,acc[0][6]); acc[1][6]=MFMA16(P##a1,P##b6,acc[1][6]); \
    acc[2][6]=MFMA16(P##a2,P##b6,acc[2][6]); acc[3][6]=MFMA16(P##a3,P##b6,acc[3][6]); \
    acc[0][7]=MFMA16(P##a0,P##b7,acc[0][7]); acc[1][7]=MFMA16(P##a1,P##b7,acc[1][7]); \
    acc[2][7]=MFMA16(P##a2,P##b7,acc[2][7]); acc[3][7]=MFMA16(P##a3,P##b7,acc[3][7]); \
    __builtin_amdgcn_s_setprio(0); \
} while (0)

__global__ __launch_bounds__(256, 2)
void gemm_qkv(const u16* __restrict__ Apk, const u16* __restrict__ Bpk,
              void* __restrict__ Cv, const float* __restrict__ cstab) {
    __shared__ __align__(1024) u16 Bs[2][8192];
    const int t    = threadIdx.x;
    const int bm   = blockIdx.x << 7;
    const int bn   = blockIdx.y << 8;
    const int wave = t >> 6;
    const int wr   = (wave >> 1) & 1;
    const int wc   = wave & 1;
    const int lane = t & 63;
    const int fr   = lane & 15;
    const int kg   = lane >> 4;

    u64 aA  = (u64)(uintptr_t)Apk + (u64)((((bm >> 4) + (wr << 2)) << 10) + (lane << 4));
    u64 gBs = (u64)(uintptr_t)Bpk + (u64)((((bn >> 4) + (wave << 2)) << 10) + (lane << 4));
    const u32 ldsB = (u32)(size_t)(las_void*)&Bs[0][0];

    f32x4 acc[4][8];
#pragma unroll
    for (int m = 0; m < 4; ++m)
#pragma unroll
        for (int n = 0; n < 8; ++n) acc[m][n] = f32x4{0.f, 0.f, 0.f, 0.f};

    FRAGS(X);
    FRAGS(Y);

    SGB(0);
    LDA(X);
    SGB(1);
    LDA(Y);
    VMWS(12);
    __builtin_amdgcn_s_barrier();
    LDB(X, 0);

#pragma unroll 1
    for (int jj = 0; jj < 15; ++jj) {
        LGKM0();
        VMWS(4);
        __builtin_amdgcn_s_barrier();
        SGB(0);
        LDB(Y, 1);
        MFMA32P(X);
        LDA(X);
        LGKM0();
        VMWS(4);
        __builtin_amdgcn_s_barrier();
        SGB(1);
        LDB(X, 0);
        MFMA32P(Y);
        LDA(Y);
    }
    LGKM0();
    VMWS(4);
    __builtin_amdgcn_s_barrier();
    LDB(Y, 1);
    MFMA32P(X);
    LGKM0();
    VMW0();
    SB0();
    MFMA32P(Y);

    // ---- fused QKV epilogue ----
    const int sel   = bn >> 10;                        // 0=q,1=k,2=v
    const int bcol  = (bn & 1023) + (wc << 7);
    const int crow0 = bm + (wr << 6) + (kg << 2);
    if (sel == 2) {
        u16* vt = (u16*)Cv + (size_t)16777216;
#pragma unroll
        for (int m = 0; m < 4; ++m) {
            const int row0 = crow0 + (m << 4);
            const int bb   = row0 >> 12;
            const int s0   = row0 & 4095;
#pragma unroll
            for (int nf = 0; nf < 8; ++nf) {
                const int col = bcol + (nf << 4) + fr;
                const int hh  = col >> 6;
                const int d   = col & 63;
                u32x2 pk;
                pk.x = (u32)f2bf(acc[m][nf][0]) | ((u32)f2bf(acc[m][nf][1]) << 16);
                pk.y = (u32)f2bf(acc[m][nf][2]) | ((u32)f2bf(acc[m][nf][3]) << 16);
                *(u32x2*)(vt + ((size_t)((bb << 4) + hh) * 64 + d) * 4096 + s0) = pk;
            }
        }
    } else {
        u16* outb = (u16*)Cv + (size_t)sel * 8388608;
        const int hb = bcol >> 6;
#pragma unroll
        for (int m = 0; m < 4; ++m)
#pragma unroll
            for (int r = 0; r < 4; ++r) {
                const int row = crow0 + (m << 4) + r;
                const int s   = row & 4095;
                const int bb  = row >> 12;
                const f32x2 c0 = *(const f32x2*)(cstab + (((s << 5) + fr) << 1));
                const f32x2 c1 = *(const f32x2*)(cstab + (((s << 5) + 16 + fr) << 1));
#pragma unroll
                for (int g = 0; g < 2; ++g) {
                    u16* qp = outb + ((size_t)((bb << 4) + hb + g) * 4096 + s) * 64;
                    {
                        const float lo = acc[m][(g << 2) + 0][r];
                        const float hi = acc[m][(g << 2) + 2][r];
                        qp[fr]      = f2bf(lo * c0.x - hi * c0.y);
                        qp[32 + fr] = f2bf(hi * c0.x + lo * c0.y);
                    }
                    {
                        const float lo = acc[m][(g << 2) + 1][r];
                        const float hi = acc[m][(g << 2) + 3][r];
                        qp[16 + fr] = f2bf(lo * c1.x - hi * c1.y);
                        qp[48 + fr] = f2bf(hi * c1.x + lo * c1.y);
                    }
                }
            }
    }
}

// =====================================================================
// PROJ GEMM: 512 thr / 8 waves (2M x 4N), wave tile 64x64, BM=128 BN=256.
// 2 waves/SIMD -> intra-SIMD phase overlap (no co-resident block needed).
// Per tile per wave: 4 A glb + 2 B gload_lds + 4 ds_read + 16 MFMA.
// vmcnt: prologue VMWS(10); steady VMWS(4) = certify {stage j+1, A j},
// leave A j+1 flying; VMW0 only at final tile. f32 row-major out.
// =====================================================================
#define FRAGS2(P) s16x8 P##a0,P##a1,P##a2,P##a3, P##b0,P##b1,P##b2,P##b3

#define SGB2(BUF) do { \
    GL((const u16*)gBs,          &Bs[BUF][(((wave << 1) + 0) << 9)]); \
    GL((const u16*)(gBs + 1024), &Bs[BUF][(((wave << 1) + 1) << 9)]); \
    gBs += 65536u; \
} while (0)

#define LDB2(P, BUF) do { \
    const u32 rb_ = ldsB + ((BUF) ? 16384u : 0u) + (wc << 12) + (lane << 4); \
    DSR0(P##b0, rb_); DSR(P##b1, rb_, 1024); DSR(P##b2, rb_, 2048); DSR(P##b3, rb_, 3072); \
} while (0)

#define MFMA16P(P) do { \
    __builtin_amdgcn_s_setprio(1); \
    acc[0][0]=MFMA16(P##a0,P##b0,acc[0][0]); acc[1][0]=MFMA16(P##a1,P##b0,acc[1][0]); \
    acc[2][0]=MFMA16(P##a2,P##b0,acc[2][0]); acc[3][0]=MFMA16(P##a3,P##b0,acc[3][0]); \
    acc[0][1]=MFMA16(P##a0,P##b1,acc[0][1]); acc[1][1]=MFMA16(P##a1,P##b1,acc[1][1]); \
    acc[2][1]=MFMA16(P##a2,P##b1,acc[2][1]); acc[3][1]=MFMA16(P##a3,P##b1,acc[3][1]); \
    acc[0][2]=MFMA16(P##a0,P##b2,acc[0][2]); acc[1][2]=MFMA16(P##a1,P##b2,acc[1][2]); \
    acc[2][2]=MFMA16(P##a2,P##b2,acc[2][2]); acc[3][2]=MFMA16(P##a3,P##b2,acc[3][2]); \
    acc[0][3]=MFMA16(P##a0,P##b3,acc[0][3]); acc[1][3]=MFMA16(P##a1,P##b3,acc[1][3]); \
    acc[2][3]=MFMA16(P##a2,P##b3,acc[2][3]); acc[3][3]=MFMA16(P##a3,P##b3,acc[3][3]); \
    __builtin_amdgcn_s_setprio(0); \
} while (0)

__global__ __launch_bounds__(512, 2)
void gemm_out(const u16* __restrict__ Apk, const u16* __restrict__ Bpk,
              float* __restrict__ Cv) {
    __shared__ __align__(1024) u16 Bs[2][8192];
    const int t    = threadIdx.x;
    const int bm   = blockIdx.x << 7;
    const int bn   = blockIdx.y << 8;
    const int wave = t >> 6;
    const int wr   = wave >> 2;                 // 0..1
    const int wc   = wave & 3;                  // 0..3
    const int lane = t & 63;
    const int fr   = lane & 15;
    const int kg   = lane >> 4;

    u64 aA  = (u64)(uintptr_t)Apk + (u64)((((bm >> 4) + (wr << 2)) << 10) + (lane << 4));
    u64 gBs = (u64)(uintptr_t)Bpk + (u64)((((bn >> 4) + (wave << 1)) << 10) + (lane << 4));
    const u32 ldsB = (u32)(size_t)(las_void*)&Bs[0][0];

    f32x4 acc[4][4];
#pragma unroll
    for (int m = 0; m < 4; ++m)
#pragma unroll
        for (int n = 0; n < 4; ++n) acc[m][n] = f32x4{0.f, 0.f, 0.f, 0.f};

    FRAGS2(X);
    FRAGS2(Y);

    SGB2(0);
    LDA(X);
    SGB2(1);
    LDA(Y);
    VMWS(10);                           // SGB2(0) landed
    __builtin_amdgcn_s_barrier();
    LDB2(X, 0);

#pragma unroll 1
    for (int jj = 0; jj < 15; ++jj) {
        LGKM0();
        VMWS(4);                        // certify stage(2jj+1)+A(2jj); leave A(2jj+1)
        __builtin_amdgcn_s_barrier();
        SGB2(0);
        LDB2(Y, 1);
        MFMA16P(X);
        LDA(X);
        LGKM0();
        VMWS(4);
        __builtin_amdgcn_s_barrier();
        SGB2(1);
        LDB2(X, 0);
        MFMA16P(Y);
        LDA(Y);
    }
    LGKM0();
    VMWS(4);                            // certify stage(31)+A(30); leave A(31)
    __builtin_amdgcn_s_barrier();
    LDB2(Y, 1);
    MFMA16P(X);
    LGKM0();
    VMW0();
    SB0();
    MFMA16P(Y);

    // ---- f32 epilogue ----
    const int bcol  = bn + (wc << 6) + fr;
    const int crow0 = bm + (wr << 6) + (kg << 2);
#pragma unroll
    for (int m = 0; m < 4; ++m)
#pragma unroll
        for (int r = 0; r < 4; ++r) {
            const int row = crow0 + (m << 4) + r;
            float* op = Cv + (size_t)row * 1024 + bcol;
            op[0]  = acc[m][0][r];
            op[16] = acc[m][1][r];
            op[32] = acc[m][2][r];
            op[48] = acc[m][3][r];
        }
}

// ---------------- sliding-window attention, MFMA, head-major inputs ----------------
// Output written in A-frag-packed layout for the projection GEMM.
__global__ __launch_bounds__(256)
void attn_kernel(const u16* __restrict__ Q, const u16* __restrict__ K,
                 const u16* __restrict__ Vt, u16* __restrict__ O) {
    __shared__ __align__(16) u16 Ks[192 * 64];
    __shared__ __align__(16) u16 Vs[64 * 192];
    const int bid0 = blockIdx.x;
    const int bid  = ((bid0 & 7) << 8) | (bid0 >> 3);
    const int ch  = bid & 63;
    const int h   = (bid >> 6) & 15;
    const int b   = bid >> 10;
    const int qs  = ch << 6;
    const int t   = threadIdx.x;
    const int ub  = t & 192;

    const u16* kwin = K + ((size_t)((b << 4) + h) << 18);

#pragma unroll
    for (int i = 0; i < 6; ++i) {
        const int cid = (i << 8) + t;
        const int row = cid >> 3;
        const int g   = (cid & 7) ^ (row & 7);
        const int kp  = qs - 64 + row;
        const u16* src = kwin + (long)kp * 64 + (g << 3);
        GL(src, &Ks[((i << 8) + ub) << 3]);
    }
#pragma unroll
    for (int i = 0; i < 6; ++i) {
        const int cid = (i << 8) + t;
        const int d   = cid / 24;
        const int c   = cid - d * 24;
        int g = c - (d & 7) * 3;
        if (g < 0) g += 24;
        const int key = qs - 64 + (g << 3);
        const u16* src = Vt + ((size_t)((b << 10) + (h << 6) + d)) * 4096 + key;
        GL(src, &Vs[((i << 8) + ub) << 3]);
    }

    const int w    = t >> 6;
    const int lane = t & 63;
    const int fr   = lane & 15;
    const int kg   = lane >> 4;
    const int f7   = fr & 7;

    const size_t qgoff = (((size_t)((b << 4) + h)) * 4096 + qs + (w << 4) + fr) * 64 + (kg << 3);
    const s16x8 qa0 = *(const s16x8*)(Q + qgoff);
    const s16x8 qa1 = *(const s16x8*)(Q + qgoff + 32);

    VMW0();
    __syncthreads();

    f32x4 sfr[9];
#pragma unroll
    for (int n = 0; n < 9; ++n) {
        const int row = (w << 4) + (n << 4) + fr;
        f32x4 a = f32x4{0.f, 0.f, 0.f, 0.f};
        const s16x8 kb0 = *(const s16x8*)(&Ks[(row << 6) + ((kg ^ f7) << 3)]);
        const s16x8 kb1 = *(const s16x8*)(&Ks[(row << 6) + (((4 + kg) ^ f7) << 3)]);
        a = MFMA16(qa0, kb0, a);
        a = MFMA16(qa1, kb1, a);
        sfr[n] = a;
    }

    const float NEG = -__builtin_inff();
    float mx[4] = {NEG, NEG, NEG, NEG};
#pragma unroll
    for (int n = 0; n < 9; ++n) {
        const int j = (n << 4) + fr;
#pragma unroll
        for (int r = 0; r < 4; ++r) {
            const int q  = (kg << 2) + r;
            const int kp = qs - 64 + (w << 4) + j;
            const bool valid = (j >= q) && (j - q < 128) && (kp >= 0) && (kp < S_LEN);
            const float s = valid ? sfr[n][r] * 0.125f : NEG;
            sfr[n][r] = s;
            mx[r] = fmaxf(mx[r], s);
        }
    }
#pragma unroll
    for (int r = 0; r < 4; ++r) mx[r] = rmax16(mx[r]);
    float ls[4] = {0.f, 0.f, 0.f, 0.f};
#pragma unroll
    for (int n = 0; n < 9; ++n)
#pragma unroll
        for (int r = 0; r < 4; ++r) {
            const float p = __expf(sfr[n][r] - mx[r]);
            sfr[n][r] = p;
            ls[r] += p;
        }
#pragma unroll
    for (int r = 0; r < 4; ++r) ls[r] = rsum16(ls[r]);

    __syncthreads();
    u16* Pw = Ks + w * 3072;
#pragma unroll
    for (int n = 0; n < 9; ++n) {
        const int j = (n << 4) + fr;
#pragma unroll
        for (int r = 0; r < 4; ++r) {
            const int q = (kg << 2) + r;
            Pw[q * 192 + (((j >> 3) ^ (q & 7)) << 3) + (j & 7)] = f2bf(sfr[n][r]);
        }
    }
    {
        const int j = 144 + fr;
#pragma unroll
        for (int r = 0; r < 4; ++r) {
            const int q = (kg << 2) + r;
            Pw[q * 192 + (((j >> 3) ^ (q & 7)) << 3) + (j & 7)] = 0;
        }
    }
    __syncthreads();

    f32x4 o[4];
#pragma unroll
    for (int nf = 0; nf < 4; ++nf) o[nf] = f32x4{0.f, 0.f, 0.f, 0.f};
    const int cs0 = f7 * 3;
#pragma unroll
    for (int ks = 0; ks < 5; ++ks) {
        const s16x8 pa = *(const s16x8*)(&Pw[fr * 192 + ((((ks << 2) + kg) ^ f7) << 3)]);
        int c = (w << 1) + (ks << 2) + kg;
        if (c > 23) c = 23;
        int cs = c + cs0;
        if (cs >= 24) cs -= 24;
#pragma unroll
        for (int nf = 0; nf < 4; ++nf) {
            const int d = (nf << 4) + fr;
            const s16x8 vbf = *(const s16x8*)(&Vs[d * 192 + (cs << 3)]);
            o[nf] = MFMA16(pa, vbf, o[nf]);
        }
    }

    // ---- normalize + store in A-frag-packed layout (nfrag_tot = 512) ----
    const int mfrag = (b << 8) + (ch << 2) + w;
#pragma unroll
    for (int r = 0; r < 4; ++r) {
        const float inv = 1.f / ls[r];
#pragma unroll
        for (int nf = 0; nf < 4; ++nf) {
            const int kt  = (h << 1) + (nf >> 1);
            const int kgp = ((nf & 1) << 1) + (fr >> 3);
            const int lp  = (kgp << 4) + (kg << 2) + r;
            O[((((size_t)kt << 9) + mfrag) * 64 + lp) * 8 + (fr & 7)] = f2bf(o[nf][r] * inv);
        }
    }
}

extern "C" void kernel_launch(void* const* d_in, const int* in_sizes, int n_in,
                              void* d_out, int out_size, void* d_ws, size_t ws_size,
                              hipStream_t stream) {
    const float* x  = (const float*)d_in[0];
    const float* fr = (const float*)d_in[1];
    const float* wq = (const float*)d_in[2];
    const float* wk = (const float*)d_in[3];
    const float* wv = (const float*)d_in[4];
    const float* wo = (const float*)d_in[5];

    u16* ws    = (u16*)d_ws;
    u16* apk   = ws;                       // 8388608  (x packed; later attn-out packed)
    u16* bpk   = apk + 8388608;            // 3145728  (wq|wk|wv packed)
    u16* wopk  = bpk + 3145728;            // 1048576
    u16* qb    = wopk + 1048576;           // 8388608 head-major; kb, vtb follow
    u16* kb    = qb + 8388608;
    u16* vtb   = kb + 8388608;
    float* cstab = (float*)(vtb + 8388608);
    u16* opk   = apk;                      // reuse after QKV GEMM

    prep_kernel<<<1280, 256, 0, stream>>>(x, wq, wk, wv, wo, fr, apk, bpk, wopk, cstab);

    dim3 gqkv(64, 12);
    gemm_qkv<<<gqkv, 256, 0, stream>>>(apk, bpk, qb, cstab);

    attn_kernel<<<2048, 256, 0, stream>>>(qb, kb, vtb, opk);

    dim3 gout(64, 4);
    gemm_out<<<gout, 512, 0, stream>>>(opk, wopk, (float*)d_out);
}